// Round 11
// baseline (2642.806 us; speedup 1.0000x reference)
//
#include <hip/hip_runtime.h>
#include <hip/hip_bf16.h>
#include <math.h>

#define CDIV(a, b) (((a) + (b) - 1) / (b))
typedef long long ll;
typedef unsigned short ushort_t;

constexpr int Bn = 32;    // batch
constexpr int Sn = 720;   // seq len
constexpr int SnP = 736;  // seq len padded to K-step multiple
constexpr int Cn = 2048;  // channels (tokens after transpose)
constexpr int Dn = 256;   // d_model
constexpr int Pn = 96;    // pred len

typedef __attribute__((ext_vector_type(8))) short bf16x8;
typedef __attribute__((ext_vector_type(4))) float f32x4;

__device__ inline ushort_t rne1(float x) {
  unsigned u = __float_as_uint(x);
  u = (u + 0x7fffu + ((u >> 16) & 1u)) >> 16;
  return (ushort_t)u;
}
__device__ inline float b2f(ushort_t u) { return __uint_as_float(((unsigned)u) << 16); }

__device__ inline void gl_lds16(const void* g, void* l) {
  __builtin_amdgcn_global_load_lds(
      (const __attribute__((address_space(1))) void*)g,
      (__attribute__((address_space(3))) void*)l, 16, 0, 0);
}

// ---------------- instance norm stats over time axis ----------------
__global__ void instnorm_stats(const float* __restrict__ x,
                               float* __restrict__ mean, float* __restrict__ stdev) {
  int c = blockIdx.x * 256 + threadIdx.x;
  int b = blockIdx.y;
  const float* p = x + (ll)b * Sn * Cn + c;
  float s = 0.f, q = 0.f;
  for (int t = 0; t < Sn; ++t) {
    float v = p[(ll)t * Cn];
    s += v; q += v * v;
  }
  float m = s / (float)Sn;
  float var = q / (float)Sn - m * m;
  var = fmaxf(var, 0.f);
  mean[b * Cn + c] = m;
  stdev[b * Cn + c] = sqrtf(var + 1e-5f);
}

// ---------------- normalize + transpose: x[b][s][c] -> xnT[b][c][s] bf16 (K-pad)
__global__ void normT_kernel(const float* __restrict__ X, ushort_t* __restrict__ D,
                             const float* __restrict__ mean,
                             const float* __restrict__ stdev) {
  int b = blockIdx.z;
  __shared__ float tl[32][33];
  int t = threadIdx.x;
  int tx = t & 31, ty = t >> 5;
  int s0 = blockIdx.y * 32, c0 = blockIdx.x * 32;
#pragma unroll
  for (int e = 0; e < 4; ++e) {
    int s = s0 + ty + 8 * e;
    tl[ty + 8 * e][tx] = (s < Sn) ? X[((ll)b * Sn + s) * Cn + c0 + tx] : 0.f;
  }
  __syncthreads();
#pragma unroll
  for (int e = 0; e < 4; ++e) {
    int c = c0 + ty + 8 * e, s = s0 + tx;
    if (s < SnP) {
      float mu = mean[b * Cn + c], sd = stdev[b * Cn + c];
      float v = (s < Sn) ? (tl[tx][ty + 8 * e] - mu) / sd : 0.f;
      D[((ll)b * Cn + c) * SnP + s] = rne1(v);
    }
  }
}

// ---------------- transpose-convert: W[K][N] f32 -> WT[N][KP] bf16 ------------
__global__ void cvtT_kernel(const float* __restrict__ S, ushort_t* __restrict__ D,
                            int K, int N, int KP) {
  int z = blockIdx.z;
  S += (ll)z * K * N;
  D += (ll)z * N * KP;
  __shared__ float tl[32][33];
  int t = threadIdx.x;
  int tx = t & 31, ty = t >> 5;
  int k0 = blockIdx.y * 32, n0 = blockIdx.x * 32;
#pragma unroll
  for (int e = 0; e < 4; ++e) {
    int k = k0 + ty + 8 * e;
    tl[ty + 8 * e][tx] = (k < K && n0 + tx < N) ? S[(ll)k * N + n0 + tx] : 0.f;
  }
  __syncthreads();
#pragma unroll
  for (int e = 0; e < 4; ++e) {
    int n = n0 + ty + 8 * e, kk = k0 + tx;
    if (n < N && kk < KP) D[(ll)n * KP + kk] = rne1(tl[tx][ty + 8 * e]);
  }
}

__global__ void cvt_bf(const float* __restrict__ S, ushort_t* __restrict__ D, int n) {
  int i = blockIdx.x * 256 + threadIdx.x;
  if (i < n) D[i] = rne1(S[i]);
}

// ---------------- canonical bf16 MFMA GEMM: C = A[M][K] * B[N][K]^T ----------
// global_load_lds staging; K must be a multiple of 32; OOB rows clamped.
// MODE bits: 1 = write f32 C (ldcf), 2 = write bf16 C (ldcb), 4 = write bf16 C^T
template <int MODE>
__global__ __launch_bounds__(256) void gemm_bf(
    const ushort_t* __restrict__ A, const ushort_t* __restrict__ B,
    int M, int N, int K, int lda, int ldb, ll sA, ll sB,
    const float* __restrict__ bias, float alpha,
    float* __restrict__ Cf, int ldcf, ll sCf,
    ushort_t* __restrict__ Cb, int ldcb, ll sCb) {
  int g = blockIdx.z;
  A += (ll)g * sA;
  B += (ll)g * sB;
  if (MODE & 1) Cf += (ll)g * sCf;
  if (MODE & 6) Cb += (ll)g * sCb;
  __shared__ ushort_t lds_ab[2][128][32];
  int t = threadIdx.x;
  int m0 = blockIdx.y * 128, n0 = blockIdx.x * 128;
  int w = t >> 6, lane = t & 63;
  int wm = (w >> 1) * 64, wn = (w & 1) * 64;
  int lrow = lane & 15, kq = lane >> 4;
  int srow = lane >> 2, skcol = (lane & 3) * 8;
  f32x4 acc[4][4] = {};
  for (int k0 = 0; k0 < K; k0 += 32) {
#pragma unroll
    for (int cc = 0; cc < 4; ++cc) {
      int c = w * 4 + cc;
      int tile = c >> 3, rb = (c & 7) * 16;
      int row = rb + srow;
      const ushort_t* src;
      if (tile == 0) {
        int gm = min(m0 + row, M - 1);
        src = &A[(ll)gm * lda + k0 + skcol];
      } else {
        int gn = min(n0 + row, N - 1);
        src = &B[(ll)gn * ldb + k0 + skcol];
      }
      gl_lds16(src, &lds_ab[tile][rb][0]);
    }
    __syncthreads();
    bf16x8 af[4], bfr[4];
#pragma unroll
    for (int i = 0; i < 4; ++i)
      af[i] = *reinterpret_cast<const bf16x8*>(&lds_ab[0][wm + i * 16 + lrow][kq * 8]);
#pragma unroll
    for (int j = 0; j < 4; ++j)
      bfr[j] = *reinterpret_cast<const bf16x8*>(&lds_ab[1][wn + j * 16 + lrow][kq * 8]);
#pragma unroll
    for (int i = 0; i < 4; ++i)
#pragma unroll
      for (int j = 0; j < 4; ++j)
        acc[i][j] = __builtin_amdgcn_mfma_f32_16x16x32_bf16(af[i], bfr[j],
                                                            acc[i][j], 0, 0, 0);
    __syncthreads();
  }
#pragma unroll
  for (int i = 0; i < 4; ++i) {
    int mb = m0 + wm + i * 16 + kq * 4;
    if (mb >= M) continue;
#pragma unroll
    for (int j = 0; j < 4; ++j) {
      int c = n0 + wn + j * 16 + lrow;
      if (c >= N) continue;
      float bv = bias ? bias[c] : 0.f;
#pragma unroll
      for (int reg = 0; reg < 4; ++reg) {
        int m = mb + reg;
        float v = acc[i][j][reg] * alpha + bv;
        if (MODE & 1) Cf[(ll)m * ldcf + c] = v;
        if (MODE & 2) Cb[(ll)m * ldcb + c] = rne1(v);
        if (MODE & 4) Cb[(ll)c * ldcb + m] = rne1(v);
      }
    }
  }
}

// ---------------- block reduction helper (blockDim = 256) ----------------
__device__ inline float blk_reduce(float v, volatile float* sh, int op) {
  int lane = threadIdx.x & 63, w = threadIdx.x >> 6;
#pragma unroll
  for (int off = 32; off > 0; off >>= 1) {
    float o = __shfl_down(v, off, 64);
    v = op ? fmaxf(v, o) : (v + o);
  }
  __syncthreads();
  if (lane == 0) sh[w] = v;
  __syncthreads();
  float r = op ? fmaxf(fmaxf(sh[0], sh[1]), fmaxf(sh[2], sh[3]))
               : (sh[0] + sh[1] + sh[2] + sh[3]);
  return r;
}

// ---------------- row softmax: f32 scores in, bf16 probs out ----------------
template <int LL>
__global__ void softmax_bf(const float* __restrict__ S, ushort_t* __restrict__ P) {
  constexpr int NE = (LL + 255) / 256;
  __shared__ float sh[4];
  ll row = blockIdx.x;
  const float* p = S + row * (ll)LL;
  ushort_t* q = P + row * (ll)LL;
  int t = threadIdx.x;
  float e[NE];
  float mx = -INFINITY;
#pragma unroll
  for (int k = 0; k < NE; ++k) {
    int i = t + k * 256;
    if (i < LL) { e[k] = p[i]; mx = fmaxf(mx, e[k]); }
  }
  mx = blk_reduce(mx, sh, 1);
  float sum = 0.f;
#pragma unroll
  for (int k = 0; k < NE; ++k) {
    int i = t + k * 256;
    if (i < LL) { e[k] = __expf(e[k] - mx); sum += e[k]; }
  }
  sum = blk_reduce(sum, sh, 0);
  float inv = 1.f / sum;
#pragma unroll
  for (int k = 0; k < NE; ++k) {
    int i = t + k * 256;
    if (i < LL) q[i] = rne1(e[k] * inv);
  }
}

// ---------------- LayerNorm over D=256; optional bf16 residual ----------------
__global__ void ln_kernel(const float* __restrict__ X, const ushort_t* __restrict__ RESb,
                          float* __restrict__ Yf, ushort_t* __restrict__ Yb, int postadd,
                          const float* __restrict__ gamma, const float* __restrict__ beta) {
  __shared__ float sh[4];
  ll row = blockIdx.x;
  int t = threadIdx.x;
  float r = RESb ? b2f(RESb[row * Dn + t]) : 0.f;
  float v = X[row * Dn + t] + r;
  float m = blk_reduce(v, sh, 0) * (1.f / (float)Dn);
  float d = v - m;
  float var = blk_reduce(d * d, sh, 0) * (1.f / (float)Dn);
  float y = d * rsqrtf(var + 1e-5f) * gamma[t] + beta[t];
  if (Yf) Yf[row * Dn + t] = y;
  if (Yb) Yb[row * Dn + t] = rne1(y + (postadd ? r : 0.f));
}

// ---------------- covariance column stats (f64 partials) ----------------
__global__ void colstat_partial(const float* __restrict__ X, double* __restrict__ part,
                                int nrows) {
  int blk = blockIdx.x, t = threadIdx.x;
  int chunk = CDIV(nrows, 256);
  int r0 = blk * chunk, r1 = min(nrows, r0 + chunk);
  double s = 0.0, q = 0.0;
  for (int r = r0; r < r1; ++r) {
    double v = (double)X[(ll)r * Dn + t];
    s += v; q += v * v;
  }
  part[blk * 512 + t] = s;
  part[blk * 512 + 256 + t] = q;
}

__global__ void colstat_final(const double* __restrict__ part, float* __restrict__ cmean,
                              float* __restrict__ cistd, int nrows) {
  int t = threadIdx.x;
  double s = 0.0, q = 0.0;
  for (int b = 0; b < 256; ++b) {
    s += part[b * 512 + t];
    q += part[b * 512 + 256 + t];
  }
  double m = s / (double)nrows;
  double var = (q - (double)nrows * m * m) / (double)(nrows - 1);
  var = fmax(var, 0.0);
  cmean[t] = (float)m;
  cistd[t] = (float)(1.0 / (sqrt(var) + 1e-5));
}

// -------- lower-triangle cov Gram: 64x64 f64 tiles, fused normalize ----------
// grid (10 lower 64-tiles, nz split-K). part[z][tile][64][64].
// Diag tiles stage one operand and reuse it (halves their fetch).
__global__ __launch_bounds__(256) void cov_gram(const float* __restrict__ X,
                                                const float* __restrict__ cmean,
                                                const float* __restrict__ cistd,
                                                double* __restrict__ part,
                                                int nr, int nz) {
  __shared__ double Am[32][66];
  __shared__ double Bq[32][66];
  __shared__ float cmA[64], ciA[64], cmB[64], ciB[64];
  int tile = blockIdx.x;
  int mi = 0;
  while (tile >= mi + 1) { tile -= mi + 1; ++mi; }
  int nj = tile;  // mi >= nj (4x4 blocks of 64)
  int m0 = mi * 64, n0 = nj * 64;
  bool diag = (mi == nj);
  int z = blockIdx.y;
  int t = threadIdx.x;
  int tx4 = (t & 15) * 4, ty4 = (t >> 4) * 4;
  if (t < 64) { cmA[t] = cmean[m0 + t]; ciA[t] = cistd[m0 + t]; }
  else if (t < 128) { cmB[t - 64] = cmean[n0 + t - 64]; ciB[t - 64] = cistd[n0 + t - 64]; }
  __syncthreads();
  int chunk = nr / nz;
  int kbeg = z * chunk, kend = kbeg + chunk;
  double acc[4][4] = {};
  const double* Bbase = diag ? &Am[0][0] : &Bq[0][0];
  for (int k0 = kbeg; k0 < kend; k0 += 32) {
#pragma unroll
    for (int e = 0; e < 8; ++e) {
      int idx = t + e * 256;
      int kk = idx >> 6, mm = idx & 63;
      float xa = X[(ll)(k0 + kk) * Dn + m0 + mm];
      Am[kk][mm] = (double)((xa - cmA[mm]) * ciA[mm]);
      if (!diag) {
        float xb = X[(ll)(k0 + kk) * Dn + n0 + mm];
        Bq[kk][mm] = (double)((xb - cmB[mm]) * ciB[mm]);
      }
    }
    __syncthreads();
#pragma unroll 4
    for (int kk = 0; kk < 32; ++kk) {
      double a[4], b[4];
#pragma unroll
      for (int q = 0; q < 4; ++q) a[q] = Am[kk][ty4 + q];
#pragma unroll
      for (int q = 0; q < 4; ++q) b[q] = Bbase[kk * 66 + tx4 + q];
#pragma unroll
      for (int i = 0; i < 4; ++i)
#pragma unroll
        for (int j = 0; j < 4; ++j) acc[i][j] += a[i] * b[j];
    }
    __syncthreads();
  }
  ll base = ((ll)z * 10 + blockIdx.x) * 4096;
#pragma unroll
  for (int i = 0; i < 4; ++i)
#pragma unroll
    for (int j = 0; j < 4; ++j)
      part[base + (ty4 + i) * 64 + tx4 + j] = acc[i][j];
}

// reduce split-K partials for the 10 lower 64-tiles
__global__ void cov_reduce(const double* __restrict__ part, double* __restrict__ Cd,
                           double inv, int nz) {
  int tile = blockIdx.x;
  int mi = 0;
  while (tile >= mi + 1) { tile -= mi + 1; ++mi; }
  int nj = tile;
  int t = threadIdx.x;
  for (int e = t; e < 4096; e += 256) {
    int rr = e >> 6, cc = e & 63;
    int m = mi * 64 + rr, n = nj * 64 + cc;
    double s = 0.0;
    for (int z = 0; z < nz; ++z) s += part[((ll)z * 10 + blockIdx.x) * 4096 + e];
    Cd[m * 256 + n] = s * inv + ((m == n) ? 1e-5 : 0.0);
  }
}

// -------- multi-launch right-looking f64 Cholesky, NB=64 panels --------------
// step A (3 blocks): factor 64x64 diag block in ONE wave via __shfl (lane t
// owns row t, upper zeroed), write per-panel logdet partial, then per-thread
// forward-substitution for up to 192 L21 rows. Diag never written back.
__global__ __launch_bounds__(256) void chol_a64(double* __restrict__ mats,
                                                double* __restrict__ ldp,
                                                int d0, int pidx) {
  double* A = mats + (ll)blockIdx.x * 65536;
  __shared__ double D[64][65];
  __shared__ double dinv[64];
  int t = threadIdx.x;
  for (int e = t; e < 4096; e += 256) {
    int i = e >> 6, j = e & 63;
    D[i][j] = (j <= i) ? A[(ll)(d0 + i) * 256 + d0 + j] : 0.0;
  }
  __syncthreads();
  if (t < 64) {
    double x[64];
#pragma unroll
    for (int j = 0; j < 64; ++j) x[j] = D[t][j];
#pragma unroll
    for (int k = 0; k < 64; ++k) {
      double piv = fmax(__shfl(x[k], k, 64), 1e-300);
      double inv = 1.0 / sqrt(piv);
      double lrk = x[k] * inv;  // lane t: l_{t,k}; lane k: d_k
      x[k] = lrk;
#pragma unroll
      for (int j = k + 1; j < 64; ++j) x[j] -= lrk * __shfl(lrk, j, 64);
    }
#pragma unroll
    for (int j = 0; j < 64; ++j) D[t][j] = x[j];
    dinv[t] = 1.0 / x[t];
    double lg = log(x[t]);
#pragma unroll
    for (int off = 32; off > 0; off >>= 1) lg += __shfl_down(lg, off, 64);
    if (t == 0) ldp[blockIdx.x * 4 + pidx] = 2.0 * lg;
  }
  __syncthreads();
  int rows = 256 - d0 - 64;
  if (t < rows) {
    int r = d0 + 64 + t;
    double y[64];
#pragma unroll
    for (int j = 0; j < 64; ++j) y[j] = A[(ll)r * 256 + d0 + j];
#pragma unroll
    for (int j = 0; j < 64; ++j) {
      double s = y[j];
#pragma unroll
      for (int i = 0; i < j; ++i) s -= y[i] * D[j][i];
      y[j] = s * dinv[j];
    }
#pragma unroll
    for (int j = 0; j < 64; ++j) A[(ll)r * 256 + d0 + j] = y[j];
  }
}

// step B (grid-parallel SYRK): trailing A22 -= L21 L21^T over 32x32 tiles,
// K=64 in two 32-chunks, lower half only.
__global__ __launch_bounds__(256) void chol_b64(double* __restrict__ mats, int d0) {
  double* A = mats + (ll)blockIdx.y * 65536;
  int tile = blockIdx.x;
  int i = 0;
  while (tile >= i + 1) { tile -= i + 1; ++i; }
  int j = tile;  // i >= j
  int ri = d0 + 64 + i * 32, rj = d0 + 64 + j * 32;
  __shared__ double Li[32][33];
  __shared__ double Lj[32][33];
  int t = threadIdx.x;
  double acc[4] = {0.0, 0.0, 0.0, 0.0};
  for (int kc = 0; kc < 64; kc += 32) {
    for (int e = t; e < 1024; e += 256) {
      int rr = e >> 5, kk = e & 31;
      Li[rr][kk] = A[(ll)(ri + rr) * 256 + d0 + kc + kk];
      Lj[rr][kk] = A[(ll)(rj + rr) * 256 + d0 + kc + kk];
    }
    __syncthreads();
#pragma unroll
    for (int e4 = 0; e4 < 4; ++e4) {
      int e = t + e4 * 256;
      int rr = e >> 5, cc = e & 31;
      double s = 0.0;
#pragma unroll
      for (int k = 0; k < 32; ++k) s += Li[rr][k] * Lj[cc][k];
      acc[e4] += s;
    }
    __syncthreads();
  }
#pragma unroll
  for (int e4 = 0; e4 < 4; ++e4) {
    int e = t + e4 * 256;
    int rr = e >> 5, cc = e & 31;
    A[(ll)(ri + rr) * 256 + rj + cc] -= acc[e4];
  }
}

__global__ void cov_final(const double* __restrict__ ldp, float* __restrict__ outp) {
  double s = 0.0;
  for (int i = 0; i < 12; ++i) s += ldp[i];
  outp[0] = (float)(-0.1 / (3.0 * 256.0) * s);
}

// ---------------- output head: xph[M][256] @ outT[96][256]^T, scatter+denorm --
__global__ __launch_bounds__(256) void out_mfma(
    const ushort_t* __restrict__ A, const ushort_t* __restrict__ B,
    const float* __restrict__ bias, const float* __restrict__ stdev,
    const float* __restrict__ mean, float* __restrict__ out) {
  constexpr int M = Bn * Cn, N = Pn, K = Dn;
  __shared__ ushort_t lds_ab[2][128][32];
  int t = threadIdx.x;
  int m0 = blockIdx.y * 128;
  int w = t >> 6, lane = t & 63;
  int wm = (w >> 1) * 64, wn = (w & 1) * 64;
  int lrow = lane & 15, kq = lane >> 4;
  int srow = lane >> 2, skcol = (lane & 3) * 8;
  f32x4 acc[4][4] = {};
  for (int k0 = 0; k0 < K; k0 += 32) {
#pragma unroll
    for (int cc = 0; cc < 4; ++cc) {
      int c = w * 4 + cc;
      int tile = c >> 3, rb = (c & 7) * 16;
      int row = rb + srow;
      const ushort_t* src;
      if (tile == 0) {
        src = &A[(ll)(m0 + row) * K + k0 + skcol];
      } else {
        int gn = min(row, N - 1);
        src = &B[(ll)gn * K + k0 + skcol];
      }
      gl_lds16(src, &lds_ab[tile][rb][0]);
    }
    __syncthreads();
    bf16x8 af[4], bfr[4];
#pragma unroll
    for (int i = 0; i < 4; ++i)
      af[i] = *reinterpret_cast<const bf16x8*>(&lds_ab[0][wm + i * 16 + lrow][kq * 8]);
#pragma unroll
    for (int j = 0; j < 4; ++j)
      bfr[j] = *reinterpret_cast<const bf16x8*>(&lds_ab[1][wn + j * 16 + lrow][kq * 8]);
#pragma unroll
    for (int i = 0; i < 4; ++i)
#pragma unroll
      for (int j = 0; j < 4; ++j)
        acc[i][j] = __builtin_amdgcn_mfma_f32_16x16x32_bf16(af[i], bfr[j],
                                                            acc[i][j], 0, 0, 0);
    __syncthreads();
  }
#pragma unroll
  for (int i = 0; i < 4; ++i) {
    int mb = m0 + wm + i * 16 + kq * 4;
#pragma unroll
    for (int j = 0; j < 4; ++j) {
      int p = wn + j * 16 + lrow;
      if (p >= N) continue;
      float bv = bias[p];
#pragma unroll
      for (int reg = 0; reg < 4; ++reg) {
        int m = mb + reg;
        int b = m >> 11, c = m & 2047;
        float v = acc[i][j][reg] + bv;
        out[((ll)(b * Pn + p)) * Cn + c] = v * stdev[m] + mean[m];
      }
    }
  }
}

// =====================================================================
extern "C" void kernel_launch(void* const* d_in, const int* in_sizes, int n_in,
                              void* d_out, int out_size, void* d_ws, size_t ws_size,
                              hipStream_t stream) {
  (void)in_sizes; (void)n_in; (void)out_size; (void)ws_size;
  const float* x_enc = (const float*)d_in[0];
  const float* in_w = (const float*)d_in[4];
  const float* in_b = (const float*)d_in[5];
  const float* lq[3] = {(const float*)d_in[6], (const float*)d_in[7],
                        (const float*)d_in[8]};
  const float* down_w = (const float*)d_in[9];
  const float* down_b = (const float*)d_in[10];
  const float* down_ln = (const float*)d_in[11];
  const float* pred_w = (const float*)d_in[12];
  const float* pred_b = (const float*)d_in[13];
  const float* up_w = (const float*)d_in[14];
  const float* up_b = (const float*)d_in[15];
  const float* up_ln = (const float*)d_in[16];
  const float* out_w = (const float*)d_in[17];
  const float* out_b = (const float*)d_in[18];
  float* out = (float*)d_out;

  float* ws = (float*)d_ws;
  size_t off = 0;
  auto alloc = [&](size_t n) {
    n = (n + 3) & ~(size_t)3;  // 16B alignment
    float* p = ws + off;
    off += n;
    return p;
  };
  float* mean = alloc((size_t)Bn * Cn);
  float* stdevv = alloc((size_t)Bn * Cn);
  float* cmean = alloc(256);
  float* cistd = alloc(256);
  double* part = (double*)alloc(256 * 512 * 2);
  double* ld = (double*)alloc(32);
  double* covd = (double*)alloc(3 * 65536 * 2);
  float* s1 = alloc((size_t)Bn * 512 * Dn);
  float* s2 = alloc((size_t)Bn * 128 * Dn);
  float* s3 = alloc((size_t)Bn * 32 * Dn);
  float* attn = alloc((size_t)Bn * 512 * 2048);     // f32 scores; also xnT(bf16)
  float* sbuf = alloc((size_t)16777216);            // attn_bf / o2 f32 / covpart
  ushort_t* h_bf = (ushort_t*)alloc((size_t)Bn * Cn * Dn / 2);
  ushort_t* s1b = (ushort_t*)alloc((size_t)Bn * 512 * Dn / 2);
  ushort_t* s2b = (ushort_t*)alloc((size_t)Bn * 128 * Dn / 2);
  ushort_t* s3b = (ushort_t*)alloc((size_t)Bn * 32 * Dn / 2);
  ushort_t* xpb = (ushort_t*)alloc((size_t)Bn * 32 * Dn / 2);
  ushort_t* xu0b = (ushort_t*)alloc((size_t)Bn * 128 * Dn / 2);
  ushort_t* xu1b = (ushort_t*)alloc((size_t)Bn * 512 * Dn / 2);
  ushort_t* qd_b = (ushort_t*)alloc(512 * 256 / 2);
  ushort_t* lqb0 = (ushort_t*)alloc(512 * 256 / 2);
  ushort_t* lqb1 = (ushort_t*)alloc(128 * 256 / 2);
  ushort_t* lqb2 = (ushort_t*)alloc(32 * 256 / 2);
  ushort_t* in_wT = (ushort_t*)alloc(256 * SnP / 2);
  ushort_t* downT = (ushort_t*)alloc(12 * 65536 / 2);
  ushort_t* upT = (ushort_t*)alloc(12 * 65536 / 2);
  ushort_t* predT = (ushort_t*)alloc(65536 / 2);
  ushort_t* outT = (ushort_t*)alloc(96 * 256 / 2);
  ushort_t* q_bf = (ushort_t*)alloc((size_t)Bn * 2048 * Dn / 2);  // also o1, xph
  ushort_t* k_bf = (ushort_t*)alloc((size_t)Bn * 2048 * Dn / 2);
  ushort_t* vT = (ushort_t*)alloc((size_t)Bn * 2048 * Dn / 2);

  ushort_t* xnT = (ushort_t*)attn;
  ushort_t* attn_b = (ushort_t*)sbuf;
  float* o2 = sbuf;
  double* covpart = (double*)sbuf;
  const float scale = 0.0625f;
  const float* npf = nullptr;

  // ---- prep: stats, normalize+transpose input, weight converts ----
  instnorm_stats<<<dim3(Cn / 256, Bn), 256, 0, stream>>>(x_enc, mean, stdevv);
  normT_kernel<<<dim3(Cn / 32, SnP / 32, Bn), 256, 0, stream>>>(x_enc, xnT, mean,
                                                                stdevv);
  cvtT_kernel<<<dim3(8, 8, 12), 256, 0, stream>>>(down_w, downT, 256, 256, 256);
  cvtT_kernel<<<dim3(8, 8, 12), 256, 0, stream>>>(up_w, upT, 256, 256, 256);
  cvtT_kernel<<<dim3(8, 8, 1), 256, 0, stream>>>(pred_w, predT, 256, 256, 256);
  cvtT_kernel<<<dim3(8, SnP / 32, 1), 256, 0, stream>>>(in_w, in_wT, Sn, 256, SnP);
  cvtT_kernel<<<dim3(3, 8, 1), 256, 0, stream>>>(out_w, outT, 256, Pn, 256);
  cvt_bf<<<512, 256, 0, stream>>>(lq[0], lqb0, 512 * 256);
  cvt_bf<<<128, 256, 0, stream>>>(lq[1], lqb1, 128 * 256);
  cvt_bf<<<32, 256, 0, stream>>>(lq[2], lqb2, 32 * 256);

  // ---- h = xn^T @ in_w + b : bf16 out (K padded to 736) ----
  gemm_bf<2><<<dim3(2, 16, Bn), 256, 0, stream>>>(
      xnT, in_wT, Cn, Dn, SnP, SnP, SnP, (ll)Cn * SnP, 0, in_b, 1.f,
      nullptr, 0, 0, h_bf, Dn, (ll)Cn * Dn);

  ushort_t* lqb[3] = {lqb0, lqb1, lqb2};
  float* skf[3] = {s1, s2, s3};
  ushort_t* skb[3] = {s1b, s2b, s3b};
  int Ls[4] = {2048, 512, 128, 32};
  const ushort_t* xinb = h_bf;

  // ---------------- down layers ----------------
  for (int i = 0; i < 3; ++i) {
    int L = Ls[i], Lq = Ls[i + 1];
    const ushort_t* WqT = downT + (size_t)(i * 4 + 0) * 65536;
    const ushort_t* WkT = downT + (size_t)(i * 4 + 1) * 65536;
    const ushort_t* WvT = downT + (size_t)(i * 4 + 2) * 65536;
    const ushort_t* WoT = downT + (size_t)(i * 4 + 3) * 65536;
    const float* bq = down_b + (i * 4 + 0) * 256;
    const float* bk = down_b + (i * 4 + 1) * 256;
    const float* bv = down_b + (i * 4 + 2) * 256;
    const float* bo = down_b + (i * 4 + 3) * 256;

    gemm_bf<2><<<dim3(2, CDIV(Lq, 128), 1), 256, 0, stream>>>(
        lqb[i], WqT, Lq, Dn, Dn, Dn, Dn, 0, 0, bq, 1.f, nullptr, 0, 0, qd_b, Dn, 0);
    gemm_bf<2><<<dim3(2, (Bn * L) / 128, 1), 256, 0, stream>>>(
        xinb, WkT, Bn * L, Dn, Dn, Dn, Dn, 0, 0, bk, 1.f, nullptr, 0, 0, k_bf, Dn, 0);
    gemm_bf<4><<<dim3(2, L / 128, Bn), 256, 0, stream>>>(
        xinb, WvT, L, Dn, Dn, Dn, Dn, (ll)L * Dn, 0, bv, 1.f, nullptr, 0, 0,
        vT, L, (ll)Dn * L);
    gemm_bf<1><<<dim3(L / 128, CDIV(Lq, 128), Bn), 256, 0, stream>>>(
        qd_b, k_bf, Lq, L, Dn, Dn, Dn, 0, (ll)L * Dn, npf, scale,
        attn, L, (ll)Lq * L, nullptr, 0, 0);
    if (L == 2048) softmax_bf<2048><<<Bn * Lq, 256, 0, stream>>>(attn, attn_b);
    else if (L == 512) softmax_bf<512><<<Bn * Lq, 256, 0, stream>>>(attn, attn_b);
    else softmax_bf<128><<<Bn * Lq, 256, 0, stream>>>(attn, attn_b);
    gemm_bf<2><<<dim3(2, CDIV(Lq, 128), Bn), 256, 0, stream>>>(
        attn_b, vT, Lq, Dn, L, L, L, (ll)Lq * L, (ll)Dn * L, npf, 1.f,
        nullptr, 0, 0, q_bf, Dn, (ll)Lq * Dn);
    gemm_bf<1><<<dim3(2, CDIV(Bn * Lq, 128), 1), 256, 0, stream>>>(
        q_bf, WoT, Bn * Lq, Dn, Dn, Dn, Dn, 0, 0, bo, 1.f, o2, Dn, 0, nullptr, 0, 0);
    ln_kernel<<<Bn * Lq, 256, 0, stream>>>(o2, nullptr, skf[i], skb[i], 0,
                                           down_ln + (i * 2 + 0) * 256,
                                           down_ln + (i * 2 + 1) * 256);
    xinb = skb[i];
  }

  // ------- covariance loss (64-tile lower-tri Gram + NB=64 Cholesky) ---------
  int nrs[3] = {Bn * 512, Bn * 128, Bn * 32};
  int nzs[3] = {64, 32, 16};
  for (int j = 0; j < 3; ++j) {
    int nr = nrs[j];
    colstat_partial<<<256, 256, 0, stream>>>(skf[j], part, nr);
    colstat_final<<<1, 256, 0, stream>>>(part, cmean, cistd, nr);
    cov_gram<<<dim3(10, nzs[j]), 256, 0, stream>>>(skf[j], cmean, cistd, covpart,
                                                   nr, nzs[j]);
    cov_reduce<<<10, 256, 0, stream>>>(covpart, covd + (size_t)j * 65536,
                                       1.0 / (double)(nr - 1), nzs[j]);
  }
  for (int kb = 0; kb < 4; ++kb) {
    chol_a64<<<3, 256, 0, stream>>>(covd, ld, kb * 64, kb);
    int T32 = 6 - 2 * kb;
    if (T32 > 0)
      chol_b64<<<dim3(T32 * (T32 + 1) / 2, 3), 256, 0, stream>>>(covd, kb * 64);
  }
  cov_final<<<1, 1, 0, stream>>>(ld, out + 6291456);

  // ---------------- pred head ----------------
  gemm_bf<2><<<dim3(2, 8, 1), 256, 0, stream>>>(
      s3b, predT, Bn * 32, Dn, Dn, Dn, Dn, 0, 0, pred_b, 1.f,
      nullptr, 0, 0, xpb, Dn, 0);

  // ---------------- up layers ----------------
  int Lks[3] = {32, 128, 512}, Lqs[3] = {128, 512, 2048};
  const ushort_t* qinb[3] = {s2b, s1b, h_bf};
  const ushort_t* xinbs[3] = {xpb, xu0b, xu1b};
  ushort_t* xoutb[3] = {xu0b, xu1b, q_bf};  // final writes xph into q_bf
  for (int i = 0; i < 3; ++i) {
    int Lk = Lks[i], Lq = Lqs[i];
    const ushort_t* WqT = upT + (size_t)(i * 4 + 0) * 65536;
    const ushort_t* WkT = upT + (size_t)(i * 4 + 1) * 65536;
    const ushort_t* WvT = upT + (size_t)(i * 4 + 2) * 65536;
    const ushort_t* WoT = upT + (size_t)(i * 4 + 3) * 65536;
    const float* bq = up_b + (i * 4 + 0) * 256;
    const float* bk = up_b + (i * 4 + 1) * 256;
    const float* bv = up_b + (i * 4 + 2) * 256;
    const float* bo = up_b + (i * 4 + 3) * 256;

    gemm_bf<2><<<dim3(2, (Bn * Lq) / 128, 1), 256, 0, stream>>>(
        qinb[i], WqT, Bn * Lq, Dn, Dn, Dn, Dn, 0, 0, bq, 1.f,
        nullptr, 0, 0, q_bf, Dn, 0);
    gemm_bf<2><<<dim3(2, CDIV(Bn * Lk, 128), 1), 256, 0, stream>>>(
        xinbs[i], WkT, Bn * Lk, Dn, Dn, Dn, Dn, 0, 0, bk, 1.f,
        nullptr, 0, 0, k_bf, Dn, 0);
    gemm_bf<4><<<dim3(2, CDIV(Lk, 128), Bn), 256, 0, stream>>>(
        xinbs[i], WvT, Lk, Dn, Dn, Dn, Dn, (ll)Lk * Dn, 0, bv, 1.f,
        nullptr, 0, 0, vT, Lk, (ll)Dn * Lk);
    gemm_bf<1><<<dim3(CDIV(Lk, 128), CDIV(Lq, 128), Bn), 256, 0, stream>>>(
        q_bf, k_bf, Lq, Lk, Dn, Dn, Dn, (ll)Lq * Dn, (ll)Lk * Dn, npf, scale,
        attn, Lk, (ll)Lq * Lk, nullptr, 0, 0);
    if (Lk == 32) softmax_bf<32><<<Bn * Lq, 256, 0, stream>>>(attn, attn_b);
    else if (Lk == 128) softmax_bf<128><<<Bn * Lq, 256, 0, stream>>>(attn, attn_b);
    else softmax_bf<512><<<Bn * Lq, 256, 0, stream>>>(attn, attn_b);
    gemm_bf<2><<<dim3(2, CDIV(Lq, 128), Bn), 256, 0, stream>>>(
        attn_b, vT, Lq, Dn, Lk, Lk, Lk, (ll)Lq * Lk, (ll)Dn * Lk, npf, 1.f,
        nullptr, 0, 0, q_bf, Dn, (ll)Lq * Dn);
    gemm_bf<1><<<dim3(2, (Bn * Lq) / 128, 1), 256, 0, stream>>>(
        q_bf, WoT, Bn * Lq, Dn, Dn, Dn, Dn, 0, 0, bo, 1.f, o2, Dn, 0, nullptr, 0, 0);
    ln_kernel<<<Bn * Lq, 256, 0, stream>>>(o2, qinb[i], nullptr, xoutb[i],
                                           (i == 2) ? 1 : 0,
                                           up_ln + (i * 2 + 0) * 256,
                                           up_ln + (i * 2 + 1) * 256);
  }

  // ---------------- output head: MFMA + transpose + de-norm ----------------
  out_mfma<<<dim3(1, (Bn * Cn) / 128, 1), 256, 0, stream>>>(q_bf, outT, out_b,
                                                            stdevv, mean, out);
}

// Round 12
// 2256.861 us; speedup vs baseline: 1.1710x; 1.1710x over previous
//
#include <hip/hip_runtime.h>
#include <hip/hip_bf16.h>
#include <math.h>

#define CDIV(a, b) (((a) + (b) - 1) / (b))
typedef long long ll;
typedef unsigned short ushort_t;

constexpr int Bn = 32;    // batch
constexpr int Sn = 720;   // seq len
constexpr int SnP = 736;  // seq len padded to K-step multiple
constexpr int Cn = 2048;  // channels (tokens after transpose)
constexpr int Dn = 256;   // d_model
constexpr int Pn = 96;    // pred len

typedef __attribute__((ext_vector_type(8))) short bf16x8;
typedef __attribute__((ext_vector_type(4))) float f32x4;

__device__ inline ushort_t rne1(float x) {
  unsigned u = __float_as_uint(x);
  u = (u + 0x7fffu + ((u >> 16) & 1u)) >> 16;
  return (ushort_t)u;
}
__device__ inline float b2f(ushort_t u) { return __uint_as_float(((unsigned)u) << 16); }

__device__ inline void gl_lds16(const void* g, void* l) {
  __builtin_amdgcn_global_load_lds(
      (const __attribute__((address_space(1))) void*)g,
      (__attribute__((address_space(3))) void*)l, 16, 0, 0);
}

// ---------------- instance norm stats over time axis ----------------
__global__ void instnorm_stats(const float* __restrict__ x,
                               float* __restrict__ mean, float* __restrict__ stdev) {
  int c = blockIdx.x * 256 + threadIdx.x;
  int b = blockIdx.y;
  const float* p = x + (ll)b * Sn * Cn + c;
  float s = 0.f, q = 0.f;
  for (int t = 0; t < Sn; ++t) {
    float v = p[(ll)t * Cn];
    s += v; q += v * v;
  }
  float m = s / (float)Sn;
  float var = q / (float)Sn - m * m;
  var = fmaxf(var, 0.f);
  mean[b * Cn + c] = m;
  stdev[b * Cn + c] = sqrtf(var + 1e-5f);
}

// ---------------- normalize + transpose: x[b][s][c] -> xnT[b][c][s] bf16 (K-pad)
__global__ void normT_kernel(const float* __restrict__ X, ushort_t* __restrict__ D,
                             const float* __restrict__ mean,
                             const float* __restrict__ stdev) {
  int b = blockIdx.z;
  __shared__ float tl[32][33];
  int t = threadIdx.x;
  int tx = t & 31, ty = t >> 5;
  int s0 = blockIdx.y * 32, c0 = blockIdx.x * 32;
#pragma unroll
  for (int e = 0; e < 4; ++e) {
    int s = s0 + ty + 8 * e;
    tl[ty + 8 * e][tx] = (s < Sn) ? X[((ll)b * Sn + s) * Cn + c0 + tx] : 0.f;
  }
  __syncthreads();
#pragma unroll
  for (int e = 0; e < 4; ++e) {
    int c = c0 + ty + 8 * e, s = s0 + tx;
    if (s < SnP) {
      float mu = mean[b * Cn + c], sd = stdev[b * Cn + c];
      float v = (s < Sn) ? (tl[tx][ty + 8 * e] - mu) / sd : 0.f;
      D[((ll)b * Cn + c) * SnP + s] = rne1(v);
    }
  }
}

// ---------------- transpose-convert: W[K][N] f32 -> WT[N][KP] bf16 ------------
__global__ void cvtT_kernel(const float* __restrict__ S, ushort_t* __restrict__ D,
                            int K, int N, int KP) {
  int z = blockIdx.z;
  S += (ll)z * K * N;
  D += (ll)z * N * KP;
  __shared__ float tl[32][33];
  int t = threadIdx.x;
  int tx = t & 31, ty = t >> 5;
  int k0 = blockIdx.y * 32, n0 = blockIdx.x * 32;
#pragma unroll
  for (int e = 0; e < 4; ++e) {
    int k = k0 + ty + 8 * e;
    tl[ty + 8 * e][tx] = (k < K && n0 + tx < N) ? S[(ll)k * N + n0 + tx] : 0.f;
  }
  __syncthreads();
#pragma unroll
  for (int e = 0; e < 4; ++e) {
    int n = n0 + ty + 8 * e, kk = k0 + tx;
    if (n < N && kk < KP) D[(ll)n * KP + kk] = rne1(tl[tx][ty + 8 * e]);
  }
}

__global__ void cvt_bf(const float* __restrict__ S, ushort_t* __restrict__ D, int n) {
  int i = blockIdx.x * 256 + threadIdx.x;
  if (i < n) D[i] = rne1(S[i]);
}

// ---------------- canonical bf16 MFMA GEMM: C = A[M][K] * B[N][K]^T ----------
// global_load_lds staging; K must be a multiple of 32; OOB rows clamped.
// MODE bits: 1 = write f32 C (ldcf), 2 = write bf16 C (ldcb), 4 = write bf16 C^T
template <int MODE>
__global__ __launch_bounds__(256) void gemm_bf(
    const ushort_t* __restrict__ A, const ushort_t* __restrict__ B,
    int M, int N, int K, int lda, int ldb, ll sA, ll sB,
    const float* __restrict__ bias, float alpha,
    float* __restrict__ Cf, int ldcf, ll sCf,
    ushort_t* __restrict__ Cb, int ldcb, ll sCb) {
  int g = blockIdx.z;
  A += (ll)g * sA;
  B += (ll)g * sB;
  if (MODE & 1) Cf += (ll)g * sCf;
  if (MODE & 6) Cb += (ll)g * sCb;
  __shared__ ushort_t lds_ab[2][128][32];
  int t = threadIdx.x;
  int m0 = blockIdx.y * 128, n0 = blockIdx.x * 128;
  int w = t >> 6, lane = t & 63;
  int wm = (w >> 1) * 64, wn = (w & 1) * 64;
  int lrow = lane & 15, kq = lane >> 4;
  int srow = lane >> 2, skcol = (lane & 3) * 8;
  f32x4 acc[4][4] = {};
  for (int k0 = 0; k0 < K; k0 += 32) {
#pragma unroll
    for (int cc = 0; cc < 4; ++cc) {
      int c = w * 4 + cc;
      int tile = c >> 3, rb = (c & 7) * 16;
      int row = rb + srow;
      const ushort_t* src;
      if (tile == 0) {
        int gm = min(m0 + row, M - 1);
        src = &A[(ll)gm * lda + k0 + skcol];
      } else {
        int gn = min(n0 + row, N - 1);
        src = &B[(ll)gn * ldb + k0 + skcol];
      }
      gl_lds16(src, &lds_ab[tile][rb][0]);
    }
    __syncthreads();
    bf16x8 af[4], bfr[4];
#pragma unroll
    for (int i = 0; i < 4; ++i)
      af[i] = *reinterpret_cast<const bf16x8*>(&lds_ab[0][wm + i * 16 + lrow][kq * 8]);
#pragma unroll
    for (int j = 0; j < 4; ++j)
      bfr[j] = *reinterpret_cast<const bf16x8*>(&lds_ab[1][wn + j * 16 + lrow][kq * 8]);
#pragma unroll
    for (int i = 0; i < 4; ++i)
#pragma unroll
      for (int j = 0; j < 4; ++j)
        acc[i][j] = __builtin_amdgcn_mfma_f32_16x16x32_bf16(af[i], bfr[j],
                                                            acc[i][j], 0, 0, 0);
    __syncthreads();
  }
#pragma unroll
  for (int i = 0; i < 4; ++i) {
    int mb = m0 + wm + i * 16 + kq * 4;
    if (mb >= M) continue;
#pragma unroll
    for (int j = 0; j < 4; ++j) {
      int c = n0 + wn + j * 16 + lrow;
      if (c >= N) continue;
      float bv = bias ? bias[c] : 0.f;
#pragma unroll
      for (int reg = 0; reg < 4; ++reg) {
        int m = mb + reg;
        float v = acc[i][j][reg] * alpha + bv;
        if (MODE & 1) Cf[(ll)m * ldcf + c] = v;
        if (MODE & 2) Cb[(ll)m * ldcb + c] = rne1(v);
        if (MODE & 4) Cb[(ll)c * ldcb + m] = rne1(v);
      }
    }
  }
}

// ---------------- block reduction helper (blockDim = 256) ----------------
__device__ inline float blk_reduce(float v, volatile float* sh, int op) {
  int lane = threadIdx.x & 63, w = threadIdx.x >> 6;
#pragma unroll
  for (int off = 32; off > 0; off >>= 1) {
    float o = __shfl_down(v, off, 64);
    v = op ? fmaxf(v, o) : (v + o);
  }
  __syncthreads();
  if (lane == 0) sh[w] = v;
  __syncthreads();
  float r = op ? fmaxf(fmaxf(sh[0], sh[1]), fmaxf(sh[2], sh[3]))
               : (sh[0] + sh[1] + sh[2] + sh[3]);
  return r;
}

// ---------------- row softmax: f32 scores in, bf16 probs out ----------------
template <int LL>
__global__ void softmax_bf(const float* __restrict__ S, ushort_t* __restrict__ P) {
  constexpr int NE = (LL + 255) / 256;
  __shared__ float sh[4];
  ll row = blockIdx.x;
  const float* p = S + row * (ll)LL;
  ushort_t* q = P + row * (ll)LL;
  int t = threadIdx.x;
  float e[NE];
  float mx = -INFINITY;
#pragma unroll
  for (int k = 0; k < NE; ++k) {
    int i = t + k * 256;
    if (i < LL) { e[k] = p[i]; mx = fmaxf(mx, e[k]); }
  }
  mx = blk_reduce(mx, sh, 1);
  float sum = 0.f;
#pragma unroll
  for (int k = 0; k < NE; ++k) {
    int i = t + k * 256;
    if (i < LL) { e[k] = __expf(e[k] - mx); sum += e[k]; }
  }
  sum = blk_reduce(sum, sh, 0);
  float inv = 1.f / sum;
#pragma unroll
  for (int k = 0; k < NE; ++k) {
    int i = t + k * 256;
    if (i < LL) q[i] = rne1(e[k] * inv);
  }
}

// ---------------- LayerNorm over D=256; optional bf16 residual ----------------
__global__ void ln_kernel(const float* __restrict__ X, const ushort_t* __restrict__ RESb,
                          float* __restrict__ Yf, ushort_t* __restrict__ Yb, int postadd,
                          const float* __restrict__ gamma, const float* __restrict__ beta) {
  __shared__ float sh[4];
  ll row = blockIdx.x;
  int t = threadIdx.x;
  float r = RESb ? b2f(RESb[row * Dn + t]) : 0.f;
  float v = X[row * Dn + t] + r;
  float m = blk_reduce(v, sh, 0) * (1.f / (float)Dn);
  float d = v - m;
  float var = blk_reduce(d * d, sh, 0) * (1.f / (float)Dn);
  float y = d * rsqrtf(var + 1e-5f) * gamma[t] + beta[t];
  if (Yf) Yf[row * Dn + t] = y;
  if (Yb) Yb[row * Dn + t] = rne1(y + (postadd ? r : 0.f));
}

// ---------------- covariance column stats (f64 partials) ----------------
__global__ void colstat_partial(const float* __restrict__ X, double* __restrict__ part,
                                int nrows) {
  int blk = blockIdx.x, t = threadIdx.x;
  int chunk = CDIV(nrows, 256);
  int r0 = blk * chunk, r1 = min(nrows, r0 + chunk);
  double s = 0.0, q = 0.0;
  for (int r = r0; r < r1; ++r) {
    double v = (double)X[(ll)r * Dn + t];
    s += v; q += v * v;
  }
  part[blk * 512 + t] = s;
  part[blk * 512 + 256 + t] = q;
}

__global__ void colstat_final(const double* __restrict__ part, float* __restrict__ cmean,
                              float* __restrict__ cistd, int nrows) {
  int t = threadIdx.x;
  double s = 0.0, q = 0.0;
  for (int b = 0; b < 256; ++b) {
    s += part[b * 512 + t];
    q += part[b * 512 + 256 + t];
  }
  double m = s / (double)nrows;
  double var = (q - (double)nrows * m * m) / (double)(nrows - 1);
  var = fmax(var, 0.0);
  cmean[t] = (float)m;
  cistd[t] = (float)(1.0 / (sqrt(var) + 1e-5));
}

// -------- lower-triangle cov Gram: 64x64 f64 tiles, fused normalize ----------
__global__ __launch_bounds__(256) void cov_gram(const float* __restrict__ X,
                                                const float* __restrict__ cmean,
                                                const float* __restrict__ cistd,
                                                double* __restrict__ part,
                                                int nr, int nz) {
  __shared__ double Am[32][66];
  __shared__ double Bq[32][66];
  __shared__ float cmA[64], ciA[64], cmB[64], ciB[64];
  int tile = blockIdx.x;
  int mi = 0;
  while (tile >= mi + 1) { tile -= mi + 1; ++mi; }
  int nj = tile;  // mi >= nj (4x4 blocks of 64)
  int m0 = mi * 64, n0 = nj * 64;
  bool diag = (mi == nj);
  int z = blockIdx.y;
  int t = threadIdx.x;
  int tx4 = (t & 15) * 4, ty4 = (t >> 4) * 4;
  if (t < 64) { cmA[t] = cmean[m0 + t]; ciA[t] = cistd[m0 + t]; }
  else if (t < 128) { cmB[t - 64] = cmean[n0 + t - 64]; ciB[t - 64] = cistd[n0 + t - 64]; }
  __syncthreads();
  int chunk = nr / nz;
  int kbeg = z * chunk, kend = kbeg + chunk;
  double acc[4][4] = {};
  const double* Bbase = diag ? &Am[0][0] : &Bq[0][0];
  for (int k0 = kbeg; k0 < kend; k0 += 32) {
#pragma unroll
    for (int e = 0; e < 8; ++e) {
      int idx = t + e * 256;
      int kk = idx >> 6, mm = idx & 63;
      float xa = X[(ll)(k0 + kk) * Dn + m0 + mm];
      Am[kk][mm] = (double)((xa - cmA[mm]) * ciA[mm]);
      if (!diag) {
        float xb = X[(ll)(k0 + kk) * Dn + n0 + mm];
        Bq[kk][mm] = (double)((xb - cmB[mm]) * ciB[mm]);
      }
    }
    __syncthreads();
#pragma unroll 4
    for (int kk = 0; kk < 32; ++kk) {
      double a[4], b[4];
#pragma unroll
      for (int q = 0; q < 4; ++q) a[q] = Am[kk][ty4 + q];
#pragma unroll
      for (int q = 0; q < 4; ++q) b[q] = Bbase[kk * 66 + tx4 + q];
#pragma unroll
      for (int i = 0; i < 4; ++i)
#pragma unroll
        for (int j = 0; j < 4; ++j) acc[i][j] += a[i] * b[j];
    }
    __syncthreads();
  }
  ll base = ((ll)z * 10 + blockIdx.x) * 4096;
#pragma unroll
  for (int i = 0; i < 4; ++i)
#pragma unroll
    for (int j = 0; j < 4; ++j)
      part[base + (ty4 + i) * 64 + tx4 + j] = acc[i][j];
}

// reduce split-K partials for the 10 lower 64-tiles
__global__ void cov_reduce(const double* __restrict__ part, double* __restrict__ Cd,
                           double inv, int nz) {
  int tile = blockIdx.x;
  int mi = 0;
  while (tile >= mi + 1) { tile -= mi + 1; ++mi; }
  int nj = tile;
  int t = threadIdx.x;
  for (int e = t; e < 4096; e += 256) {
    int rr = e >> 6, cc = e & 63;
    int m = mi * 64 + rr, n = nj * 64 + cc;
    double s = 0.0;
    for (int z = 0; z < nz; ++z) s += part[((ll)z * 10 + blockIdx.x) * 4096 + e];
    Cd[m * 256 + n] = s * inv + ((m == n) ? 1e-5 : 0.0);
  }
}

// ---------------- multi-launch right-looking f64 Cholesky (NB=32) ------------
// step A (3 blocks): factor 32x32 diag block in-wave via __shfl (no barriers),
// then per-thread forward-substitution for up to 224 L21 rows. Register-fit.
__global__ __launch_bounds__(256) void chol_step_a(double* __restrict__ mats, int d0) {
  double* A = mats + (ll)blockIdx.x * 65536;
  __shared__ double D[32][33];
  __shared__ double dinv[32];
  int t = threadIdx.x;
  for (int e = t; e < 1024; e += 256) {
    int i = e >> 5, j = e & 31;
    D[i][j] = (j <= i) ? A[(ll)(d0 + i) * 256 + d0 + j] : 0.0;  // upper never computed
  }
  __syncthreads();
  if (t < 32) {
    double x[32];
#pragma unroll
    for (int j = 0; j < 32; ++j) x[j] = D[t][j];
#pragma unroll
    for (int k = 0; k < 32; ++k) {
      double piv = fmax(__shfl(x[k], k, 64), 1e-300);
      double inv = 1.0 / sqrt(piv);
      double lrk = x[k] * inv;  // lane t: l_{t,k}; lane k: d_k
      x[k] = lrk;
#pragma unroll
      for (int j = k + 1; j < 32; ++j) x[j] -= lrk * __shfl(lrk, j, 64);
    }
#pragma unroll
    for (int j = 0; j < 32; ++j) D[t][j] = x[j];
    dinv[t] = 1.0 / x[t];
  }
  __syncthreads();
  // L21 solve: thread t -> row d0+32+t ; y = L11^{-1} a_row
  int r = d0 + 32 + t;
  if (r < 256) {
    double y[32];
#pragma unroll
    for (int j = 0; j < 32; ++j) y[j] = A[(ll)r * 256 + d0 + j];
#pragma unroll
    for (int j = 0; j < 32; ++j) {
      double s = y[j];
#pragma unroll
      for (int i = 0; i < j; ++i) s -= y[i] * D[j][i];
      y[j] = s * dinv[j];
    }
#pragma unroll
    for (int j = 0; j < 32; ++j) A[(ll)r * 256 + d0 + j] = y[j];
  }
  // write factored diag block back (logdet_diag reads diagonal)
  for (int e = t; e < 1024; e += 256)
    A[(ll)(d0 + (e >> 5)) * 256 + d0 + (e & 31)] = D[e >> 5][e & 31];
}

// step B (grid-parallel SYRK): trailing A22 -= L21 L21^T, 32x32 tiles, lower half
__global__ __launch_bounds__(256) void chol_step_b(double* __restrict__ mats, int d0) {
  double* A = mats + (ll)blockIdx.y * 65536;
  int tile = blockIdx.x;
  int i = 0;
  while (tile >= i + 1) { tile -= i + 1; ++i; }
  int j = tile;  // i >= j
  int ri = d0 + 32 + i * 32, rj = d0 + 32 + j * 32;
  __shared__ double Li[32][33];
  __shared__ double Lj[32][33];
  int t = threadIdx.x;
  for (int e = t; e < 1024; e += 256) {
    int rr = e >> 5, kk = e & 31;
    Li[rr][kk] = A[(ll)(ri + rr) * 256 + d0 + kk];
    Lj[rr][kk] = A[(ll)(rj + rr) * 256 + d0 + kk];
  }
  __syncthreads();
  for (int e = t; e < 1024; e += 256) {
    int rr = e >> 5, cc = e & 31;
    double s = 0.0;
#pragma unroll
    for (int k = 0; k < 32; ++k) s += Li[rr][k] * Lj[cc][k];
    A[(ll)(ri + rr) * 256 + rj + cc] -= s;
  }
}

// logdet = 2 * sum log(diag(L)), parallel reduce
__global__ void logdet_diag(const double* __restrict__ mats, double* __restrict__ ld) {
  __shared__ double sh[4];
  const double* A = mats + (ll)blockIdx.x * 65536;
  int t = threadIdx.x;
  double lg = log(A[(ll)t * 257]);
  int lane = t & 63, w = t >> 6;
#pragma unroll
  for (int off = 32; off > 0; off >>= 1) lg += __shfl_down(lg, off, 64);
  if (lane == 0) sh[w] = lg;
  __syncthreads();
  if (t == 0) ld[blockIdx.x] = 2.0 * (sh[0] + sh[1] + sh[2] + sh[3]);
}

__global__ void cov_final(const double* __restrict__ ld, float* __restrict__ outp) {
  outp[0] = (float)(-0.1 / (3.0 * 256.0) * (ld[0] + ld[1] + ld[2]));
}

// ---------------- output head: xph[M][256] @ outT[96][256]^T, scatter+denorm --
__global__ __launch_bounds__(256) void out_mfma(
    const ushort_t* __restrict__ A, const ushort_t* __restrict__ B,
    const float* __restrict__ bias, const float* __restrict__ stdev,
    const float* __restrict__ mean, float* __restrict__ out) {
  constexpr int M = Bn * Cn, N = Pn, K = Dn;
  __shared__ ushort_t lds_ab[2][128][32];
  int t = threadIdx.x;
  int m0 = blockIdx.y * 128;
  int w = t >> 6, lane = t & 63;
  int wm = (w >> 1) * 64, wn = (w & 1) * 64;
  int lrow = lane & 15, kq = lane >> 4;
  int srow = lane >> 2, skcol = (lane & 3) * 8;
  f32x4 acc[4][4] = {};
  for (int k0 = 0; k0 < K; k0 += 32) {
#pragma unroll
    for (int cc = 0; cc < 4; ++cc) {
      int c = w * 4 + cc;
      int tile = c >> 3, rb = (c & 7) * 16;
      int row = rb + srow;
      const ushort_t* src;
      if (tile == 0) {
        src = &A[(ll)(m0 + row) * K + k0 + skcol];
      } else {
        int gn = min(row, N - 1);
        src = &B[(ll)gn * K + k0 + skcol];
      }
      gl_lds16(src, &lds_ab[tile][rb][0]);
    }
    __syncthreads();
    bf16x8 af[4], bfr[4];
#pragma unroll
    for (int i = 0; i < 4; ++i)
      af[i] = *reinterpret_cast<const bf16x8*>(&lds_ab[0][wm + i * 16 + lrow][kq * 8]);
#pragma unroll
    for (int j = 0; j < 4; ++j)
      bfr[j] = *reinterpret_cast<const bf16x8*>(&lds_ab[1][wn + j * 16 + lrow][kq * 8]);
#pragma unroll
    for (int i = 0; i < 4; ++i)
#pragma unroll
      for (int j = 0; j < 4; ++j)
        acc[i][j] = __builtin_amdgcn_mfma_f32_16x16x32_bf16(af[i], bfr[j],
                                                            acc[i][j], 0, 0, 0);
    __syncthreads();
  }
#pragma unroll
  for (int i = 0; i < 4; ++i) {
    int mb = m0 + wm + i * 16 + kq * 4;
#pragma unroll
    for (int j = 0; j < 4; ++j) {
      int p = wn + j * 16 + lrow;
      if (p >= N) continue;
      float bv = bias[p];
#pragma unroll
      for (int reg = 0; reg < 4; ++reg) {
        int m = mb + reg;
        int b = m >> 11, c = m & 2047;
        float v = acc[i][j][reg] + bv;
        out[((ll)(b * Pn + p)) * Cn + c] = v * stdev[m] + mean[m];
      }
    }
  }
}

// =====================================================================
extern "C" void kernel_launch(void* const* d_in, const int* in_sizes, int n_in,
                              void* d_out, int out_size, void* d_ws, size_t ws_size,
                              hipStream_t stream) {
  (void)in_sizes; (void)n_in; (void)out_size; (void)ws_size;
  const float* x_enc = (const float*)d_in[0];
  const float* in_w = (const float*)d_in[4];
  const float* in_b = (const float*)d_in[5];
  const float* lq[3] = {(const float*)d_in[6], (const float*)d_in[7],
                        (const float*)d_in[8]};
  const float* down_w = (const float*)d_in[9];
  const float* down_b = (const float*)d_in[10];
  const float* down_ln = (const float*)d_in[11];
  const float* pred_w = (const float*)d_in[12];
  const float* pred_b = (const float*)d_in[13];
  const float* up_w = (const float*)d_in[14];
  const float* up_b = (const float*)d_in[15];
  const float* up_ln = (const float*)d_in[16];
  const float* out_w = (const float*)d_in[17];
  const float* out_b = (const float*)d_in[18];
  float* out = (float*)d_out;

  float* ws = (float*)d_ws;
  size_t off = 0;
  auto alloc = [&](size_t n) {
    n = (n + 3) & ~(size_t)3;  // 16B alignment
    float* p = ws + off;
    off += n;
    return p;
  };
  float* mean = alloc((size_t)Bn * Cn);
  float* stdevv = alloc((size_t)Bn * Cn);
  float* cmean = alloc(256);
  float* cistd = alloc(256);
  double* part = (double*)alloc(256 * 512 * 2);
  double* ld = (double*)alloc(32);
  double* covd = (double*)alloc(3 * 65536 * 2);
  float* s1 = alloc((size_t)Bn * 512 * Dn);
  float* s2 = alloc((size_t)Bn * 128 * Dn);
  float* s3 = alloc((size_t)Bn * 32 * Dn);
  float* attn = alloc((size_t)Bn * 512 * 2048);     // f32 scores; also xnT(bf16)
  float* sbuf = alloc((size_t)16777216);            // attn_bf / o2 f32 / covpart
  ushort_t* h_bf = (ushort_t*)alloc((size_t)Bn * Cn * Dn / 2);
  ushort_t* s1b = (ushort_t*)alloc((size_t)Bn * 512 * Dn / 2);
  ushort_t* s2b = (ushort_t*)alloc((size_t)Bn * 128 * Dn / 2);
  ushort_t* s3b = (ushort_t*)alloc((size_t)Bn * 32 * Dn / 2);
  ushort_t* xpb = (ushort_t*)alloc((size_t)Bn * 32 * Dn / 2);
  ushort_t* xu0b = (ushort_t*)alloc((size_t)Bn * 128 * Dn / 2);
  ushort_t* xu1b = (ushort_t*)alloc((size_t)Bn * 512 * Dn / 2);
  ushort_t* qd_b = (ushort_t*)alloc(512 * 256 / 2);
  ushort_t* lqb0 = (ushort_t*)alloc(512 * 256 / 2);
  ushort_t* lqb1 = (ushort_t*)alloc(128 * 256 / 2);
  ushort_t* lqb2 = (ushort_t*)alloc(32 * 256 / 2);
  ushort_t* in_wT = (ushort_t*)alloc(256 * SnP / 2);
  ushort_t* downT = (ushort_t*)alloc(12 * 65536 / 2);
  ushort_t* upT = (ushort_t*)alloc(12 * 65536 / 2);
  ushort_t* predT = (ushort_t*)alloc(65536 / 2);
  ushort_t* outT = (ushort_t*)alloc(96 * 256 / 2);
  ushort_t* q_bf = (ushort_t*)alloc((size_t)Bn * 2048 * Dn / 2);  // also o1, xph
  ushort_t* k_bf = (ushort_t*)alloc((size_t)Bn * 2048 * Dn / 2);
  ushort_t* vT = (ushort_t*)alloc((size_t)Bn * 2048 * Dn / 2);

  ushort_t* xnT = (ushort_t*)attn;
  ushort_t* attn_b = (ushort_t*)sbuf;
  float* o2 = sbuf;
  double* covpart = (double*)sbuf;
  const float scale = 0.0625f;
  const float* npf = nullptr;

  // ---- prep: stats, normalize+transpose input, weight converts ----
  instnorm_stats<<<dim3(Cn / 256, Bn), 256, 0, stream>>>(x_enc, mean, stdevv);
  normT_kernel<<<dim3(Cn / 32, SnP / 32, Bn), 256, 0, stream>>>(x_enc, xnT, mean,
                                                                stdevv);
  cvtT_kernel<<<dim3(8, 8, 12), 256, 0, stream>>>(down_w, downT, 256, 256, 256);
  cvtT_kernel<<<dim3(8, 8, 12), 256, 0, stream>>>(up_w, upT, 256, 256, 256);
  cvtT_kernel<<<dim3(8, 8, 1), 256, 0, stream>>>(pred_w, predT, 256, 256, 256);
  cvtT_kernel<<<dim3(8, SnP / 32, 1), 256, 0, stream>>>(in_w, in_wT, Sn, 256, SnP);
  cvtT_kernel<<<dim3(3, 8, 1), 256, 0, stream>>>(out_w, outT, 256, Pn, 256);
  cvt_bf<<<512, 256, 0, stream>>>(lq[0], lqb0, 512 * 256);
  cvt_bf<<<128, 256, 0, stream>>>(lq[1], lqb1, 128 * 256);
  cvt_bf<<<32, 256, 0, stream>>>(lq[2], lqb2, 32 * 256);

  // ---- h = xn^T @ in_w + b : bf16 out (K padded to 736) ----
  gemm_bf<2><<<dim3(2, 16, Bn), 256, 0, stream>>>(
      xnT, in_wT, Cn, Dn, SnP, SnP, SnP, (ll)Cn * SnP, 0, in_b, 1.f,
      nullptr, 0, 0, h_bf, Dn, (ll)Cn * Dn);

  ushort_t* lqb[3] = {lqb0, lqb1, lqb2};
  float* skf[3] = {s1, s2, s3};
  ushort_t* skb[3] = {s1b, s2b, s3b};
  int Ls[4] = {2048, 512, 128, 32};
  const ushort_t* xinb = h_bf;

  // ---------------- down layers ----------------
  for (int i = 0; i < 3; ++i) {
    int L = Ls[i], Lq = Ls[i + 1];
    const ushort_t* WqT = downT + (size_t)(i * 4 + 0) * 65536;
    const ushort_t* WkT = downT + (size_t)(i * 4 + 1) * 65536;
    const ushort_t* WvT = downT + (size_t)(i * 4 + 2) * 65536;
    const ushort_t* WoT = downT + (size_t)(i * 4 + 3) * 65536;
    const float* bq = down_b + (i * 4 + 0) * 256;
    const float* bk = down_b + (i * 4 + 1) * 256;
    const float* bv = down_b + (i * 4 + 2) * 256;
    const float* bo = down_b + (i * 4 + 3) * 256;

    gemm_bf<2><<<dim3(2, CDIV(Lq, 128), 1), 256, 0, stream>>>(
        lqb[i], WqT, Lq, Dn, Dn, Dn, Dn, 0, 0, bq, 1.f, nullptr, 0, 0, qd_b, Dn, 0);
    gemm_bf<2><<<dim3(2, (Bn * L) / 128, 1), 256, 0, stream>>>(
        xinb, WkT, Bn * L, Dn, Dn, Dn, Dn, 0, 0, bk, 1.f, nullptr, 0, 0, k_bf, Dn, 0);
    gemm_bf<4><<<dim3(2, L / 128, Bn), 256, 0, stream>>>(
        xinb, WvT, L, Dn, Dn, Dn, Dn, (ll)L * Dn, 0, bv, 1.f, nullptr, 0, 0,
        vT, L, (ll)Dn * L);
    gemm_bf<1><<<dim3(L / 128, CDIV(Lq, 128), Bn), 256, 0, stream>>>(
        qd_b, k_bf, Lq, L, Dn, Dn, Dn, 0, (ll)L * Dn, npf, scale,
        attn, L, (ll)Lq * L, nullptr, 0, 0);
    if (L == 2048) softmax_bf<2048><<<Bn * Lq, 256, 0, stream>>>(attn, attn_b);
    else if (L == 512) softmax_bf<512><<<Bn * Lq, 256, 0, stream>>>(attn, attn_b);
    else softmax_bf<128><<<Bn * Lq, 256, 0, stream>>>(attn, attn_b);
    gemm_bf<2><<<dim3(2, CDIV(Lq, 128), Bn), 256, 0, stream>>>(
        attn_b, vT, Lq, Dn, L, L, L, (ll)Lq * L, (ll)Dn * L, npf, 1.f,
        nullptr, 0, 0, q_bf, Dn, (ll)Lq * Dn);
    gemm_bf<1><<<dim3(2, CDIV(Bn * Lq, 128), 1), 256, 0, stream>>>(
        q_bf, WoT, Bn * Lq, Dn, Dn, Dn, Dn, 0, 0, bo, 1.f, o2, Dn, 0, nullptr, 0, 0);
    ln_kernel<<<Bn * Lq, 256, 0, stream>>>(o2, nullptr, skf[i], skb[i], 0,
                                           down_ln + (i * 2 + 0) * 256,
                                           down_ln + (i * 2 + 1) * 256);
    xinb = skb[i];
  }

  // ------- covariance loss (64-tile lower-tri Gram + NB=32 Cholesky) ---------
  int nrs[3] = {Bn * 512, Bn * 128, Bn * 32};
  int nzs[3] = {64, 32, 16};
  for (int j = 0; j < 3; ++j) {
    int nr = nrs[j];
    colstat_partial<<<256, 256, 0, stream>>>(skf[j], part, nr);
    colstat_final<<<1, 256, 0, stream>>>(part, cmean, cistd, nr);
    cov_gram<<<dim3(10, nzs[j]), 256, 0, stream>>>(skf[j], cmean, cistd, covpart,
                                                   nr, nzs[j]);
    cov_reduce<<<10, 256, 0, stream>>>(covpart, covd + (size_t)j * 65536,
                                       1.0 / (double)(nr - 1), nzs[j]);
  }
  for (int kb = 0; kb < 8; ++kb) {
    chol_step_a<<<3, 256, 0, stream>>>(covd, kb * 32);
    int T = 7 - kb;
    if (T > 0)
      chol_step_b<<<dim3(T * (T + 1) / 2, 3), 256, 0, stream>>>(covd, kb * 32);
  }
  logdet_diag<<<3, 256, 0, stream>>>(covd, ld);
  cov_final<<<1, 1, 0, stream>>>(ld, out + 6291456);

  // ---------------- pred head ----------------
  gemm_bf<2><<<dim3(2, 8, 1), 256, 0, stream>>>(
      s3b, predT, Bn * 32, Dn, Dn, Dn, Dn, 0, 0, pred_b, 1.f,
      nullptr, 0, 0, xpb, Dn, 0);

  // ---------------- up layers ----------------
  int Lks[3] = {32, 128, 512}, Lqs[3] = {128, 512, 2048};
  const ushort_t* qinb[3] = {s2b, s1b, h_bf};
  const ushort_t* xinbs[3] = {xpb, xu0b, xu1b};
  ushort_t* xoutb[3] = {xu0b, xu1b, q_bf};  // final writes xph into q_bf
  for (int i = 0; i < 3; ++i) {
    int Lk = Lks[i], Lq = Lqs[i];
    const ushort_t* WqT = upT + (size_t)(i * 4 + 0) * 65536;
    const ushort_t* WkT = upT + (size_t)(i * 4 + 1) * 65536;
    const ushort_t* WvT = upT + (size_t)(i * 4 + 2) * 65536;
    const ushort_t* WoT = upT + (size_t)(i * 4 + 3) * 65536;
    const float* bq = up_b + (i * 4 + 0) * 256;
    const float* bk = up_b + (i * 4 + 1) * 256;
    const float* bv = up_b + (i * 4 + 2) * 256;
    const float* bo = up_b + (i * 4 + 3) * 256;

    gemm_bf<2><<<dim3(2, (Bn * Lq) / 128, 1), 256, 0, stream>>>(
        qinb[i], WqT, Bn * Lq, Dn, Dn, Dn, Dn, 0, 0, bq, 1.f,
        nullptr, 0, 0, q_bf, Dn, 0);
    gemm_bf<2><<<dim3(2, CDIV(Bn * Lk, 128), 1), 256, 0, stream>>>(
        xinbs[i], WkT, Bn * Lk, Dn, Dn, Dn, Dn, 0, 0, bk, 1.f,
        nullptr, 0, 0, k_bf, Dn, 0);
    gemm_bf<4><<<dim3(2, CDIV(Lk, 128), Bn), 256, 0, stream>>>(
        xinbs[i], WvT, Lk, Dn, Dn, Dn, Dn, (ll)Lk * Dn, 0, bv, 1.f,
        nullptr, 0, 0, vT, Lk, (ll)Dn * Lk);
    gemm_bf<1><<<dim3(CDIV(Lk, 128), CDIV(Lq, 128), Bn), 256, 0, stream>>>(
        q_bf, k_bf, Lq, Lk, Dn, Dn, Dn, (ll)Lq * Dn, (ll)Lk * Dn, npf, scale,
        attn, Lk, (ll)Lq * Lk, nullptr, 0, 0);
    if (Lk == 32) softmax_bf<32><<<Bn * Lq, 256, 0, stream>>>(attn, attn_b);
    else if (Lk == 128) softmax_bf<128><<<Bn * Lq, 256, 0, stream>>>(attn, attn_b);
    else softmax_bf<512><<<Bn * Lq, 256, 0, stream>>>(attn, attn_b);
    gemm_bf<2><<<dim3(2, CDIV(Lq, 128), Bn), 256, 0, stream>>>(
        attn_b, vT, Lq, Dn, Lk, Lk, Lk, (ll)Lq * Lk, (ll)Dn * Lk, npf, 1.f,
        nullptr, 0, 0, q_bf, Dn, (ll)Lq * Dn);
    gemm_bf<1><<<dim3(2, (Bn * Lq) / 128, 1), 256, 0, stream>>>(
        q_bf, WoT, Bn * Lq, Dn, Dn, Dn, Dn, 0, 0, bo, 1.f, o2, Dn, 0, nullptr, 0, 0);
    ln_kernel<<<Bn * Lq, 256, 0, stream>>>(o2, qinb[i], nullptr, xoutb[i],
                                           (i == 2) ? 1 : 0,
                                           up_ln + (i * 2 + 0) * 256,
                                           up_ln + (i * 2 + 1) * 256);
  }

  // ---------------- output head: MFMA + transpose + de-norm ----------------
  out_mfma<<<dim3(1, (Bn * Cn) / 128, 1), 256, 0, stream>>>(q_bf, outT, out_b,
                                                            stdevv, mean, out);
}

// Round 13
// 1799.620 us; speedup vs baseline: 1.4685x; 1.2541x over previous
//
#include <hip/hip_runtime.h>
#include <hip/hip_bf16.h>
#include <math.h>

#define CDIV(a, b) (((a) + (b) - 1) / (b))
typedef long long ll;
typedef unsigned short ushort_t;

constexpr int Bn = 32;    // batch
constexpr int Sn = 720;   // seq len
constexpr int SnP = 736;  // seq len padded to K-step multiple
constexpr int Cn = 2048;  // channels (tokens after transpose)
constexpr int Dn = 256;   // d_model
constexpr int Pn = 96;    // pred len

typedef __attribute__((ext_vector_type(8))) short bf16x8;
typedef __attribute__((ext_vector_type(4))) float f32x4;

__device__ inline ushort_t rne1(float x) {
  unsigned u = __float_as_uint(x);
  u = (u + 0x7fffu + ((u >> 16) & 1u)) >> 16;
  return (ushort_t)u;
}
__device__ inline float b2f(ushort_t u) { return __uint_as_float(((unsigned)u) << 16); }

__device__ inline void gl_lds16(const void* g, void* l) {
  __builtin_amdgcn_global_load_lds(
      (const __attribute__((address_space(1))) void*)g,
      (__attribute__((address_space(3))) void*)l, 16, 0, 0);
}

// ---------------- instance norm stats over time axis ----------------
__global__ void instnorm_stats(const float* __restrict__ x,
                               float* __restrict__ mean, float* __restrict__ stdev) {
  int c = blockIdx.x * 256 + threadIdx.x;
  int b = blockIdx.y;
  const float* p = x + (ll)b * Sn * Cn + c;
  float s = 0.f, q = 0.f;
  for (int t = 0; t < Sn; ++t) {
    float v = p[(ll)t * Cn];
    s += v; q += v * v;
  }
  float m = s / (float)Sn;
  float var = q / (float)Sn - m * m;
  var = fmaxf(var, 0.f);
  mean[b * Cn + c] = m;
  stdev[b * Cn + c] = sqrtf(var + 1e-5f);
}

// ---------------- normalize + transpose: x[b][s][c] -> xnT[b][c][s] bf16 (K-pad)
__global__ void normT_kernel(const float* __restrict__ X, ushort_t* __restrict__ D,
                             const float* __restrict__ mean,
                             const float* __restrict__ stdev) {
  int b = blockIdx.z;
  __shared__ float tl[32][33];
  int t = threadIdx.x;
  int tx = t & 31, ty = t >> 5;
  int s0 = blockIdx.y * 32, c0 = blockIdx.x * 32;
#pragma unroll
  for (int e = 0; e < 4; ++e) {
    int s = s0 + ty + 8 * e;
    tl[ty + 8 * e][tx] = (s < Sn) ? X[((ll)b * Sn + s) * Cn + c0 + tx] : 0.f;
  }
  __syncthreads();
#pragma unroll
  for (int e = 0; e < 4; ++e) {
    int c = c0 + ty + 8 * e, s = s0 + tx;
    if (s < SnP) {
      float mu = mean[b * Cn + c], sd = stdev[b * Cn + c];
      float v = (s < Sn) ? (tl[tx][ty + 8 * e] - mu) / sd : 0.f;
      D[((ll)b * Cn + c) * SnP + s] = rne1(v);
    }
  }
}

// ---------------- transpose-convert: W[K][N] f32 -> WT[N][KP] bf16 ------------
__global__ void cvtT_kernel(const float* __restrict__ S, ushort_t* __restrict__ D,
                            int K, int N, int KP) {
  int z = blockIdx.z;
  S += (ll)z * K * N;
  D += (ll)z * N * KP;
  __shared__ float tl[32][33];
  int t = threadIdx.x;
  int tx = t & 31, ty = t >> 5;
  int k0 = blockIdx.y * 32, n0 = blockIdx.x * 32;
#pragma unroll
  for (int e = 0; e < 4; ++e) {
    int k = k0 + ty + 8 * e;
    tl[ty + 8 * e][tx] = (k < K && n0 + tx < N) ? S[(ll)k * N + n0 + tx] : 0.f;
  }
  __syncthreads();
#pragma unroll
  for (int e = 0; e < 4; ++e) {
    int n = n0 + ty + 8 * e, kk = k0 + tx;
    if (n < N && kk < KP) D[(ll)n * KP + kk] = rne1(tl[tx][ty + 8 * e]);
  }
}

__global__ void cvt_bf(const float* __restrict__ S, ushort_t* __restrict__ D, int n) {
  int i = blockIdx.x * 256 + threadIdx.x;
  if (i < n) D[i] = rne1(S[i]);
}

// ---------------- canonical bf16 MFMA GEMM: C = A[M][K] * B[N][K]^T ----------
// global_load_lds staging; K must be a multiple of 32; OOB rows clamped.
// MODE bits: 1 = write f32 C (ldcf), 2 = write bf16 C (ldcb), 4 = write bf16 C^T
template <int MODE>
__global__ __launch_bounds__(256) void gemm_bf(
    const ushort_t* __restrict__ A, const ushort_t* __restrict__ B,
    int M, int N, int K, int lda, int ldb, ll sA, ll sB,
    const float* __restrict__ bias, float alpha,
    float* __restrict__ Cf, int ldcf, ll sCf,
    ushort_t* __restrict__ Cb, int ldcb, ll sCb) {
  int g = blockIdx.z;
  A += (ll)g * sA;
  B += (ll)g * sB;
  if (MODE & 1) Cf += (ll)g * sCf;
  if (MODE & 6) Cb += (ll)g * sCb;
  __shared__ ushort_t lds_ab[2][128][32];
  int t = threadIdx.x;
  int m0 = blockIdx.y * 128, n0 = blockIdx.x * 128;
  int w = t >> 6, lane = t & 63;
  int wm = (w >> 1) * 64, wn = (w & 1) * 64;
  int lrow = lane & 15, kq = lane >> 4;
  int srow = lane >> 2, skcol = (lane & 3) * 8;
  f32x4 acc[4][4] = {};
  for (int k0 = 0; k0 < K; k0 += 32) {
#pragma unroll
    for (int cc = 0; cc < 4; ++cc) {
      int c = w * 4 + cc;
      int tile = c >> 3, rb = (c & 7) * 16;
      int row = rb + srow;
      const ushort_t* src;
      if (tile == 0) {
        int gm = min(m0 + row, M - 1);
        src = &A[(ll)gm * lda + k0 + skcol];
      } else {
        int gn = min(n0 + row, N - 1);
        src = &B[(ll)gn * ldb + k0 + skcol];
      }
      gl_lds16(src, &lds_ab[tile][rb][0]);
    }
    __syncthreads();
    bf16x8 af[4], bfr[4];
#pragma unroll
    for (int i = 0; i < 4; ++i)
      af[i] = *reinterpret_cast<const bf16x8*>(&lds_ab[0][wm + i * 16 + lrow][kq * 8]);
#pragma unroll
    for (int j = 0; j < 4; ++j)
      bfr[j] = *reinterpret_cast<const bf16x8*>(&lds_ab[1][wn + j * 16 + lrow][kq * 8]);
#pragma unroll
    for (int i = 0; i < 4; ++i)
#pragma unroll
      for (int j = 0; j < 4; ++j)
        acc[i][j] = __builtin_amdgcn_mfma_f32_16x16x32_bf16(af[i], bfr[j],
                                                            acc[i][j], 0, 0, 0);
    __syncthreads();
  }
#pragma unroll
  for (int i = 0; i < 4; ++i) {
    int mb = m0 + wm + i * 16 + kq * 4;
    if (mb >= M) continue;
#pragma unroll
    for (int j = 0; j < 4; ++j) {
      int c = n0 + wn + j * 16 + lrow;
      if (c >= N) continue;
      float bv = bias ? bias[c] : 0.f;
#pragma unroll
      for (int reg = 0; reg < 4; ++reg) {
        int m = mb + reg;
        float v = acc[i][j][reg] * alpha + bv;
        if (MODE & 1) Cf[(ll)m * ldcf + c] = v;
        if (MODE & 2) Cb[(ll)m * ldcb + c] = rne1(v);
        if (MODE & 4) Cb[(ll)c * ldcb + m] = rne1(v);
      }
    }
  }
}

// ---------------- block reduction helper (blockDim = 256) ----------------
__device__ inline float blk_reduce(float v, volatile float* sh, int op) {
  int lane = threadIdx.x & 63, w = threadIdx.x >> 6;
#pragma unroll
  for (int off = 32; off > 0; off >>= 1) {
    float o = __shfl_down(v, off, 64);
    v = op ? fmaxf(v, o) : (v + o);
  }
  __syncthreads();
  if (lane == 0) sh[w] = v;
  __syncthreads();
  float r = op ? fmaxf(fmaxf(sh[0], sh[1]), fmaxf(sh[2], sh[3]))
               : (sh[0] + sh[1] + sh[2] + sh[3]);
  return r;
}

// ---------------- row softmax: f32 scores in, bf16 probs out ----------------
template <int LL>
__global__ void softmax_bf(const float* __restrict__ S, ushort_t* __restrict__ P) {
  constexpr int NE = (LL + 255) / 256;
  __shared__ float sh[4];
  ll row = blockIdx.x;
  const float* p = S + row * (ll)LL;
  ushort_t* q = P + row * (ll)LL;
  int t = threadIdx.x;
  float e[NE];
  float mx = -INFINITY;
#pragma unroll
  for (int k = 0; k < NE; ++k) {
    int i = t + k * 256;
    if (i < LL) { e[k] = p[i]; mx = fmaxf(mx, e[k]); }
  }
  mx = blk_reduce(mx, sh, 1);
  float sum = 0.f;
#pragma unroll
  for (int k = 0; k < NE; ++k) {
    int i = t + k * 256;
    if (i < LL) { e[k] = __expf(e[k] - mx); sum += e[k]; }
  }
  sum = blk_reduce(sum, sh, 0);
  float inv = 1.f / sum;
#pragma unroll
  for (int k = 0; k < NE; ++k) {
    int i = t + k * 256;
    if (i < LL) q[i] = rne1(e[k] * inv);
  }
}

// ---------------- LayerNorm over D=256; optional bf16 residual ----------------
__global__ void ln_kernel(const float* __restrict__ X, const ushort_t* __restrict__ RESb,
                          float* __restrict__ Yf, ushort_t* __restrict__ Yb, int postadd,
                          const float* __restrict__ gamma, const float* __restrict__ beta) {
  __shared__ float sh[4];
  ll row = blockIdx.x;
  int t = threadIdx.x;
  float r = RESb ? b2f(RESb[row * Dn + t]) : 0.f;
  float v = X[row * Dn + t] + r;
  float m = blk_reduce(v, sh, 0) * (1.f / (float)Dn);
  float d = v - m;
  float var = blk_reduce(d * d, sh, 0) * (1.f / (float)Dn);
  float y = d * rsqrtf(var + 1e-5f) * gamma[t] + beta[t];
  if (Yf) Yf[row * Dn + t] = y;
  if (Yb) Yb[row * Dn + t] = rne1(y + (postadd ? r : 0.f));
}

// ---------------- covariance column stats (f64 partials) ----------------
__global__ void colstat_partial(const float* __restrict__ X, double* __restrict__ part,
                                int nrows) {
  int blk = blockIdx.x, t = threadIdx.x;
  int chunk = CDIV(nrows, 256);
  int r0 = blk * chunk, r1 = min(nrows, r0 + chunk);
  double s = 0.0, q = 0.0;
  for (int r = r0; r < r1; ++r) {
    double v = (double)X[(ll)r * Dn + t];
    s += v; q += v * v;
  }
  part[blk * 512 + t] = s;
  part[blk * 512 + 256 + t] = q;
}

__global__ void colstat_final(const double* __restrict__ part, float* __restrict__ cmean,
                              float* __restrict__ cistd, int nrows) {
  int t = threadIdx.x;
  double s = 0.0, q = 0.0;
  for (int b = 0; b < 256; ++b) {
    s += part[b * 512 + t];
    q += part[b * 512 + 256 + t];
  }
  double m = s / (double)nrows;
  double var = (q - (double)nrows * m * m) / (double)(nrows - 1);
  var = fmax(var, 0.0);
  cmean[t] = (float)m;
  cistd[t] = (float)(1.0 / (sqrt(var) + 1e-5));
}

// -------- lower-triangle cov Gram: 64x64 f64 tiles, fused normalize ----------
__global__ __launch_bounds__(256) void cov_gram(const float* __restrict__ X,
                                                const float* __restrict__ cmean,
                                                const float* __restrict__ cistd,
                                                double* __restrict__ part,
                                                int nr, int nz) {
  __shared__ double Am[32][66];
  __shared__ double Bq[32][66];
  __shared__ float cmA[64], ciA[64], cmB[64], ciB[64];
  int tile = blockIdx.x;
  int mi = 0;
  while (tile >= mi + 1) { tile -= mi + 1; ++mi; }
  int nj = tile;  // mi >= nj (4x4 blocks of 64)
  int m0 = mi * 64, n0 = nj * 64;
  bool diag = (mi == nj);
  int z = blockIdx.y;
  int t = threadIdx.x;
  int tx4 = (t & 15) * 4, ty4 = (t >> 4) * 4;
  if (t < 64) { cmA[t] = cmean[m0 + t]; ciA[t] = cistd[m0 + t]; }
  else if (t < 128) { cmB[t - 64] = cmean[n0 + t - 64]; ciB[t - 64] = cistd[n0 + t - 64]; }
  __syncthreads();
  int chunk = nr / nz;
  int kbeg = z * chunk, kend = kbeg + chunk;
  double acc[4][4] = {};
  const double* Bbase = diag ? &Am[0][0] : &Bq[0][0];
  for (int k0 = kbeg; k0 < kend; k0 += 32) {
#pragma unroll
    for (int e = 0; e < 8; ++e) {
      int idx = t + e * 256;
      int kk = idx >> 6, mm = idx & 63;
      float xa = X[(ll)(k0 + kk) * Dn + m0 + mm];
      Am[kk][mm] = (double)((xa - cmA[mm]) * ciA[mm]);
      if (!diag) {
        float xb = X[(ll)(k0 + kk) * Dn + n0 + mm];
        Bq[kk][mm] = (double)((xb - cmB[mm]) * ciB[mm]);
      }
    }
    __syncthreads();
#pragma unroll 4
    for (int kk = 0; kk < 32; ++kk) {
      double a[4], b[4];
#pragma unroll
      for (int q = 0; q < 4; ++q) a[q] = Am[kk][ty4 + q];
#pragma unroll
      for (int q = 0; q < 4; ++q) b[q] = Bbase[kk * 66 + tx4 + q];
#pragma unroll
      for (int i = 0; i < 4; ++i)
#pragma unroll
        for (int j = 0; j < 4; ++j) acc[i][j] += a[i] * b[j];
    }
    __syncthreads();
  }
  ll base = ((ll)z * 10 + blockIdx.x) * 4096;
#pragma unroll
  for (int i = 0; i < 4; ++i)
#pragma unroll
    for (int j = 0; j < 4; ++j)
      part[base + (ty4 + i) * 64 + tx4 + j] = acc[i][j];
}

// reduce split-K partials; grid (10 tiles, 16 segments of 256 elements)
__global__ void cov_reduce(const double* __restrict__ part, double* __restrict__ Cd,
                           double inv, int nz) {
  int tile = blockIdx.x;
  int mi = 0;
  while (tile >= mi + 1) { tile -= mi + 1; ++mi; }
  int nj = tile;
  int e = blockIdx.y * 256 + threadIdx.x;
  int rr = e >> 6, cc = e & 63;
  int m = mi * 64 + rr, n = nj * 64 + cc;
  double s0 = 0.0, s1 = 0.0, s2 = 0.0, s3 = 0.0;
  int z = 0;
  for (; z + 4 <= nz; z += 4) {
    s0 += part[((ll)(z + 0) * 10 + blockIdx.x) * 4096 + e];
    s1 += part[((ll)(z + 1) * 10 + blockIdx.x) * 4096 + e];
    s2 += part[((ll)(z + 2) * 10 + blockIdx.x) * 4096 + e];
    s3 += part[((ll)(z + 3) * 10 + blockIdx.x) * 4096 + e];
  }
  for (; z < nz; ++z) s0 += part[((ll)z * 10 + blockIdx.x) * 4096 + e];
  double s = ((s0 + s1) + (s2 + s3)) * inv + ((m == n) ? 1e-5 : 0.0);
  Cd[m * 256 + n] = s;
}

// ---------------- multi-launch right-looking f64 Cholesky (NB=32) ------------
// step A (3 blocks): factor 32x32 diag block in-wave via __shfl (no barriers),
// then per-thread forward-substitution for up to 224 L21 rows. Register-fit.
__global__ __launch_bounds__(256) void chol_step_a(double* __restrict__ mats, int d0) {
  double* A = mats + (ll)blockIdx.x * 65536;
  __shared__ double D[32][33];
  __shared__ double dinv[32];
  int t = threadIdx.x;
  for (int e = t; e < 1024; e += 256) {
    int i = e >> 5, j = e & 31;
    D[i][j] = (j <= i) ? A[(ll)(d0 + i) * 256 + d0 + j] : 0.0;  // upper never computed
  }
  __syncthreads();
  if (t < 32) {
    double x[32];
#pragma unroll
    for (int j = 0; j < 32; ++j) x[j] = D[t][j];
#pragma unroll
    for (int k = 0; k < 32; ++k) {
      double piv = fmax(__shfl(x[k], k, 64), 1e-300);
      double inv = 1.0 / sqrt(piv);
      double lrk = x[k] * inv;  // lane t: l_{t,k}; lane k: d_k
      x[k] = lrk;
#pragma unroll
      for (int j = k + 1; j < 32; ++j) x[j] -= lrk * __shfl(lrk, j, 64);
    }
#pragma unroll
    for (int j = 0; j < 32; ++j) D[t][j] = x[j];
    dinv[t] = 1.0 / x[t];
  }
  __syncthreads();
  // L21 solve: thread t -> row d0+32+t ; y = L11^{-1} a_row
  int r = d0 + 32 + t;
  if (r < 256) {
    double y[32];
#pragma unroll
    for (int j = 0; j < 32; ++j) y[j] = A[(ll)r * 256 + d0 + j];
#pragma unroll
    for (int j = 0; j < 32; ++j) {
      double s = y[j];
#pragma unroll
      for (int i = 0; i < j; ++i) s -= y[i] * D[j][i];
      y[j] = s * dinv[j];
    }
#pragma unroll
    for (int j = 0; j < 32; ++j) A[(ll)r * 256 + d0 + j] = y[j];
  }
  // write factored diag block back (logdet_diag reads diagonal)
  for (int e = t; e < 1024; e += 256)
    A[(ll)(d0 + (e >> 5)) * 256 + d0 + (e & 31)] = D[e >> 5][e & 31];
}

// step B (grid-parallel SYRK): trailing A22 -= L21 L21^T, 32x32 tiles, lower half
__global__ __launch_bounds__(256) void chol_step_b(double* __restrict__ mats, int d0) {
  double* A = mats + (ll)blockIdx.y * 65536;
  int tile = blockIdx.x;
  int i = 0;
  while (tile >= i + 1) { tile -= i + 1; ++i; }
  int j = tile;  // i >= j
  int ri = d0 + 32 + i * 32, rj = d0 + 32 + j * 32;
  __shared__ double Li[32][33];
  __shared__ double Lj[32][33];
  int t = threadIdx.x;
  for (int e = t; e < 1024; e += 256) {
    int rr = e >> 5, kk = e & 31;
    Li[rr][kk] = A[(ll)(ri + rr) * 256 + d0 + kk];
    Lj[rr][kk] = A[(ll)(rj + rr) * 256 + d0 + kk];
  }
  __syncthreads();
  for (int e = t; e < 1024; e += 256) {
    int rr = e >> 5, cc = e & 31;
    double s = 0.0;
#pragma unroll
    for (int k = 0; k < 32; ++k) s += Li[rr][k] * Lj[cc][k];
    A[(ll)(ri + rr) * 256 + rj + cc] -= s;
  }
}

// logdet = 2 * sum log(diag(L)), parallel reduce
__global__ void logdet_diag(const double* __restrict__ mats, double* __restrict__ ld) {
  __shared__ double sh[4];
  const double* A = mats + (ll)blockIdx.x * 65536;
  int t = threadIdx.x;
  double lg = log(A[(ll)t * 257]);
  int lane = t & 63, w = t >> 6;
#pragma unroll
  for (int off = 32; off > 0; off >>= 1) lg += __shfl_down(lg, off, 64);
  if (lane == 0) sh[w] = lg;
  __syncthreads();
  if (t == 0) ld[blockIdx.x] = 2.0 * (sh[0] + sh[1] + sh[2] + sh[3]);
}

__global__ void cov_final(const double* __restrict__ ld, float* __restrict__ outp) {
  outp[0] = (float)(-0.1 / (3.0 * 256.0) * (ld[0] + ld[1] + ld[2]));
}

// ---------------- output head: xph[M][256] @ outT[96][256]^T, scatter+denorm --
__global__ __launch_bounds__(256) void out_mfma(
    const ushort_t* __restrict__ A, const ushort_t* __restrict__ B,
    const float* __restrict__ bias, const float* __restrict__ stdev,
    const float* __restrict__ mean, float* __restrict__ out) {
  constexpr int M = Bn * Cn, N = Pn, K = Dn;
  __shared__ ushort_t lds_ab[2][128][32];
  int t = threadIdx.x;
  int m0 = blockIdx.y * 128;
  int w = t >> 6, lane = t & 63;
  int wm = (w >> 1) * 64, wn = (w & 1) * 64;
  int lrow = lane & 15, kq = lane >> 4;
  int srow = lane >> 2, skcol = (lane & 3) * 8;
  f32x4 acc[4][4] = {};
  for (int k0 = 0; k0 < K; k0 += 32) {
#pragma unroll
    for (int cc = 0; cc < 4; ++cc) {
      int c = w * 4 + cc;
      int tile = c >> 3, rb = (c & 7) * 16;
      int row = rb + srow;
      const ushort_t* src;
      if (tile == 0) {
        src = &A[(ll)(m0 + row) * K + k0 + skcol];
      } else {
        int gn = min(row, N - 1);
        src = &B[(ll)gn * K + k0 + skcol];
      }
      gl_lds16(src, &lds_ab[tile][rb][0]);
    }
    __syncthreads();
    bf16x8 af[4], bfr[4];
#pragma unroll
    for (int i = 0; i < 4; ++i)
      af[i] = *reinterpret_cast<const bf16x8*>(&lds_ab[0][wm + i * 16 + lrow][kq * 8]);
#pragma unroll
    for (int j = 0; j < 4; ++j)
      bfr[j] = *reinterpret_cast<const bf16x8*>(&lds_ab[1][wn + j * 16 + lrow][kq * 8]);
#pragma unroll
    for (int i = 0; i < 4; ++i)
#pragma unroll
      for (int j = 0; j < 4; ++j)
        acc[i][j] = __builtin_amdgcn_mfma_f32_16x16x32_bf16(af[i], bfr[j],
                                                            acc[i][j], 0, 0, 0);
    __syncthreads();
  }
#pragma unroll
  for (int i = 0; i < 4; ++i) {
    int mb = m0 + wm + i * 16 + kq * 4;
#pragma unroll
    for (int j = 0; j < 4; ++j) {
      int p = wn + j * 16 + lrow;
      if (p >= N) continue;
      float bv = bias[p];
#pragma unroll
      for (int reg = 0; reg < 4; ++reg) {
        int m = mb + reg;
        int b = m >> 11, c = m & 2047;
        float v = acc[i][j][reg] + bv;
        out[((ll)(b * Pn + p)) * Cn + c] = v * stdev[m] + mean[m];
      }
    }
  }
}

// =====================================================================
extern "C" void kernel_launch(void* const* d_in, const int* in_sizes, int n_in,
                              void* d_out, int out_size, void* d_ws, size_t ws_size,
                              hipStream_t stream) {
  (void)in_sizes; (void)n_in; (void)out_size; (void)ws_size;
  const float* x_enc = (const float*)d_in[0];
  const float* in_w = (const float*)d_in[4];
  const float* in_b = (const float*)d_in[5];
  const float* lq[3] = {(const float*)d_in[6], (const float*)d_in[7],
                        (const float*)d_in[8]};
  const float* down_w = (const float*)d_in[9];
  const float* down_b = (const float*)d_in[10];
  const float* down_ln = (const float*)d_in[11];
  const float* pred_w = (const float*)d_in[12];
  const float* pred_b = (const float*)d_in[13];
  const float* up_w = (const float*)d_in[14];
  const float* up_b = (const float*)d_in[15];
  const float* up_ln = (const float*)d_in[16];
  const float* out_w = (const float*)d_in[17];
  const float* out_b = (const float*)d_in[18];
  float* out = (float*)d_out;

  float* ws = (float*)d_ws;
  size_t off = 0;
  auto alloc = [&](size_t n) {
    n = (n + 3) & ~(size_t)3;  // 16B alignment
    float* p = ws + off;
    off += n;
    return p;
  };
  float* mean = alloc((size_t)Bn * Cn);
  float* stdevv = alloc((size_t)Bn * Cn);
  float* cmean = alloc(256);
  float* cistd = alloc(256);
  double* part = (double*)alloc(256 * 512 * 2);
  double* ld = (double*)alloc(32);
  double* covd = (double*)alloc(3 * 65536 * 2);
  float* s1 = alloc((size_t)Bn * 512 * Dn);
  float* s2 = alloc((size_t)Bn * 128 * Dn);
  float* s3 = alloc((size_t)Bn * 32 * Dn);
  float* attn = alloc((size_t)Bn * 512 * 2048);     // f32 scores; also xnT(bf16)
  float* sbuf = alloc((size_t)16777216);            // attn_bf / o2 f32 / covpart
  ushort_t* h_bf = (ushort_t*)alloc((size_t)Bn * Cn * Dn / 2);
  ushort_t* s1b = (ushort_t*)alloc((size_t)Bn * 512 * Dn / 2);
  ushort_t* s2b = (ushort_t*)alloc((size_t)Bn * 128 * Dn / 2);
  ushort_t* s3b = (ushort_t*)alloc((size_t)Bn * 32 * Dn / 2);
  ushort_t* xpb = (ushort_t*)alloc((size_t)Bn * 32 * Dn / 2);
  ushort_t* xu0b = (ushort_t*)alloc((size_t)Bn * 128 * Dn / 2);
  ushort_t* xu1b = (ushort_t*)alloc((size_t)Bn * 512 * Dn / 2);
  ushort_t* qd_b = (ushort_t*)alloc(512 * 256 / 2);
  ushort_t* lqb0 = (ushort_t*)alloc(512 * 256 / 2);
  ushort_t* lqb1 = (ushort_t*)alloc(128 * 256 / 2);
  ushort_t* lqb2 = (ushort_t*)alloc(32 * 256 / 2);
  ushort_t* in_wT = (ushort_t*)alloc(256 * SnP / 2);
  ushort_t* downT = (ushort_t*)alloc(12 * 65536 / 2);
  ushort_t* upT = (ushort_t*)alloc(12 * 65536 / 2);
  ushort_t* predT = (ushort_t*)alloc(65536 / 2);
  ushort_t* outT = (ushort_t*)alloc(96 * 256 / 2);
  ushort_t* q_bf = (ushort_t*)alloc((size_t)Bn * 2048 * Dn / 2);  // also o1, xph
  ushort_t* k_bf = (ushort_t*)alloc((size_t)Bn * 2048 * Dn / 2);
  ushort_t* vT = (ushort_t*)alloc((size_t)Bn * 2048 * Dn / 2);

  ushort_t* xnT = (ushort_t*)attn;
  ushort_t* attn_b = (ushort_t*)sbuf;
  float* o2 = sbuf;
  double* covpart = (double*)sbuf;
  const float scale = 0.0625f;
  const float* npf = nullptr;

  // ---- prep: stats, normalize+transpose input, weight converts ----
  instnorm_stats<<<dim3(Cn / 256, Bn), 256, 0, stream>>>(x_enc, mean, stdevv);
  normT_kernel<<<dim3(Cn / 32, SnP / 32, Bn), 256, 0, stream>>>(x_enc, xnT, mean,
                                                                stdevv);
  cvtT_kernel<<<dim3(8, 8, 12), 256, 0, stream>>>(down_w, downT, 256, 256, 256);
  cvtT_kernel<<<dim3(8, 8, 12), 256, 0, stream>>>(up_w, upT, 256, 256, 256);
  cvtT_kernel<<<dim3(8, 8, 1), 256, 0, stream>>>(pred_w, predT, 256, 256, 256);
  cvtT_kernel<<<dim3(8, SnP / 32, 1), 256, 0, stream>>>(in_w, in_wT, Sn, 256, SnP);
  cvtT_kernel<<<dim3(3, 8, 1), 256, 0, stream>>>(out_w, outT, 256, Pn, 256);
  cvt_bf<<<512, 256, 0, stream>>>(lq[0], lqb0, 512 * 256);
  cvt_bf<<<128, 256, 0, stream>>>(lq[1], lqb1, 128 * 256);
  cvt_bf<<<32, 256, 0, stream>>>(lq[2], lqb2, 32 * 256);

  // ---- h = xn^T @ in_w + b : bf16 out (K padded to 736) ----
  gemm_bf<2><<<dim3(2, 16, Bn), 256, 0, stream>>>(
      xnT, in_wT, Cn, Dn, SnP, SnP, SnP, (ll)Cn * SnP, 0, in_b, 1.f,
      nullptr, 0, 0, h_bf, Dn, (ll)Cn * Dn);

  ushort_t* lqb[3] = {lqb0, lqb1, lqb2};
  float* skf[3] = {s1, s2, s3};
  ushort_t* skb[3] = {s1b, s2b, s3b};
  int Ls[4] = {2048, 512, 128, 32};
  const ushort_t* xinb = h_bf;

  // ---------------- down layers ----------------
  for (int i = 0; i < 3; ++i) {
    int L = Ls[i], Lq = Ls[i + 1];
    const ushort_t* WqT = downT + (size_t)(i * 4 + 0) * 65536;
    const ushort_t* WkT = downT + (size_t)(i * 4 + 1) * 65536;
    const ushort_t* WvT = downT + (size_t)(i * 4 + 2) * 65536;
    const ushort_t* WoT = downT + (size_t)(i * 4 + 3) * 65536;
    const float* bq = down_b + (i * 4 + 0) * 256;
    const float* bk = down_b + (i * 4 + 1) * 256;
    const float* bv = down_b + (i * 4 + 2) * 256;
    const float* bo = down_b + (i * 4 + 3) * 256;

    gemm_bf<2><<<dim3(2, CDIV(Lq, 128), 1), 256, 0, stream>>>(
        lqb[i], WqT, Lq, Dn, Dn, Dn, Dn, 0, 0, bq, 1.f, nullptr, 0, 0, qd_b, Dn, 0);
    gemm_bf<2><<<dim3(2, (Bn * L) / 128, 1), 256, 0, stream>>>(
        xinb, WkT, Bn * L, Dn, Dn, Dn, Dn, 0, 0, bk, 1.f, nullptr, 0, 0, k_bf, Dn, 0);
    gemm_bf<4><<<dim3(2, L / 128, Bn), 256, 0, stream>>>(
        xinb, WvT, L, Dn, Dn, Dn, Dn, (ll)L * Dn, 0, bv, 1.f, nullptr, 0, 0,
        vT, L, (ll)Dn * L);
    gemm_bf<1><<<dim3(L / 128, CDIV(Lq, 128), Bn), 256, 0, stream>>>(
        qd_b, k_bf, Lq, L, Dn, Dn, Dn, 0, (ll)L * Dn, npf, scale,
        attn, L, (ll)Lq * L, nullptr, 0, 0);
    if (L == 2048) softmax_bf<2048><<<Bn * Lq, 256, 0, stream>>>(attn, attn_b);
    else if (L == 512) softmax_bf<512><<<Bn * Lq, 256, 0, stream>>>(attn, attn_b);
    else softmax_bf<128><<<Bn * Lq, 256, 0, stream>>>(attn, attn_b);
    gemm_bf<2><<<dim3(2, CDIV(Lq, 128), Bn), 256, 0, stream>>>(
        attn_b, vT, Lq, Dn, L, L, L, (ll)Lq * L, (ll)Dn * L, npf, 1.f,
        nullptr, 0, 0, q_bf, Dn, (ll)Lq * Dn);
    gemm_bf<1><<<dim3(2, CDIV(Bn * Lq, 128), 1), 256, 0, stream>>>(
        q_bf, WoT, Bn * Lq, Dn, Dn, Dn, Dn, 0, 0, bo, 1.f, o2, Dn, 0, nullptr, 0, 0);
    ln_kernel<<<Bn * Lq, 256, 0, stream>>>(o2, nullptr, skf[i], skb[i], 0,
                                           down_ln + (i * 2 + 0) * 256,
                                           down_ln + (i * 2 + 1) * 256);
    xinb = skb[i];
  }

  // ------- covariance loss (64-tile lower-tri Gram + NB=32 Cholesky) ---------
  int nrs[3] = {Bn * 512, Bn * 128, Bn * 32};
  int nzs[3] = {64, 32, 16};
  for (int j = 0; j < 3; ++j) {
    int nr = nrs[j];
    colstat_partial<<<256, 256, 0, stream>>>(skf[j], part, nr);
    colstat_final<<<1, 256, 0, stream>>>(part, cmean, cistd, nr);
    cov_gram<<<dim3(10, nzs[j]), 256, 0, stream>>>(skf[j], cmean, cistd, covpart,
                                                   nr, nzs[j]);
    cov_reduce<<<dim3(10, 16), 256, 0, stream>>>(covpart, covd + (size_t)j * 65536,
                                                 1.0 / (double)(nr - 1), nzs[j]);
  }
  for (int kb = 0; kb < 8; ++kb) {
    chol_step_a<<<3, 256, 0, stream>>>(covd, kb * 32);
    int T = 7 - kb;
    if (T > 0)
      chol_step_b<<<dim3(T * (T + 1) / 2, 3), 256, 0, stream>>>(covd, kb * 32);
  }
  logdet_diag<<<3, 256, 0, stream>>>(covd, ld);
  cov_final<<<1, 1, 0, stream>>>(ld, out + 6291456);

  // ---------------- pred head ----------------
  gemm_bf<2><<<dim3(2, 8, 1), 256, 0, stream>>>(
      s3b, predT, Bn * 32, Dn, Dn, Dn, Dn, 0, 0, pred_b, 1.f,
      nullptr, 0, 0, xpb, Dn, 0);

  // ---------------- up layers ----------------
  int Lks[3] = {32, 128, 512}, Lqs[3] = {128, 512, 2048};
  const ushort_t* qinb[3] = {s2b, s1b, h_bf};
  const ushort_t* xinbs[3] = {xpb, xu0b, xu1b};
  ushort_t* xoutb[3] = {xu0b, xu1b, q_bf};  // final writes xph into q_bf
  for (int i = 0; i < 3; ++i) {
    int Lk = Lks[i], Lq = Lqs[i];
    const ushort_t* WqT = upT + (size_t)(i * 4 + 0) * 65536;
    const ushort_t* WkT = upT + (size_t)(i * 4 + 1) * 65536;
    const ushort_t* WvT = upT + (size_t)(i * 4 + 2) * 65536;
    const ushort_t* WoT = upT + (size_t)(i * 4 + 3) * 65536;
    const float* bq = up_b + (i * 4 + 0) * 256;
    const float* bk = up_b + (i * 4 + 1) * 256;
    const float* bv = up_b + (i * 4 + 2) * 256;
    const float* bo = up_b + (i * 4 + 3) * 256;

    gemm_bf<2><<<dim3(2, (Bn * Lq) / 128, 1), 256, 0, stream>>>(
        qinb[i], WqT, Bn * Lq, Dn, Dn, Dn, Dn, 0, 0, bq, 1.f,
        nullptr, 0, 0, q_bf, Dn, 0);
    gemm_bf<2><<<dim3(2, CDIV(Bn * Lk, 128), 1), 256, 0, stream>>>(
        xinbs[i], WkT, Bn * Lk, Dn, Dn, Dn, Dn, 0, 0, bk, 1.f,
        nullptr, 0, 0, k_bf, Dn, 0);
    gemm_bf<4><<<dim3(2, CDIV(Lk, 128), Bn), 256, 0, stream>>>(
        xinbs[i], WvT, Lk, Dn, Dn, Dn, Dn, (ll)Lk * Dn, 0, bv, 1.f,
        nullptr, 0, 0, vT, Lk, (ll)Dn * Lk);
    gemm_bf<1><<<dim3(CDIV(Lk, 128), CDIV(Lq, 128), Bn), 256, 0, stream>>>(
        q_bf, k_bf, Lq, Lk, Dn, Dn, Dn, (ll)Lq * Dn, (ll)Lk * Dn, npf, scale,
        attn, Lk, (ll)Lq * Lk, nullptr, 0, 0);
    if (Lk == 32) softmax_bf<32><<<Bn * Lq, 256, 0, stream>>>(attn, attn_b);
    else if (Lk == 128) softmax_bf<128><<<Bn * Lq, 256, 0, stream>>>(attn, attn_b);
    else softmax_bf<512><<<Bn * Lq, 256, 0, stream>>>(attn, attn_b);
    gemm_bf<2><<<dim3(2, CDIV(Lq, 128), Bn), 256, 0, stream>>>(
        attn_b, vT, Lq, Dn, Lk, Lk, Lk, (ll)Lq * Lk, (ll)Dn * Lk, npf, 1.f,
        nullptr, 0, 0, q_bf, Dn, (ll)Lq * Dn);
    gemm_bf<1><<<dim3(2, (Bn * Lq) / 128, 1), 256, 0, stream>>>(
        q_bf, WoT, Bn * Lq, Dn, Dn, Dn, Dn, 0, 0, bo, 1.f, o2, Dn, 0, nullptr, 0, 0);
    ln_kernel<<<Bn * Lq, 256, 0, stream>>>(o2, qinb[i], nullptr, xoutb[i],
                                           (i == 2) ? 1 : 0,
                                           up_ln + (i * 2 + 0) * 256,
                                           up_ln + (i * 2 + 1) * 256);
  }

  // ---------------- output head: MFMA + transpose + de-norm ----------------
  out_mfma<<<dim3(1, (Bn * Cn) / 128, 1), 256, 0, stream>>>(q_bf, outT, out_b,
                                                            stdevv, mean, out);
}

// Round 14
// 1796.103 us; speedup vs baseline: 1.4714x; 1.0020x over previous
//
#include <hip/hip_runtime.h>
#include <hip/hip_bf16.h>
#include <math.h>

#define CDIV(a, b) (((a) + (b) - 1) / (b))
typedef long long ll;
typedef unsigned short ushort_t;

constexpr int Bn = 32;    // batch
constexpr int Sn = 720;   // seq len
constexpr int SnP = 768;  // seq len padded to BK=64 multiple
constexpr int Cn = 2048;  // channels (tokens after transpose)
constexpr int Dn = 256;   // d_model
constexpr int Pn = 96;    // pred len

typedef __attribute__((ext_vector_type(8))) short bf16x8;
typedef __attribute__((ext_vector_type(4))) float f32x4;

__device__ inline ushort_t rne1(float x) {
  unsigned u = __float_as_uint(x);
  u = (u + 0x7fffu + ((u >> 16) & 1u)) >> 16;
  return (ushort_t)u;
}
__device__ inline float b2f(ushort_t u) { return __uint_as_float(((unsigned)u) << 16); }

__device__ inline void gl_lds16(const void* g, void* l) {
  __builtin_amdgcn_global_load_lds(
      (const __attribute__((address_space(1))) void*)g,
      (__attribute__((address_space(3))) void*)l, 16, 0, 0);
}

// ---------------- instance norm stats over time axis ----------------
__global__ void instnorm_stats(const float* __restrict__ x,
                               float* __restrict__ mean, float* __restrict__ stdev) {
  int c = blockIdx.x * 256 + threadIdx.x;
  int b = blockIdx.y;
  const float* p = x + (ll)b * Sn * Cn + c;
  float s = 0.f, q = 0.f;
  for (int t = 0; t < Sn; ++t) {
    float v = p[(ll)t * Cn];
    s += v; q += v * v;
  }
  float m = s / (float)Sn;
  float var = q / (float)Sn - m * m;
  var = fmaxf(var, 0.f);
  mean[b * Cn + c] = m;
  stdev[b * Cn + c] = sqrtf(var + 1e-5f);
}

// ---------------- normalize + transpose: x[b][s][c] -> xnT[b][c][s] bf16 (K-pad)
__global__ void normT_kernel(const float* __restrict__ X, ushort_t* __restrict__ D,
                             const float* __restrict__ mean,
                             const float* __restrict__ stdev) {
  int b = blockIdx.z;
  __shared__ float tl[32][33];
  int t = threadIdx.x;
  int tx = t & 31, ty = t >> 5;
  int s0 = blockIdx.y * 32, c0 = blockIdx.x * 32;
#pragma unroll
  for (int e = 0; e < 4; ++e) {
    int s = s0 + ty + 8 * e;
    tl[ty + 8 * e][tx] = (s < Sn) ? X[((ll)b * Sn + s) * Cn + c0 + tx] : 0.f;
  }
  __syncthreads();
#pragma unroll
  for (int e = 0; e < 4; ++e) {
    int c = c0 + ty + 8 * e, s = s0 + tx;
    if (s < SnP) {
      float mu = mean[b * Cn + c], sd = stdev[b * Cn + c];
      float v = (s < Sn) ? (tl[tx][ty + 8 * e] - mu) / sd : 0.f;
      D[((ll)b * Cn + c) * SnP + s] = rne1(v);
    }
  }
}

// ---------------- transpose-convert: W[K][N] f32 -> WT[N][KP] bf16 ------------
__global__ void cvtT_kernel(const float* __restrict__ S, ushort_t* __restrict__ D,
                            int K, int N, int KP) {
  int z = blockIdx.z;
  S += (ll)z * K * N;
  D += (ll)z * N * KP;
  __shared__ float tl[32][33];
  int t = threadIdx.x;
  int tx = t & 31, ty = t >> 5;
  int k0 = blockIdx.y * 32, n0 = blockIdx.x * 32;
#pragma unroll
  for (int e = 0; e < 4; ++e) {
    int k = k0 + ty + 8 * e;
    tl[ty + 8 * e][tx] = (k < K && n0 + tx < N) ? S[(ll)k * N + n0 + tx] : 0.f;
  }
  __syncthreads();
#pragma unroll
  for (int e = 0; e < 4; ++e) {
    int n = n0 + ty + 8 * e, kk = k0 + tx;
    if (n < N && kk < KP) D[(ll)n * KP + kk] = rne1(tl[tx][ty + 8 * e]);
  }
}

__global__ void cvt_bf(const float* __restrict__ S, ushort_t* __restrict__ D, int n) {
  int i = blockIdx.x * 256 + threadIdx.x;
  if (i < n) D[i] = rne1(S[i]);
}

// ---------------- canonical bf16 MFMA GEMM: C = A[M][K] * B[N][K]^T ----------
// global_load_lds staging; K must be a multiple of BK; OOB rows clamped.
// BK=64 uses XOR row-swizzle (pre-swizzled global source + swizzled read) to
// keep ds_read_b128 conflict-free at 128B row stride; BK=32 is the proven
// linear layout. MODE bits: 1 = f32 C ; 2 = bf16 C ; 4 = bf16 C^T.
template <int MODE, int BK>
__global__ __launch_bounds__(256) void gemm_bf(
    const ushort_t* __restrict__ A, const ushort_t* __restrict__ B,
    int M, int N, int K, int lda, int ldb, ll sA, ll sB,
    const float* __restrict__ bias, float alpha,
    float* __restrict__ Cf, int ldcf, ll sCf,
    ushort_t* __restrict__ Cb, int ldcb, ll sCb) {
  int g = blockIdx.z;
  A += (ll)g * sA;
  B += (ll)g * sB;
  if (MODE & 1) Cf += (ll)g * sCf;
  if (MODE & 6) Cb += (ll)g * sCb;
  __shared__ ushort_t lds_ab[2][128][BK];
  constexpr int LPR = BK / 8;    // lanes per row (16B units per row)
  constexpr int RPC = 512 / BK;  // rows per 1KB chunk
  constexpr int CPT = BK / 4;    // chunks per tile
  constexpr int CPW = BK / 8;    // chunks per wave
  int t = threadIdx.x;
  int m0 = blockIdx.y * 128, n0 = blockIdx.x * 128;
  int w = t >> 6, lane = t & 63;
  int wm = (w >> 1) * 64, wn = (w & 1) * 64;
  int lrow = lane & 15, kq = lane >> 4;
  int srow = lane / LPR;
  int skl = (lane % LPR) * 8;
  f32x4 acc[4][4] = {};
  for (int k0 = 0; k0 < K; k0 += BK) {
#pragma unroll
    for (int cc = 0; cc < CPW; ++cc) {
      int c = w * CPW + cc;
      int tile = c / CPT, rb = (c % CPT) * RPC;
      int row = rb + srow;
      int scol = (BK == 64) ? (skl ^ ((row & 1) * 32)) : skl;
      const ushort_t* src;
      if (tile == 0) {
        int gm = min(m0 + row, M - 1);
        src = &A[(ll)gm * lda + k0 + scol];
      } else {
        int gn = min(n0 + row, N - 1);
        src = &B[(ll)gn * ldb + k0 + scol];
      }
      gl_lds16(src, &lds_ab[tile][rb][0]);
    }
    __syncthreads();
#pragma unroll
    for (int kh = 0; kh < BK / 32; ++kh) {
      bf16x8 af[4], bfr[4];
#pragma unroll
      for (int i = 0; i < 4; ++i) {
        int r = wm + i * 16 + lrow;
        int off = kh * 32 + kq * 8;
        if (BK == 64) off ^= (r & 1) * 32;
        af[i] = *reinterpret_cast<const bf16x8*>(&lds_ab[0][r][off]);
      }
#pragma unroll
      for (int j = 0; j < 4; ++j) {
        int r = wn + j * 16 + lrow;
        int off = kh * 32 + kq * 8;
        if (BK == 64) off ^= (r & 1) * 32;
        bfr[j] = *reinterpret_cast<const bf16x8*>(&lds_ab[1][r][off]);
      }
#pragma unroll
      for (int i = 0; i < 4; ++i)
#pragma unroll
        for (int j = 0; j < 4; ++j)
          acc[i][j] = __builtin_amdgcn_mfma_f32_16x16x32_bf16(af[i], bfr[j],
                                                              acc[i][j], 0, 0, 0);
    }
    __syncthreads();
  }
#pragma unroll
  for (int i = 0; i < 4; ++i) {
    int mb = m0 + wm + i * 16 + kq * 4;
    if (mb >= M) continue;
#pragma unroll
    for (int j = 0; j < 4; ++j) {
      int c = n0 + wn + j * 16 + lrow;
      if (c >= N) continue;
      float bv = bias ? bias[c] : 0.f;
#pragma unroll
      for (int reg = 0; reg < 4; ++reg) {
        int m = mb + reg;
        float v = acc[i][j][reg] * alpha + bv;
        if (MODE & 1) Cf[(ll)m * ldcf + c] = v;
        if (MODE & 2) Cb[(ll)m * ldcb + c] = rne1(v);
        if (MODE & 4) Cb[(ll)c * ldcb + m] = rne1(v);
      }
    }
  }
}

// ---------------- block reduction helper (blockDim = 256) ----------------
__device__ inline float blk_reduce(float v, volatile float* sh, int op) {
  int lane = threadIdx.x & 63, w = threadIdx.x >> 6;
#pragma unroll
  for (int off = 32; off > 0; off >>= 1) {
    float o = __shfl_down(v, off, 64);
    v = op ? fmaxf(v, o) : (v + o);
  }
  __syncthreads();
  if (lane == 0) sh[w] = v;
  __syncthreads();
  float r = op ? fmaxf(fmaxf(sh[0], sh[1]), fmaxf(sh[2], sh[3]))
               : (sh[0] + sh[1] + sh[2] + sh[3]);
  return r;
}

// ---------------- row softmax: f32 scores in, bf16 probs out ----------------
template <int LL>
__global__ void softmax_bf(const float* __restrict__ S, ushort_t* __restrict__ P) {
  constexpr int NE = (LL + 255) / 256;
  __shared__ float sh[4];
  ll row = blockIdx.x;
  const float* p = S + row * (ll)LL;
  ushort_t* q = P + row * (ll)LL;
  int t = threadIdx.x;
  float e[NE];
  float mx = -INFINITY;
#pragma unroll
  for (int k = 0; k < NE; ++k) {
    int i = t + k * 256;
    if (i < LL) { e[k] = p[i]; mx = fmaxf(mx, e[k]); }
  }
  mx = blk_reduce(mx, sh, 1);
  float sum = 0.f;
#pragma unroll
  for (int k = 0; k < NE; ++k) {
    int i = t + k * 256;
    if (i < LL) { e[k] = __expf(e[k] - mx); sum += e[k]; }
  }
  sum = blk_reduce(sum, sh, 0);
  float inv = 1.f / sum;
#pragma unroll
  for (int k = 0; k < NE; ++k) {
    int i = t + k * 256;
    if (i < LL) q[i] = rne1(e[k] * inv);
  }
}

// ---------------- LayerNorm over D=256; optional bf16 residual ----------------
__global__ void ln_kernel(const float* __restrict__ X, const ushort_t* __restrict__ RESb,
                          float* __restrict__ Yf, ushort_t* __restrict__ Yb, int postadd,
                          const float* __restrict__ gamma, const float* __restrict__ beta) {
  __shared__ float sh[4];
  ll row = blockIdx.x;
  int t = threadIdx.x;
  float r = RESb ? b2f(RESb[row * Dn + t]) : 0.f;
  float v = X[row * Dn + t] + r;
  float m = blk_reduce(v, sh, 0) * (1.f / (float)Dn);
  float d = v - m;
  float var = blk_reduce(d * d, sh, 0) * (1.f / (float)Dn);
  float y = d * rsqrtf(var + 1e-5f) * gamma[t] + beta[t];
  if (Yf) Yf[row * Dn + t] = y;
  if (Yb) Yb[row * Dn + t] = rne1(y + (postadd ? r : 0.f));
}

// ---------------- covariance column stats (f64 partials) ----------------
__global__ void colstat_partial(const float* __restrict__ X, double* __restrict__ part,
                                int nrows) {
  int blk = blockIdx.x, t = threadIdx.x;
  int chunk = CDIV(nrows, 256);
  int r0 = blk * chunk, r1 = min(nrows, r0 + chunk);
  double s = 0.0, q = 0.0;
  for (int r = r0; r < r1; ++r) {
    double v = (double)X[(ll)r * Dn + t];
    s += v; q += v * v;
  }
  part[blk * 512 + t] = s;
  part[blk * 512 + 256 + t] = q;
}

__global__ void colstat_final(const double* __restrict__ part, float* __restrict__ cmean,
                              float* __restrict__ cistd, int nrows) {
  int t = threadIdx.x;
  double s = 0.0, q = 0.0;
  for (int b = 0; b < 256; ++b) {
    s += part[b * 512 + t];
    q += part[b * 512 + 256 + t];
  }
  double m = s / (double)nrows;
  double var = (q - (double)nrows * m * m) / (double)(nrows - 1);
  var = fmax(var, 0.0);
  cmean[t] = (float)m;
  cistd[t] = (float)(1.0 / (sqrt(var) + 1e-5));
}

// -------- lower-triangle cov Gram: 64x64 f64 tiles, fused normalize ----------
__global__ __launch_bounds__(256) void cov_gram(const float* __restrict__ X,
                                                const float* __restrict__ cmean,
                                                const float* __restrict__ cistd,
                                                double* __restrict__ part,
                                                int nr, int nz) {
  __shared__ double Am[32][66];
  __shared__ double Bq[32][66];
  __shared__ float cmA[64], ciA[64], cmB[64], ciB[64];
  int tile = blockIdx.x;
  int mi = 0;
  while (tile >= mi + 1) { tile -= mi + 1; ++mi; }
  int nj = tile;  // mi >= nj (4x4 blocks of 64)
  int m0 = mi * 64, n0 = nj * 64;
  bool diag = (mi == nj);
  int z = blockIdx.y;
  int t = threadIdx.x;
  int tx4 = (t & 15) * 4, ty4 = (t >> 4) * 4;
  if (t < 64) { cmA[t] = cmean[m0 + t]; ciA[t] = cistd[m0 + t]; }
  else if (t < 128) { cmB[t - 64] = cmean[n0 + t - 64]; ciB[t - 64] = cistd[n0 + t - 64]; }
  __syncthreads();
  int chunk = nr / nz;
  int kbeg = z * chunk, kend = kbeg + chunk;
  double acc[4][4] = {};
  const double* Bbase = diag ? &Am[0][0] : &Bq[0][0];
  for (int k0 = kbeg; k0 < kend; k0 += 32) {
#pragma unroll
    for (int e = 0; e < 8; ++e) {
      int idx = t + e * 256;
      int kk = idx >> 6, mm = idx & 63;
      float xa = X[(ll)(k0 + kk) * Dn + m0 + mm];
      Am[kk][mm] = (double)((xa - cmA[mm]) * ciA[mm]);
      if (!diag) {
        float xb = X[(ll)(k0 + kk) * Dn + n0 + mm];
        Bq[kk][mm] = (double)((xb - cmB[mm]) * ciB[mm]);
      }
    }
    __syncthreads();
#pragma unroll 4
    for (int kk = 0; kk < 32; ++kk) {
      double a[4], b[4];
#pragma unroll
      for (int q = 0; q < 4; ++q) a[q] = Am[kk][ty4 + q];
#pragma unroll
      for (int q = 0; q < 4; ++q) b[q] = Bbase[kk * 66 + tx4 + q];
#pragma unroll
      for (int i = 0; i < 4; ++i)
#pragma unroll
        for (int j = 0; j < 4; ++j) acc[i][j] += a[i] * b[j];
    }
    __syncthreads();
  }
  ll base = ((ll)z * 10 + blockIdx.x) * 4096;
#pragma unroll
  for (int i = 0; i < 4; ++i)
#pragma unroll
    for (int j = 0; j < 4; ++j)
      part[base + (ty4 + i) * 64 + tx4 + j] = acc[i][j];
}

// reduce split-K partials; grid (10 tiles, 16 segments of 256 elements)
__global__ void cov_reduce(const double* __restrict__ part, double* __restrict__ Cd,
                           double inv, int nz) {
  int tile = blockIdx.x;
  int mi = 0;
  while (tile >= mi + 1) { tile -= mi + 1; ++mi; }
  int nj = tile;
  int e = blockIdx.y * 256 + threadIdx.x;
  int rr = e >> 6, cc = e & 63;
  int m = mi * 64 + rr, n = nj * 64 + cc;
  double s0 = 0.0, s1 = 0.0, s2 = 0.0, s3 = 0.0;
  int z = 0;
  for (; z + 4 <= nz; z += 4) {
    s0 += part[((ll)(z + 0) * 10 + blockIdx.x) * 4096 + e];
    s1 += part[((ll)(z + 1) * 10 + blockIdx.x) * 4096 + e];
    s2 += part[((ll)(z + 2) * 10 + blockIdx.x) * 4096 + e];
    s3 += part[((ll)(z + 3) * 10 + blockIdx.x) * 4096 + e];
  }
  for (; z < nz; ++z) s0 += part[((ll)z * 10 + blockIdx.x) * 4096 + e];
  double s = ((s0 + s1) + (s2 + s3)) * inv + ((m == n) ? 1e-5 : 0.0);
  Cd[m * 256 + n] = s;
}

// ---------------- multi-launch right-looking f64 Cholesky (NB=32) ------------
__global__ __launch_bounds__(256) void chol_step_a(double* __restrict__ mats, int d0) {
  double* A = mats + (ll)blockIdx.x * 65536;
  __shared__ double D[32][33];
  __shared__ double dinv[32];
  int t = threadIdx.x;
  for (int e = t; e < 1024; e += 256) {
    int i = e >> 5, j = e & 31;
    D[i][j] = (j <= i) ? A[(ll)(d0 + i) * 256 + d0 + j] : 0.0;  // upper never computed
  }
  __syncthreads();
  if (t < 32) {
    double x[32];
#pragma unroll
    for (int j = 0; j < 32; ++j) x[j] = D[t][j];
#pragma unroll
    for (int k = 0; k < 32; ++k) {
      double piv = fmax(__shfl(x[k], k, 64), 1e-300);
      double inv = 1.0 / sqrt(piv);
      double lrk = x[k] * inv;  // lane t: l_{t,k}; lane k: d_k
      x[k] = lrk;
#pragma unroll
      for (int j = k + 1; j < 32; ++j) x[j] -= lrk * __shfl(lrk, j, 64);
    }
#pragma unroll
    for (int j = 0; j < 32; ++j) D[t][j] = x[j];
    dinv[t] = 1.0 / x[t];
  }
  __syncthreads();
  // L21 solve: thread t -> row d0+32+t ; y = L11^{-1} a_row
  int r = d0 + 32 + t;
  if (r < 256) {
    double y[32];
#pragma unroll
    for (int j = 0; j < 32; ++j) y[j] = A[(ll)r * 256 + d0 + j];
#pragma unroll
    for (int j = 0; j < 32; ++j) {
      double s = y[j];
#pragma unroll
      for (int i = 0; i < j; ++i) s -= y[i] * D[j][i];
      y[j] = s * dinv[j];
    }
#pragma unroll
    for (int j = 0; j < 32; ++j) A[(ll)r * 256 + d0 + j] = y[j];
  }
  // write factored diag block back (logdet_diag reads diagonal)
  for (int e = t; e < 1024; e += 256)
    A[(ll)(d0 + (e >> 5)) * 256 + d0 + (e & 31)] = D[e >> 5][e & 31];
}

// step B (grid-parallel SYRK): trailing A22 -= L21 L21^T, 32x32 tiles, lower half
__global__ __launch_bounds__(256) void chol_step_b(double* __restrict__ mats, int d0) {
  double* A = mats + (ll)blockIdx.y * 65536;
  int tile = blockIdx.x;
  int i = 0;
  while (tile >= i + 1) { tile -= i + 1; ++i; }
  int j = tile;  // i >= j
  int ri = d0 + 32 + i * 32, rj = d0 + 32 + j * 32;
  __shared__ double Li[32][33];
  __shared__ double Lj[32][33];
  int t = threadIdx.x;
  for (int e = t; e < 1024; e += 256) {
    int rr = e >> 5, kk = e & 31;
    Li[rr][kk] = A[(ll)(ri + rr) * 256 + d0 + kk];
    Lj[rr][kk] = A[(ll)(rj + rr) * 256 + d0 + kk];
  }
  __syncthreads();
  for (int e = t; e < 1024; e += 256) {
    int rr = e >> 5, cc = e & 31;
    double s = 0.0;
#pragma unroll
    for (int k = 0; k < 32; ++k) s += Li[rr][k] * Lj[cc][k];
    A[(ll)(ri + rr) * 256 + rj + cc] -= s;
  }
}

// logdet = 2 * sum log(diag(L)), parallel reduce
__global__ void logdet_diag(const double* __restrict__ mats, double* __restrict__ ld) {
  __shared__ double sh[4];
  const double* A = mats + (ll)blockIdx.x * 65536;
  int t = threadIdx.x;
  double lg = log(A[(ll)t * 257]);
  int lane = t & 63, w = t >> 6;
#pragma unroll
  for (int off = 32; off > 0; off >>= 1) lg += __shfl_down(lg, off, 64);
  if (lane == 0) sh[w] = lg;
  __syncthreads();
  if (t == 0) ld[blockIdx.x] = 2.0 * (sh[0] + sh[1] + sh[2] + sh[3]);
}

__global__ void cov_final(const double* __restrict__ ld, float* __restrict__ outp) {
  outp[0] = (float)(-0.1 / (3.0 * 256.0) * (ld[0] + ld[1] + ld[2]));
}

// ---------------- output head: xph[M][256] @ outT[96][256]^T, scatter+denorm --
__global__ __launch_bounds__(256) void out_mfma(
    const ushort_t* __restrict__ A, const ushort_t* __restrict__ B,
    const float* __restrict__ bias, const float* __restrict__ stdev,
    const float* __restrict__ mean, float* __restrict__ out) {
  constexpr int M = Bn * Cn, N = Pn, K = Dn;
  __shared__ ushort_t lds_ab[2][128][32];
  int t = threadIdx.x;
  int m0 = blockIdx.y * 128;
  int w = t >> 6, lane = t & 63;
  int wm = (w >> 1) * 64, wn = (w & 1) * 64;
  int lrow = lane & 15, kq = lane >> 4;
  int srow = lane >> 2, skcol = (lane & 3) * 8;
  f32x4 acc[4][4] = {};
  for (int k0 = 0; k0 < K; k0 += 32) {
#pragma unroll
    for (int cc = 0; cc < 4; ++cc) {
      int c = w * 4 + cc;
      int tile = c >> 3, rb = (c & 7) * 16;
      int row = rb + srow;
      const ushort_t* src;
      if (tile == 0) {
        src = &A[(ll)(m0 + row) * K + k0 + skcol];
      } else {
        int gn = min(row, N - 1);
        src = &B[(ll)gn * K + k0 + skcol];
      }
      gl_lds16(src, &lds_ab[tile][rb][0]);
    }
    __syncthreads();
    bf16x8 af[4], bfr[4];
#pragma unroll
    for (int i = 0; i < 4; ++i)
      af[i] = *reinterpret_cast<const bf16x8*>(&lds_ab[0][wm + i * 16 + lrow][kq * 8]);
#pragma unroll
    for (int j = 0; j < 4; ++j)
      bfr[j] = *reinterpret_cast<const bf16x8*>(&lds_ab[1][wn + j * 16 + lrow][kq * 8]);
#pragma unroll
    for (int i = 0; i < 4; ++i)
#pragma unroll
      for (int j = 0; j < 4; ++j)
        acc[i][j] = __builtin_amdgcn_mfma_f32_16x16x32_bf16(af[i], bfr[j],
                                                            acc[i][j], 0, 0, 0);
    __syncthreads();
  }
#pragma unroll
  for (int i = 0; i < 4; ++i) {
    int mb = m0 + wm + i * 16 + kq * 4;
#pragma unroll
    for (int j = 0; j < 4; ++j) {
      int p = wn + j * 16 + lrow;
      if (p >= N) continue;
      float bv = bias[p];
#pragma unroll
      for (int reg = 0; reg < 4; ++reg) {
        int m = mb + reg;
        int b = m >> 11, c = m & 2047;
        float v = acc[i][j][reg] + bv;
        out[((ll)(b * Pn + p)) * Cn + c] = v * stdev[m] + mean[m];
      }
    }
  }
}

// =====================================================================
extern "C" void kernel_launch(void* const* d_in, const int* in_sizes, int n_in,
                              void* d_out, int out_size, void* d_ws, size_t ws_size,
                              hipStream_t stream) {
  (void)in_sizes; (void)n_in; (void)out_size; (void)ws_size;
  const float* x_enc = (const float*)d_in[0];
  const float* in_w = (const float*)d_in[4];
  const float* in_b = (const float*)d_in[5];
  const float* lq[3] = {(const float*)d_in[6], (const float*)d_in[7],
                        (const float*)d_in[8]};
  const float* down_w = (const float*)d_in[9];
  const float* down_b = (const float*)d_in[10];
  const float* down_ln = (const float*)d_in[11];
  const float* pred_w = (const float*)d_in[12];
  const float* pred_b = (const float*)d_in[13];
  const float* up_w = (const float*)d_in[14];
  const float* up_b = (const float*)d_in[15];
  const float* up_ln = (const float*)d_in[16];
  const float* out_w = (const float*)d_in[17];
  const float* out_b = (const float*)d_in[18];
  float* out = (float*)d_out;

  float* ws = (float*)d_ws;
  size_t off = 0;
  auto alloc = [&](size_t n) {
    n = (n + 3) & ~(size_t)3;  // 16B alignment
    float* p = ws + off;
    off += n;
    return p;
  };
  float* mean = alloc((size_t)Bn * Cn);
  float* stdevv = alloc((size_t)Bn * Cn);
  float* cmean = alloc(256);
  float* cistd = alloc(256);
  double* part = (double*)alloc(256 * 512 * 2);
  double* ld = (double*)alloc(32);
  double* covd = (double*)alloc(3 * 65536 * 2);
  float* s1 = alloc((size_t)Bn * 512 * Dn);
  float* s2 = alloc((size_t)Bn * 128 * Dn);
  float* s3 = alloc((size_t)Bn * 32 * Dn);
  float* attn = alloc((size_t)Bn * 512 * 2048);     // f32 scores; also xnT(bf16)
  float* sbuf = alloc((size_t)16777216);            // attn_bf / o2 f32 / covpart
  ushort_t* h_bf = (ushort_t*)alloc((size_t)Bn * Cn * Dn / 2);
  ushort_t* s1b = (ushort_t*)alloc((size_t)Bn * 512 * Dn / 2);
  ushort_t* s2b = (ushort_t*)alloc((size_t)Bn * 128 * Dn / 2);
  ushort_t* s3b = (ushort_t*)alloc((size_t)Bn * 32 * Dn / 2);
  ushort_t* xpb = (ushort_t*)alloc((size_t)Bn * 32 * Dn / 2);
  ushort_t* xu0b = (ushort_t*)alloc((size_t)Bn * 128 * Dn / 2);
  ushort_t* xu1b = (ushort_t*)alloc((size_t)Bn * 512 * Dn / 2);
  ushort_t* qd_b = (ushort_t*)alloc(512 * 256 / 2);
  ushort_t* lqb0 = (ushort_t*)alloc(512 * 256 / 2);
  ushort_t* lqb1 = (ushort_t*)alloc(128 * 256 / 2);
  ushort_t* lqb2 = (ushort_t*)alloc(32 * 256 / 2);
  ushort_t* in_wT = (ushort_t*)alloc(256 * SnP / 2);
  ushort_t* downT = (ushort_t*)alloc(12 * 65536 / 2);
  ushort_t* upT = (ushort_t*)alloc(12 * 65536 / 2);
  ushort_t* predT = (ushort_t*)alloc(65536 / 2);
  ushort_t* outT = (ushort_t*)alloc(96 * 256 / 2);
  ushort_t* q_bf = (ushort_t*)alloc((size_t)Bn * 2048 * Dn / 2);  // also o1, xph
  ushort_t* k_bf = (ushort_t*)alloc((size_t)Bn * 2048 * Dn / 2);
  ushort_t* vT = (ushort_t*)alloc((size_t)Bn * 2048 * Dn / 2);

  ushort_t* xnT = (ushort_t*)attn;
  ushort_t* attn_b = (ushort_t*)sbuf;
  float* o2 = sbuf;
  double* covpart = (double*)sbuf;
  const float scale = 0.0625f;
  const float* npf = nullptr;

  // ---- prep: stats, normalize+transpose input, weight converts ----
  instnorm_stats<<<dim3(Cn / 256, Bn), 256, 0, stream>>>(x_enc, mean, stdevv);
  normT_kernel<<<dim3(Cn / 32, SnP / 32, Bn), 256, 0, stream>>>(x_enc, xnT, mean,
                                                                stdevv);
  cvtT_kernel<<<dim3(8, 8, 12), 256, 0, stream>>>(down_w, downT, 256, 256, 256);
  cvtT_kernel<<<dim3(8, 8, 12), 256, 0, stream>>>(up_w, upT, 256, 256, 256);
  cvtT_kernel<<<dim3(8, 8, 1), 256, 0, stream>>>(pred_w, predT, 256, 256, 256);
  cvtT_kernel<<<dim3(8, SnP / 32, 1), 256, 0, stream>>>(in_w, in_wT, Sn, 256, SnP);
  cvtT_kernel<<<dim3(3, 8, 1), 256, 0, stream>>>(out_w, outT, 256, Pn, 256);
  cvt_bf<<<512, 256, 0, stream>>>(lq[0], lqb0, 512 * 256);
  cvt_bf<<<128, 256, 0, stream>>>(lq[1], lqb1, 128 * 256);
  cvt_bf<<<32, 256, 0, stream>>>(lq[2], lqb2, 32 * 256);

  // ---- h = xn^T @ in_w + b : bf16 out (K padded to 768) ----
  gemm_bf<2, 64><<<dim3(2, 16, Bn), 256, 0, stream>>>(
      xnT, in_wT, Cn, Dn, SnP, SnP, SnP, (ll)Cn * SnP, 0, in_b, 1.f,
      nullptr, 0, 0, h_bf, Dn, (ll)Cn * Dn);

  ushort_t* lqb[3] = {lqb0, lqb1, lqb2};
  float* skf[3] = {s1, s2, s3};
  ushort_t* skb[3] = {s1b, s2b, s3b};
  int Ls[4] = {2048, 512, 128, 32};
  const ushort_t* xinb = h_bf;

  // ---------------- down layers ----------------
  for (int i = 0; i < 3; ++i) {
    int L = Ls[i], Lq = Ls[i + 1];
    const ushort_t* WqT = downT + (size_t)(i * 4 + 0) * 65536;
    const ushort_t* WkT = downT + (size_t)(i * 4 + 1) * 65536;
    const ushort_t* WvT = downT + (size_t)(i * 4 + 2) * 65536;
    const ushort_t* WoT = downT + (size_t)(i * 4 + 3) * 65536;
    const float* bq = down_b + (i * 4 + 0) * 256;
    const float* bk = down_b + (i * 4 + 1) * 256;
    const float* bv = down_b + (i * 4 + 2) * 256;
    const float* bo = down_b + (i * 4 + 3) * 256;

    gemm_bf<2, 64><<<dim3(2, CDIV(Lq, 128), 1), 256, 0, stream>>>(
        lqb[i], WqT, Lq, Dn, Dn, Dn, Dn, 0, 0, bq, 1.f, nullptr, 0, 0, qd_b, Dn, 0);
    gemm_bf<2, 64><<<dim3(2, (Bn * L) / 128, 1), 256, 0, stream>>>(
        xinb, WkT, Bn * L, Dn, Dn, Dn, Dn, 0, 0, bk, 1.f, nullptr, 0, 0, k_bf, Dn, 0);
    gemm_bf<4, 64><<<dim3(2, L / 128, Bn), 256, 0, stream>>>(
        xinb, WvT, L, Dn, Dn, Dn, Dn, (ll)L * Dn, 0, bv, 1.f, nullptr, 0, 0,
        vT, L, (ll)Dn * L);
    gemm_bf<1, 64><<<dim3(L / 128, CDIV(Lq, 128), Bn), 256, 0, stream>>>(
        qd_b, k_bf, Lq, L, Dn, Dn, Dn, 0, (ll)L * Dn, npf, scale,
        attn, L, (ll)Lq * L, nullptr, 0, 0);
    if (L == 2048) softmax_bf<2048><<<Bn * Lq, 256, 0, stream>>>(attn, attn_b);
    else if (L == 512) softmax_bf<512><<<Bn * Lq, 256, 0, stream>>>(attn, attn_b);
    else softmax_bf<128><<<Bn * Lq, 256, 0, stream>>>(attn, attn_b);
    gemm_bf<2, 64><<<dim3(2, CDIV(Lq, 128), Bn), 256, 0, stream>>>(
        attn_b, vT, Lq, Dn, L, L, L, (ll)Lq * L, (ll)Dn * L, npf, 1.f,
        nullptr, 0, 0, q_bf, Dn, (ll)Lq * Dn);
    gemm_bf<1, 64><<<dim3(2, CDIV(Bn * Lq, 128), 1), 256, 0, stream>>>(
        q_bf, WoT, Bn * Lq, Dn, Dn, Dn, Dn, 0, 0, bo, 1.f, o2, Dn, 0, nullptr, 0, 0);
    ln_kernel<<<Bn * Lq, 256, 0, stream>>>(o2, nullptr, skf[i], skb[i], 0,
                                           down_ln + (i * 2 + 0) * 256,
                                           down_ln + (i * 2 + 1) * 256);
    xinb = skb[i];
  }

  // ------- covariance loss (64-tile lower-tri Gram + NB=32 Cholesky) ---------
  int nrs[3] = {Bn * 512, Bn * 128, Bn * 32};
  int nzs[3] = {64, 32, 16};
  for (int j = 0; j < 3; ++j) {
    int nr = nrs[j];
    colstat_partial<<<256, 256, 0, stream>>>(skf[j], part, nr);
    colstat_final<<<1, 256, 0, stream>>>(part, cmean, cistd, nr);
    cov_gram<<<dim3(10, nzs[j]), 256, 0, stream>>>(skf[j], cmean, cistd, covpart,
                                                   nr, nzs[j]);
    cov_reduce<<<dim3(10, 16), 256, 0, stream>>>(covpart, covd + (size_t)j * 65536,
                                                 1.0 / (double)(nr - 1), nzs[j]);
  }
  for (int kb = 0; kb < 8; ++kb) {
    chol_step_a<<<3, 256, 0, stream>>>(covd, kb * 32);
    int T = 7 - kb;
    if (T > 0)
      chol_step_b<<<dim3(T * (T + 1) / 2, 3), 256, 0, stream>>>(covd, kb * 32);
  }
  logdet_diag<<<3, 256, 0, stream>>>(covd, ld);
  cov_final<<<1, 1, 0, stream>>>(ld, out + 6291456);

  // ---------------- pred head ----------------
  gemm_bf<2, 64><<<dim3(2, 8, 1), 256, 0, stream>>>(
      s3b, predT, Bn * 32, Dn, Dn, Dn, Dn, 0, 0, pred_b, 1.f,
      nullptr, 0, 0, xpb, Dn, 0);

  // ---------------- up layers ----------------
  int Lks[3] = {32, 128, 512}, Lqs[3] = {128, 512, 2048};
  const ushort_t* qinb[3] = {s2b, s1b, h_bf};
  const ushort_t* xinbs[3] = {xpb, xu0b, xu1b};
  ushort_t* xoutb[3] = {xu0b, xu1b, q_bf};  // final writes xph into q_bf
  for (int i = 0; i < 3; ++i) {
    int Lk = Lks[i], Lq = Lqs[i];
    const ushort_t* WqT = upT + (size_t)(i * 4 + 0) * 65536;
    const ushort_t* WkT = upT + (size_t)(i * 4 + 1) * 65536;
    const ushort_t* WvT = upT + (size_t)(i * 4 + 2) * 65536;
    const ushort_t* WoT = upT + (size_t)(i * 4 + 3) * 65536;
    const float* bq = up_b + (i * 4 + 0) * 256;
    const float* bk = up_b + (i * 4 + 1) * 256;
    const float* bv = up_b + (i * 4 + 2) * 256;
    const float* bo = up_b + (i * 4 + 3) * 256;

    gemm_bf<2, 64><<<dim3(2, (Bn * Lq) / 128, 1), 256, 0, stream>>>(
        qinb[i], WqT, Bn * Lq, Dn, Dn, Dn, Dn, 0, 0, bq, 1.f,
        nullptr, 0, 0, q_bf, Dn, 0);
    gemm_bf<2, 64><<<dim3(2, CDIV(Bn * Lk, 128), 1), 256, 0, stream>>>(
        xinbs[i], WkT, Bn * Lk, Dn, Dn, Dn, Dn, 0, 0, bk, 1.f,
        nullptr, 0, 0, k_bf, Dn, 0);
    gemm_bf<4, 64><<<dim3(2, CDIV(Lk, 128), Bn), 256, 0, stream>>>(
        xinbs[i], WvT, Lk, Dn, Dn, Dn, Dn, (ll)Lk * Dn, 0, bv, 1.f,
        nullptr, 0, 0, vT, Lk, (ll)Dn * Lk);
    gemm_bf<1, 64><<<dim3(CDIV(Lk, 128), CDIV(Lq, 128), Bn), 256, 0, stream>>>(
        q_bf, k_bf, Lq, Lk, Dn, Dn, Dn, (ll)Lq * Dn, (ll)Lk * Dn, npf, scale,
        attn, Lk, (ll)Lq * Lk, nullptr, 0, 0);
    if (Lk == 32) softmax_bf<32><<<Bn * Lq, 256, 0, stream>>>(attn, attn_b);
    else if (Lk == 128) softmax_bf<128><<<Bn * Lq, 256, 0, stream>>>(attn, attn_b);
    else softmax_bf<512><<<Bn * Lq, 256, 0, stream>>>(attn, attn_b);
    if (Lk == 32) {
      gemm_bf<2, 32><<<dim3(2, CDIV(Lq, 128), Bn), 256, 0, stream>>>(
          attn_b, vT, Lq, Dn, Lk, Lk, Lk, (ll)Lq * Lk, (ll)Dn * Lk, npf, 1.f,
          nullptr, 0, 0, q_bf, Dn, (ll)Lq * Dn);
    } else {
      gemm_bf<2, 64><<<dim3(2, CDIV(Lq, 128), Bn), 256, 0, stream>>>(
          attn_b, vT, Lq, Dn, Lk, Lk, Lk, (ll)Lq * Lk, (ll)Dn * Lk, npf, 1.f,
          nullptr, 0, 0, q_bf, Dn, (ll)Lq * Dn);
    }
    gemm_bf<1, 64><<<dim3(2, (Bn * Lq) / 128, 1), 256, 0, stream>>>(
        q_bf, WoT, Bn * Lq, Dn, Dn, Dn, Dn, 0, 0, bo, 1.f, o2, Dn, 0, nullptr, 0, 0);
    ln_kernel<<<Bn * Lq, 256, 0, stream>>>(o2, qinb[i], nullptr, xoutb[i],
                                           (i == 2) ? 1 : 0,
                                           up_ln + (i * 2 + 0) * 256,
                                           up_ln + (i * 2 + 1) * 256);
  }

  // ---------------- output head: MFMA + transpose + de-norm ----------------
  out_mfma<<<dim3(1, (Bn * Cn) / 128, 1), 256, 0, stream>>>(q_bf, outT, out_b,
                                                            stdevv, mean, out);
}

// Round 15
// 1708.826 us; speedup vs baseline: 1.5466x; 1.0511x over previous
//
#include <hip/hip_runtime.h>
#include <hip/hip_bf16.h>
#include <math.h>

#define CDIV(a, b) (((a) + (b) - 1) / (b))
typedef long long ll;
typedef unsigned short ushort_t;

constexpr int Bn = 32;    // batch
constexpr int Sn = 720;   // seq len
constexpr int SnP = 768;  // seq len padded to BK=64 multiple
constexpr int Cn = 2048;  // channels (tokens after transpose)
constexpr int Dn = 256;   // d_model
constexpr int Pn = 96;    // pred len

typedef __attribute__((ext_vector_type(8))) short bf16x8;
typedef __attribute__((ext_vector_type(4))) float f32x4;

__device__ inline ushort_t rne1(float x) {
  unsigned u = __float_as_uint(x);
  u = (u + 0x7fffu + ((u >> 16) & 1u)) >> 16;
  return (ushort_t)u;
}
__device__ inline float b2f(ushort_t u) { return __uint_as_float(((unsigned)u) << 16); }

__device__ inline void gl_lds16(const void* g, void* l) {
  __builtin_amdgcn_global_load_lds(
      (const __attribute__((address_space(1))) void*)g,
      (__attribute__((address_space(3))) void*)l, 16, 0, 0);
}

// ---------------- instance norm stats over time axis ----------------
__global__ void instnorm_stats(const float* __restrict__ x,
                               float* __restrict__ mean, float* __restrict__ stdev) {
  int c = blockIdx.x * 256 + threadIdx.x;
  int b = blockIdx.y;
  const float* p = x + (ll)b * Sn * Cn + c;
  float s = 0.f, q = 0.f;
  for (int t = 0; t < Sn; ++t) {
    float v = p[(ll)t * Cn];
    s += v; q += v * v;
  }
  float m = s / (float)Sn;
  float var = q / (float)Sn - m * m;
  var = fmaxf(var, 0.f);
  mean[b * Cn + c] = m;
  stdev[b * Cn + c] = sqrtf(var + 1e-5f);
}

// ---------------- normalize + transpose: x[b][s][c] -> xnT[b][c][s] bf16 (K-pad)
__global__ void normT_kernel(const float* __restrict__ X, ushort_t* __restrict__ D,
                             const float* __restrict__ mean,
                             const float* __restrict__ stdev) {
  int b = blockIdx.z;
  __shared__ float tl[32][33];
  int t = threadIdx.x;
  int tx = t & 31, ty = t >> 5;
  int s0 = blockIdx.y * 32, c0 = blockIdx.x * 32;
#pragma unroll
  for (int e = 0; e < 4; ++e) {
    int s = s0 + ty + 8 * e;
    tl[ty + 8 * e][tx] = (s < Sn) ? X[((ll)b * Sn + s) * Cn + c0 + tx] : 0.f;
  }
  __syncthreads();
#pragma unroll
  for (int e = 0; e < 4; ++e) {
    int c = c0 + ty + 8 * e, s = s0 + tx;
    if (s < SnP) {
      float mu = mean[b * Cn + c], sd = stdev[b * Cn + c];
      float v = (s < Sn) ? (tl[tx][ty + 8 * e] - mu) / sd : 0.f;
      D[((ll)b * Cn + c) * SnP + s] = rne1(v);
    }
  }
}

// ---------------- transpose-convert: W[K][N] f32 -> WT[N][KP] bf16 ------------
__global__ void cvtT_kernel(const float* __restrict__ S, ushort_t* __restrict__ D,
                            int K, int N, int KP) {
  int z = blockIdx.z;
  S += (ll)z * K * N;
  D += (ll)z * N * KP;
  __shared__ float tl[32][33];
  int t = threadIdx.x;
  int tx = t & 31, ty = t >> 5;
  int k0 = blockIdx.y * 32, n0 = blockIdx.x * 32;
#pragma unroll
  for (int e = 0; e < 4; ++e) {
    int k = k0 + ty + 8 * e;
    tl[ty + 8 * e][tx] = (k < K && n0 + tx < N) ? S[(ll)k * N + n0 + tx] : 0.f;
  }
  __syncthreads();
#pragma unroll
  for (int e = 0; e < 4; ++e) {
    int n = n0 + ty + 8 * e, kk = k0 + tx;
    if (n < N && kk < KP) D[(ll)n * KP + kk] = rne1(tl[tx][ty + 8 * e]);
  }
}

__global__ void cvt_bf(const float* __restrict__ S, ushort_t* __restrict__ D, int n) {
  int i = blockIdx.x * 256 + threadIdx.x;
  if (i < n) D[i] = rne1(S[i]);
}

// ---------------- canonical bf16 MFMA GEMM: C = A[M][K] * B[N][K]^T ----------
// global_load_lds staging; K must be a multiple of BK; OOB rows clamped.
// MODE bits: 1 = f32 C ; 2 = bf16 C ; 4 = bf16 C^T ;
//            8 = fused KV: c<256 -> bf16 C (Cb), c>=256 -> bf16 C^T (via Cf ptr).
template <int MODE, int BK>
__global__ __launch_bounds__(256) void gemm_bf(
    const ushort_t* __restrict__ A, const ushort_t* __restrict__ B,
    int M, int N, int K, int lda, int ldb, ll sA, ll sB,
    const float* __restrict__ bias, float alpha,
    float* __restrict__ Cf, int ldcf, ll sCf,
    ushort_t* __restrict__ Cb, int ldcb, ll sCb) {
  int g = blockIdx.z;
  A += (ll)g * sA;
  B += (ll)g * sB;
  if (MODE & 1) Cf += (ll)g * sCf;
  if (MODE & 14) Cb += (ll)g * sCb;
  ushort_t* Vt = nullptr;
  if (MODE & 8) Vt = (ushort_t*)Cf + (ll)g * sCf;
  __shared__ ushort_t lds_ab[2][128][BK];
  constexpr int LPR = BK / 8;    // lanes per row (16B units per row)
  constexpr int RPC = 512 / BK;  // rows per 1KB chunk
  constexpr int CPT = BK / 4;    // chunks per tile
  constexpr int CPW = BK / 8;    // chunks per wave
  int t = threadIdx.x;
  int m0 = blockIdx.y * 128, n0 = blockIdx.x * 128;
  int w = t >> 6, lane = t & 63;
  int wm = (w >> 1) * 64, wn = (w & 1) * 64;
  int lrow = lane & 15, kq = lane >> 4;
  int srow = lane / LPR;
  int skl = (lane % LPR) * 8;
  f32x4 acc[4][4] = {};
  for (int k0 = 0; k0 < K; k0 += BK) {
#pragma unroll
    for (int cc = 0; cc < CPW; ++cc) {
      int c = w * CPW + cc;
      int tile = c / CPT, rb = (c % CPT) * RPC;
      int row = rb + srow;
      int scol = (BK == 64) ? (skl ^ ((row & 1) * 32)) : skl;
      const ushort_t* src;
      if (tile == 0) {
        int gm = min(m0 + row, M - 1);
        src = &A[(ll)gm * lda + k0 + scol];
      } else {
        int gn = min(n0 + row, N - 1);
        src = &B[(ll)gn * ldb + k0 + scol];
      }
      gl_lds16(src, &lds_ab[tile][rb][0]);
    }
    __syncthreads();
#pragma unroll
    for (int kh = 0; kh < BK / 32; ++kh) {
      bf16x8 af[4], bfr[4];
#pragma unroll
      for (int i = 0; i < 4; ++i) {
        int r = wm + i * 16 + lrow;
        int off = kh * 32 + kq * 8;
        if (BK == 64) off ^= (r & 1) * 32;
        af[i] = *reinterpret_cast<const bf16x8*>(&lds_ab[0][r][off]);
      }
#pragma unroll
      for (int j = 0; j < 4; ++j) {
        int r = wn + j * 16 + lrow;
        int off = kh * 32 + kq * 8;
        if (BK == 64) off ^= (r & 1) * 32;
        bfr[j] = *reinterpret_cast<const bf16x8*>(&lds_ab[1][r][off]);
      }
#pragma unroll
      for (int i = 0; i < 4; ++i)
#pragma unroll
        for (int j = 0; j < 4; ++j)
          acc[i][j] = __builtin_amdgcn_mfma_f32_16x16x32_bf16(af[i], bfr[j],
                                                              acc[i][j], 0, 0, 0);
    }
    __syncthreads();
  }
#pragma unroll
  for (int i = 0; i < 4; ++i) {
    int mb = m0 + wm + i * 16 + kq * 4;
    if (mb >= M) continue;
#pragma unroll
    for (int j = 0; j < 4; ++j) {
      int c = n0 + wn + j * 16 + lrow;
      if (c >= N) continue;
      float bv = bias ? bias[c] : 0.f;
#pragma unroll
      for (int reg = 0; reg < 4; ++reg) {
        int m = mb + reg;
        float v = acc[i][j][reg] * alpha + bv;
        if (MODE & 8) {
          if (c < 256) Cb[(ll)m * ldcb + c] = rne1(v);
          else Vt[(ll)(c - 256) * ldcf + m] = rne1(v);
        } else {
          if (MODE & 1) Cf[(ll)m * ldcf + c] = v;
          if (MODE & 2) Cb[(ll)m * ldcb + c] = rne1(v);
          if (MODE & 4) Cb[(ll)c * ldcb + m] = rne1(v);
        }
      }
    }
  }
}

// ---------------- block reduction helper (blockDim = 256) ----------------
__device__ inline float blk_reduce(float v, volatile float* sh, int op) {
  int lane = threadIdx.x & 63, w = threadIdx.x >> 6;
#pragma unroll
  for (int off = 32; off > 0; off >>= 1) {
    float o = __shfl_down(v, off, 64);
    v = op ? fmaxf(v, o) : (v + o);
  }
  __syncthreads();
  if (lane == 0) sh[w] = v;
  __syncthreads();
  float r = op ? fmaxf(fmaxf(sh[0], sh[1]), fmaxf(sh[2], sh[3]))
               : (sh[0] + sh[1] + sh[2] + sh[3]);
  return r;
}

// ---------------- row softmax: f32 scores in, bf16 probs out ----------------
template <int LL>
__global__ void softmax_bf(const float* __restrict__ S, ushort_t* __restrict__ P) {
  constexpr int NE = (LL + 255) / 256;
  __shared__ float sh[4];
  ll row = blockIdx.x;
  const float* p = S + row * (ll)LL;
  ushort_t* q = P + row * (ll)LL;
  int t = threadIdx.x;
  float e[NE];
  float mx = -INFINITY;
#pragma unroll
  for (int k = 0; k < NE; ++k) {
    int i = t + k * 256;
    if (i < LL) { e[k] = p[i]; mx = fmaxf(mx, e[k]); }
  }
  mx = blk_reduce(mx, sh, 1);
  float sum = 0.f;
#pragma unroll
  for (int k = 0; k < NE; ++k) {
    int i = t + k * 256;
    if (i < LL) { e[k] = __expf(e[k] - mx); sum += e[k]; }
  }
  sum = blk_reduce(sum, sh, 0);
  float inv = 1.f / sum;
#pragma unroll
  for (int k = 0; k < NE; ++k) {
    int i = t + k * 256;
    if (i < LL) q[i] = rne1(e[k] * inv);
  }
}

// ---------------- LayerNorm over D=256; optional bf16 residual ----------------
__global__ void ln_kernel(const float* __restrict__ X, const ushort_t* __restrict__ RESb,
                          float* __restrict__ Yf, ushort_t* __restrict__ Yb, int postadd,
                          const float* __restrict__ gamma, const float* __restrict__ beta) {
  __shared__ float sh[4];
  ll row = blockIdx.x;
  int t = threadIdx.x;
  float r = RESb ? b2f(RESb[row * Dn + t]) : 0.f;
  float v = X[row * Dn + t] + r;
  float m = blk_reduce(v, sh, 0) * (1.f / (float)Dn);
  float d = v - m;
  float var = blk_reduce(d * d, sh, 0) * (1.f / (float)Dn);
  float y = d * rsqrtf(var + 1e-5f) * gamma[t] + beta[t];
  if (Yf) Yf[row * Dn + t] = y;
  if (Yb) Yb[row * Dn + t] = rne1(y + (postadd ? r : 0.f));
}

// --------- batched covariance column stats over the 3 skips (f64) -----------
// skips live contiguously from s1: offsets {0, 4194304, 5242880} floats.
__global__ void colstat_partial3(const float* __restrict__ X0,
                                 double* __restrict__ part) {
  int j = blockIdx.y;
  ll joff = (j == 0) ? 0LL : ((j == 1) ? 4194304LL : 5242880LL);
  int nrows = (j == 0) ? 16384 : ((j == 1) ? 4096 : 1024);
  const float* X = X0 + joff;
  int blk = blockIdx.x, t = threadIdx.x;
  int chunk = CDIV(nrows, 256);
  int r0 = blk * chunk, r1 = min(nrows, r0 + chunk);
  double s = 0.0, q = 0.0;
  for (int r = r0; r < r1; ++r) {
    double v = (double)X[(ll)r * Dn + t];
    s += v; q += v * v;
  }
  part[(ll)j * 131072 + blk * 512 + t] = s;
  part[(ll)j * 131072 + blk * 512 + 256 + t] = q;
}

__global__ void colstat_final3(const double* __restrict__ part,
                               float* __restrict__ cmean, float* __restrict__ cistd) {
  int j = blockIdx.x;
  int nrows = (j == 0) ? 16384 : ((j == 1) ? 4096 : 1024);
  int t = threadIdx.x;
  double s = 0.0, q = 0.0;
  for (int b = 0; b < 256; ++b) {
    s += part[(ll)j * 131072 + b * 512 + t];
    q += part[(ll)j * 131072 + b * 512 + 256 + t];
  }
  double m = s / (double)nrows;
  double var = (q - (double)nrows * m * m) / (double)(nrows - 1);
  var = fmax(var, 0.0);
  cmean[j * 256 + t] = (float)m;
  cistd[j * 256 + t] = (float)(1.0 / (sqrt(var) + 1e-5));
}

// -------- batched lower-triangle cov Gram: 64x64 f64 tiles, fused normalize --
// grid (10 tiles, 64 z-slots, 3 skips); z >= nz[j] exits.
__global__ __launch_bounds__(256) void cov_gram3(const float* __restrict__ X0,
                                                 const float* __restrict__ cmean0,
                                                 const float* __restrict__ cistd0,
                                                 double* __restrict__ part) {
  int j = blockIdx.z;
  int nz = (j == 0) ? 64 : ((j == 1) ? 32 : 16);
  int z = blockIdx.y;
  if (z >= nz) return;
  int nr = (j == 0) ? 16384 : ((j == 1) ? 4096 : 1024);
  ll joff = (j == 0) ? 0LL : ((j == 1) ? 4194304LL : 5242880LL);
  const float* X = X0 + joff;
  const float* cmean = cmean0 + j * 256;
  const float* cistd = cistd0 + j * 256;
  __shared__ double Am[32][66];
  __shared__ double Bq[32][66];
  __shared__ float cmA[64], ciA[64], cmB[64], ciB[64];
  int tile = blockIdx.x;
  int mi = 0;
  while (tile >= mi + 1) { tile -= mi + 1; ++mi; }
  int nj = tile;  // mi >= nj (4x4 blocks of 64)
  int m0 = mi * 64, n0 = nj * 64;
  bool diag = (mi == nj);
  int t = threadIdx.x;
  int tx4 = (t & 15) * 4, ty4 = (t >> 4) * 4;
  if (t < 64) { cmA[t] = cmean[m0 + t]; ciA[t] = cistd[m0 + t]; }
  else if (t < 128) { cmB[t - 64] = cmean[n0 + t - 64]; ciB[t - 64] = cistd[n0 + t - 64]; }
  __syncthreads();
  int chunk = nr / nz;
  int kbeg = z * chunk, kend = kbeg + chunk;
  double acc[4][4] = {};
  const double* Bbase = diag ? &Am[0][0] : &Bq[0][0];
  for (int k0 = kbeg; k0 < kend; k0 += 32) {
#pragma unroll
    for (int e = 0; e < 8; ++e) {
      int idx = t + e * 256;
      int kk = idx >> 6, mm = idx & 63;
      float xa = X[(ll)(k0 + kk) * Dn + m0 + mm];
      Am[kk][mm] = (double)((xa - cmA[mm]) * ciA[mm]);
      if (!diag) {
        float xb = X[(ll)(k0 + kk) * Dn + n0 + mm];
        Bq[kk][mm] = (double)((xb - cmB[mm]) * ciB[mm]);
      }
    }
    __syncthreads();
#pragma unroll 4
    for (int kk = 0; kk < 32; ++kk) {
      double a[4], b[4];
#pragma unroll
      for (int q = 0; q < 4; ++q) a[q] = Am[kk][ty4 + q];
#pragma unroll
      for (int q = 0; q < 4; ++q) b[q] = Bbase[kk * 66 + tx4 + q];
#pragma unroll
      for (int i = 0; i < 4; ++i)
#pragma unroll
        for (int jj = 0; jj < 4; ++jj) acc[i][jj] += a[i] * b[jj];
    }
    __syncthreads();
  }
  ll base = ((ll)((j * 64 + z) * 10 + blockIdx.x)) * 4096;
#pragma unroll
  for (int i = 0; i < 4; ++i)
#pragma unroll
    for (int jj = 0; jj < 4; ++jj)
      part[base + (ty4 + i) * 64 + tx4 + jj] = acc[i][jj];
}

// reduce split-K partials; grid (10 tiles, 16 segments, 3 skips)
__global__ void cov_reduce3(const double* __restrict__ part, double* __restrict__ Cd0) {
  int j = blockIdx.z;
  int nz = (j == 0) ? 64 : ((j == 1) ? 32 : 16);
  int nr = (j == 0) ? 16384 : ((j == 1) ? 4096 : 1024);
  double inv = 1.0 / (double)(nr - 1);
  double* Cd = Cd0 + (ll)j * 65536;
  int tile = blockIdx.x;
  int mi = 0;
  while (tile >= mi + 1) { tile -= mi + 1; ++mi; }
  int nj = tile;
  int e = blockIdx.y * 256 + threadIdx.x;
  int rr = e >> 6, cc = e & 63;
  int m = mi * 64 + rr, n = nj * 64 + cc;
  double s0 = 0.0, s1 = 0.0, s2 = 0.0, s3 = 0.0;
  int z = 0;
  for (; z + 4 <= nz; z += 4) {
    s0 += part[((ll)((j * 64 + z + 0) * 10 + blockIdx.x)) * 4096 + e];
    s1 += part[((ll)((j * 64 + z + 1) * 10 + blockIdx.x)) * 4096 + e];
    s2 += part[((ll)((j * 64 + z + 2) * 10 + blockIdx.x)) * 4096 + e];
    s3 += part[((ll)((j * 64 + z + 3) * 10 + blockIdx.x)) * 4096 + e];
  }
  double s = ((s0 + s1) + (s2 + s3)) * inv + ((m == n) ? 1e-5 : 0.0);
  Cd[m * 256 + n] = s;
}

// ---------------- multi-launch right-looking f64 Cholesky (NB=32) ------------
__global__ __launch_bounds__(256) void chol_step_a(double* __restrict__ mats, int d0) {
  double* A = mats + (ll)blockIdx.x * 65536;
  __shared__ double D[32][33];
  __shared__ double dinv[32];
  int t = threadIdx.x;
  for (int e = t; e < 1024; e += 256) {
    int i = e >> 5, j = e & 31;
    D[i][j] = (j <= i) ? A[(ll)(d0 + i) * 256 + d0 + j] : 0.0;  // upper never computed
  }
  __syncthreads();
  if (t < 32) {
    double x[32];
#pragma unroll
    for (int j = 0; j < 32; ++j) x[j] = D[t][j];
#pragma unroll
    for (int k = 0; k < 32; ++k) {
      double piv = fmax(__shfl(x[k], k, 64), 1e-300);
      double inv = 1.0 / sqrt(piv);
      double lrk = x[k] * inv;  // lane t: l_{t,k}; lane k: d_k
      x[k] = lrk;
#pragma unroll
      for (int j = k + 1; j < 32; ++j) x[j] -= lrk * __shfl(lrk, j, 64);
    }
#pragma unroll
    for (int j = 0; j < 32; ++j) D[t][j] = x[j];
    dinv[t] = 1.0 / x[t];
  }
  __syncthreads();
  // L21 solve: thread t -> row d0+32+t ; y = L11^{-1} a_row
  int r = d0 + 32 + t;
  if (r < 256) {
    double y[32];
#pragma unroll
    for (int j = 0; j < 32; ++j) y[j] = A[(ll)r * 256 + d0 + j];
#pragma unroll
    for (int j = 0; j < 32; ++j) {
      double s = y[j];
#pragma unroll
      for (int i = 0; i < j; ++i) s -= y[i] * D[j][i];
      y[j] = s * dinv[j];
    }
#pragma unroll
    for (int j = 0; j < 32; ++j) A[(ll)r * 256 + d0 + j] = y[j];
  }
  // write factored diag block back (logdet_diag reads diagonal)
  for (int e = t; e < 1024; e += 256)
    A[(ll)(d0 + (e >> 5)) * 256 + d0 + (e & 31)] = D[e >> 5][e & 31];
}

// step B (grid-parallel SYRK): trailing A22 -= L21 L21^T, 32x32 tiles, lower half
__global__ __launch_bounds__(256) void chol_step_b(double* __restrict__ mats, int d0) {
  double* A = mats + (ll)blockIdx.y * 65536;
  int tile = blockIdx.x;
  int i = 0;
  while (tile >= i + 1) { tile -= i + 1; ++i; }
  int j = tile;  // i >= j
  int ri = d0 + 32 + i * 32, rj = d0 + 32 + j * 32;
  __shared__ double Li[32][33];
  __shared__ double Lj[32][33];
  int t = threadIdx.x;
  for (int e = t; e < 1024; e += 256) {
    int rr = e >> 5, kk = e & 31;
    Li[rr][kk] = A[(ll)(ri + rr) * 256 + d0 + kk];
    Lj[rr][kk] = A[(ll)(rj + rr) * 256 + d0 + kk];
  }
  __syncthreads();
  for (int e = t; e < 1024; e += 256) {
    int rr = e >> 5, cc = e & 31;
    double s = 0.0;
#pragma unroll
    for (int k = 0; k < 32; ++k) s += Li[rr][k] * Lj[cc][k];
    A[(ll)(ri + rr) * 256 + rj + cc] -= s;
  }
}

// logdet = 2 * sum log(diag(L)), parallel reduce
__global__ void logdet_diag(const double* __restrict__ mats, double* __restrict__ ld) {
  __shared__ double sh[4];
  const double* A = mats + (ll)blockIdx.x * 65536;
  int t = threadIdx.x;
  double lg = log(A[(ll)t * 257]);
  int lane = t & 63, w = t >> 6;
#pragma unroll
  for (int off = 32; off > 0; off >>= 1) lg += __shfl_down(lg, off, 64);
  if (lane == 0) sh[w] = lg;
  __syncthreads();
  if (t == 0) ld[blockIdx.x] = 2.0 * (sh[0] + sh[1] + sh[2] + sh[3]);
}

__global__ void cov_final(const double* __restrict__ ld, float* __restrict__ outp) {
  outp[0] = (float)(-0.1 / (3.0 * 256.0) * (ld[0] + ld[1] + ld[2]));
}

// ---------------- output head: xph[M][256] @ outT[96][256]^T, scatter+denorm --
__global__ __launch_bounds__(256) void out_mfma(
    const ushort_t* __restrict__ A, const ushort_t* __restrict__ B,
    const float* __restrict__ bias, const float* __restrict__ stdev,
    const float* __restrict__ mean, float* __restrict__ out) {
  constexpr int M = Bn * Cn, N = Pn, K = Dn;
  __shared__ ushort_t lds_ab[2][128][32];
  int t = threadIdx.x;
  int m0 = blockIdx.y * 128;
  int w = t >> 6, lane = t & 63;
  int wm = (w >> 1) * 64, wn = (w & 1) * 64;
  int lrow = lane & 15, kq = lane >> 4;
  int srow = lane >> 2, skcol = (lane & 3) * 8;
  f32x4 acc[4][4] = {};
  for (int k0 = 0; k0 < K; k0 += 32) {
#pragma unroll
    for (int cc = 0; cc < 4; ++cc) {
      int c = w * 4 + cc;
      int tile = c >> 3, rb = (c & 7) * 16;
      int row = rb + srow;
      const ushort_t* src;
      if (tile == 0) {
        src = &A[(ll)(m0 + row) * K + k0 + skcol];
      } else {
        int gn = min(row, N - 1);
        src = &B[(ll)gn * K + k0 + skcol];
      }
      gl_lds16(src, &lds_ab[tile][rb][0]);
    }
    __syncthreads();
    bf16x8 af[4], bfr[4];
#pragma unroll
    for (int i = 0; i < 4; ++i)
      af[i] = *reinterpret_cast<const bf16x8*>(&lds_ab[0][wm + i * 16 + lrow][kq * 8]);
#pragma unroll
    for (int j = 0; j < 4; ++j)
      bfr[j] = *reinterpret_cast<const bf16x8*>(&lds_ab[1][wn + j * 16 + lrow][kq * 8]);
#pragma unroll
    for (int i = 0; i < 4; ++i)
#pragma unroll
      for (int j = 0; j < 4; ++j)
        acc[i][j] = __builtin_amdgcn_mfma_f32_16x16x32_bf16(af[i], bfr[j],
                                                            acc[i][j], 0, 0, 0);
    __syncthreads();
  }
#pragma unroll
  for (int i = 0; i < 4; ++i) {
    int mb = m0 + wm + i * 16 + kq * 4;
#pragma unroll
    for (int j = 0; j < 4; ++j) {
      int p = wn + j * 16 + lrow;
      if (p >= N) continue;
      float bv = bias[p];
#pragma unroll
      for (int reg = 0; reg < 4; ++reg) {
        int m = mb + reg;
        int b = m >> 11, c = m & 2047;
        float v = acc[i][j][reg] + bv;
        out[((ll)(b * Pn + p)) * Cn + c] = v * stdev[m] + mean[m];
      }
    }
  }
}

// =====================================================================
extern "C" void kernel_launch(void* const* d_in, const int* in_sizes, int n_in,
                              void* d_out, int out_size, void* d_ws, size_t ws_size,
                              hipStream_t stream) {
  (void)in_sizes; (void)n_in; (void)out_size; (void)ws_size;
  const float* x_enc = (const float*)d_in[0];
  const float* in_w = (const float*)d_in[4];
  const float* in_b = (const float*)d_in[5];
  const float* lq[3] = {(const float*)d_in[6], (const float*)d_in[7],
                        (const float*)d_in[8]};
  const float* down_w = (const float*)d_in[9];
  const float* down_b = (const float*)d_in[10];
  const float* down_ln = (const float*)d_in[11];
  const float* pred_w = (const float*)d_in[12];
  const float* pred_b = (const float*)d_in[13];
  const float* up_w = (const float*)d_in[14];
  const float* up_b = (const float*)d_in[15];
  const float* up_ln = (const float*)d_in[16];
  const float* out_w = (const float*)d_in[17];
  const float* out_b = (const float*)d_in[18];
  float* out = (float*)d_out;

  float* ws = (float*)d_ws;
  size_t off = 0;
  auto alloc = [&](size_t n) {
    n = (n + 3) & ~(size_t)3;  // 16B alignment
    float* p = ws + off;
    off += n;
    return p;
  };
  float* mean = alloc((size_t)Bn * Cn);
  float* stdevv = alloc((size_t)Bn * Cn);
  float* cmean = alloc(3 * 256);
  float* cistd = alloc(3 * 256);
  double* part = (double*)alloc(3 * 256 * 512 * 2);
  double* ld = (double*)alloc(32);
  double* covd = (double*)alloc(3 * 65536 * 2);
  float* s1 = alloc((size_t)Bn * 512 * Dn);   // s1,s2,s3 contiguous (cov batched)
  float* s2 = alloc((size_t)Bn * 128 * Dn);
  float* s3 = alloc((size_t)Bn * 32 * Dn);
  float* attn = alloc((size_t)Bn * 512 * 2048);     // f32 scores; also xnT(bf16)
  float* sbuf = alloc((size_t)16777216);            // attn_bf / o2 f32 / covpart
  ushort_t* h_bf = (ushort_t*)alloc((size_t)Bn * Cn * Dn / 2);
  ushort_t* s1b = (ushort_t*)alloc((size_t)Bn * 512 * Dn / 2);
  ushort_t* s2b = (ushort_t*)alloc((size_t)Bn * 128 * Dn / 2);
  ushort_t* s3b = (ushort_t*)alloc((size_t)Bn * 32 * Dn / 2);
  ushort_t* xpb = (ushort_t*)alloc((size_t)Bn * 32 * Dn / 2);
  ushort_t* xu0b = (ushort_t*)alloc((size_t)Bn * 128 * Dn / 2);
  ushort_t* xu1b = (ushort_t*)alloc((size_t)Bn * 512 * Dn / 2);
  ushort_t* qd_b = (ushort_t*)alloc(512 * 256 / 2);
  ushort_t* lqb0 = (ushort_t*)alloc(512 * 256 / 2);
  ushort_t* lqb1 = (ushort_t*)alloc(128 * 256 / 2);
  ushort_t* lqb2 = (ushort_t*)alloc(32 * 256 / 2);
  ushort_t* in_wT = (ushort_t*)alloc(256 * SnP / 2);
  ushort_t* downT = (ushort_t*)alloc(12 * 65536 / 2);
  ushort_t* upT = (ushort_t*)alloc(12 * 65536 / 2);
  ushort_t* predT = (ushort_t*)alloc(65536 / 2);
  ushort_t* outT = (ushort_t*)alloc(96 * 256 / 2);
  ushort_t* q_bf = (ushort_t*)alloc((size_t)Bn * 2048 * Dn / 2);  // also o1, xph
  ushort_t* k_bf = (ushort_t*)alloc((size_t)Bn * 2048 * Dn / 2);
  ushort_t* vT = (ushort_t*)alloc((size_t)Bn * 2048 * Dn / 2);

  ushort_t* xnT = (ushort_t*)attn;
  ushort_t* attn_b = (ushort_t*)sbuf;
  float* o2 = sbuf;
  double* covpart = (double*)sbuf;
  const float scale = 0.0625f;
  const float* npf = nullptr;

  // ---- prep: stats, normalize+transpose input, weight converts ----
  instnorm_stats<<<dim3(Cn / 256, Bn), 256, 0, stream>>>(x_enc, mean, stdevv);
  normT_kernel<<<dim3(Cn / 32, SnP / 32, Bn), 256, 0, stream>>>(x_enc, xnT, mean,
                                                                stdevv);
  cvtT_kernel<<<dim3(8, 8, 12), 256, 0, stream>>>(down_w, downT, 256, 256, 256);
  cvtT_kernel<<<dim3(8, 8, 12), 256, 0, stream>>>(up_w, upT, 256, 256, 256);
  cvtT_kernel<<<dim3(8, 8, 1), 256, 0, stream>>>(pred_w, predT, 256, 256, 256);
  cvtT_kernel<<<dim3(8, SnP / 32, 1), 256, 0, stream>>>(in_w, in_wT, Sn, 256, SnP);
  cvtT_kernel<<<dim3(3, 8, 1), 256, 0, stream>>>(out_w, outT, 256, Pn, 256);
  cvt_bf<<<512, 256, 0, stream>>>(lq[0], lqb0, 512 * 256);
  cvt_bf<<<128, 256, 0, stream>>>(lq[1], lqb1, 128 * 256);
  cvt_bf<<<32, 256, 0, stream>>>(lq[2], lqb2, 32 * 256);

  // ---- h = xn^T @ in_w + b : bf16 out (K padded to 768) ----
  gemm_bf<2, 64><<<dim3(2, 16, Bn), 256, 0, stream>>>(
      xnT, in_wT, Cn, Dn, SnP, SnP, SnP, (ll)Cn * SnP, 0, in_b, 1.f,
      nullptr, 0, 0, h_bf, Dn, (ll)Cn * Dn);

  ushort_t* lqb[3] = {lqb0, lqb1, lqb2};
  float* skf[3] = {s1, s2, s3};
  ushort_t* skb[3] = {s1b, s2b, s3b};
  int Ls[4] = {2048, 512, 128, 32};
  const ushort_t* xinb = h_bf;

  // ---------------- down layers ----------------
  for (int i = 0; i < 3; ++i) {
    int L = Ls[i], Lq = Ls[i + 1];
    const ushort_t* WqT = downT + (size_t)(i * 4 + 0) * 65536;
    const ushort_t* WkvT = downT + (size_t)(i * 4 + 1) * 65536;  // Wk||Wv
    const ushort_t* WoT = downT + (size_t)(i * 4 + 3) * 65536;
    const float* bq = down_b + (i * 4 + 0) * 256;
    const float* bkv = down_b + (i * 4 + 1) * 256;  // bk||bv (512)
    const float* bo = down_b + (i * 4 + 3) * 256;

    gemm_bf<2, 64><<<dim3(2, CDIV(Lq, 128), 1), 256, 0, stream>>>(
        lqb[i], WqT, Lq, Dn, Dn, Dn, Dn, 0, 0, bq, 1.f, nullptr, 0, 0, qd_b, Dn, 0);
    // fused K+V projection: c<256 -> k_bf (row), c>=256 -> vT (transposed)
    gemm_bf<8, 64><<<dim3(4, L / 128, Bn), 256, 0, stream>>>(
        xinb, WkvT, L, 512, Dn, Dn, Dn, (ll)L * Dn, 0, bkv, 1.f,
        (float*)vT, L, (ll)Dn * L, k_bf, Dn, (ll)L * Dn);
    gemm_bf<1, 64><<<dim3(L / 128, CDIV(Lq, 128), Bn), 256, 0, stream>>>(
        qd_b, k_bf, Lq, L, Dn, Dn, Dn, 0, (ll)L * Dn, npf, scale,
        attn, L, (ll)Lq * L, nullptr, 0, 0);
    if (L == 2048) softmax_bf<2048><<<Bn * Lq, 256, 0, stream>>>(attn, attn_b);
    else if (L == 512) softmax_bf<512><<<Bn * Lq, 256, 0, stream>>>(attn, attn_b);
    else softmax_bf<128><<<Bn * Lq, 256, 0, stream>>>(attn, attn_b);
    gemm_bf<2, 64><<<dim3(2, CDIV(Lq, 128), Bn), 256, 0, stream>>>(
        attn_b, vT, Lq, Dn, L, L, L, (ll)Lq * L, (ll)Dn * L, npf, 1.f,
        nullptr, 0, 0, q_bf, Dn, (ll)Lq * Dn);
    gemm_bf<1, 64><<<dim3(2, CDIV(Bn * Lq, 128), 1), 256, 0, stream>>>(
        q_bf, WoT, Bn * Lq, Dn, Dn, Dn, Dn, 0, 0, bo, 1.f, o2, Dn, 0, nullptr, 0, 0);
    ln_kernel<<<Bn * Lq, 256, 0, stream>>>(o2, nullptr, skf[i], skb[i], 0,
                                           down_ln + (i * 2 + 0) * 256,
                                           down_ln + (i * 2 + 1) * 256);
    xinb = skb[i];
  }

  // ------- covariance loss (batched front-end + NB=32 Cholesky) --------------
  colstat_partial3<<<dim3(256, 3), 256, 0, stream>>>(s1, part);
  colstat_final3<<<3, 256, 0, stream>>>(part, cmean, cistd);
  cov_gram3<<<dim3(10, 64, 3), 256, 0, stream>>>(s1, cmean, cistd, covpart);
  cov_reduce3<<<dim3(10, 16, 3), 256, 0, stream>>>(covpart, covd);
  for (int kb = 0; kb < 8; ++kb) {
    chol_step_a<<<3, 256, 0, stream>>>(covd, kb * 32);
    int T = 7 - kb;
    if (T > 0)
      chol_step_b<<<dim3(T * (T + 1) / 2, 3), 256, 0, stream>>>(covd, kb * 32);
  }
  logdet_diag<<<3, 256, 0, stream>>>(covd, ld);
  cov_final<<<1, 1, 0, stream>>>(ld, out + 6291456);

  // ---------------- pred head ----------------
  gemm_bf<2, 64><<<dim3(2, 8, 1), 256, 0, stream>>>(
      s3b, predT, Bn * 32, Dn, Dn, Dn, Dn, 0, 0, pred_b, 1.f,
      nullptr, 0, 0, xpb, Dn, 0);

  // ---------------- up layers ----------------
  int Lks[3] = {32, 128, 512}, Lqs[3] = {128, 512, 2048};
  const ushort_t* qinb[3] = {s2b, s1b, h_bf};
  const ushort_t* xinbs[3] = {xpb, xu0b, xu1b};
  ushort_t* xoutb[3] = {xu0b, xu1b, q_bf};  // final writes xph into q_bf
  for (int i = 0; i < 3; ++i) {
    int Lk = Lks[i], Lq = Lqs[i];
    const ushort_t* WqT = upT + (size_t)(i * 4 + 0) * 65536;
    const ushort_t* WkvT = upT + (size_t)(i * 4 + 1) * 65536;  // Wk||Wv
    const ushort_t* WoT = upT + (size_t)(i * 4 + 3) * 65536;
    const float* bq = up_b + (i * 4 + 0) * 256;
    const float* bkv = up_b + (i * 4 + 1) * 256;  // bk||bv (512)
    const float* bo = up_b + (i * 4 + 3) * 256;

    gemm_bf<2, 64><<<dim3(2, (Bn * Lq) / 128, 1), 256, 0, stream>>>(
        qinb[i], WqT, Bn * Lq, Dn, Dn, Dn, Dn, 0, 0, bq, 1.f,
        nullptr, 0, 0, q_bf, Dn, 0);
    gemm_bf<8, 64><<<dim3(4, CDIV(Lk, 128), Bn), 256, 0, stream>>>(
        xinbs[i], WkvT, Lk, 512, Dn, Dn, Dn, (ll)Lk * Dn, 0, bkv, 1.f,
        (float*)vT, Lk, (ll)Dn * Lk, k_bf, Dn, (ll)Lk * Dn);
    gemm_bf<1, 64><<<dim3(CDIV(Lk, 128), CDIV(Lq, 128), Bn), 256, 0, stream>>>(
        q_bf, k_bf, Lq, Lk, Dn, Dn, Dn, (ll)Lq * Dn, (ll)Lk * Dn, npf, scale,
        attn, Lk, (ll)Lq * Lk, nullptr, 0, 0);
    if (Lk == 32) softmax_bf<32><<<Bn * Lq, 256, 0, stream>>>(attn, attn_b);
    else if (Lk == 128) softmax_bf<128><<<Bn * Lq, 256, 0, stream>>>(attn, attn_b);
    else softmax_bf<512><<<Bn * Lq, 256, 0, stream>>>(attn, attn_b);
    if (Lk == 32) {
      gemm_bf<2, 32><<<dim3(2, CDIV(Lq, 128), Bn), 256, 0, stream>>>(
          attn_b, vT, Lq, Dn, Lk, Lk, Lk, (ll)Lq * Lk, (ll)Dn * Lk, npf, 1.f,
          nullptr, 0, 0, q_bf, Dn, (ll)Lq * Dn);
    } else {
      gemm_bf<2, 64><<<dim3(2, CDIV(Lq, 128), Bn), 256, 0, stream>>>(
          attn_b, vT, Lq, Dn, Lk, Lk, Lk, (ll)Lq * Lk, (ll)Dn * Lk, npf, 1.f,
          nullptr, 0, 0, q_bf, Dn, (ll)Lq * Dn);
    }
    gemm_bf<1, 64><<<dim3(2, (Bn * Lq) / 128, 1), 256, 0, stream>>>(
        q_bf, WoT, Bn * Lq, Dn, Dn, Dn, Dn, 0, 0, bo, 1.f, o2, Dn, 0, nullptr, 0, 0);
    ln_kernel<<<Bn * Lq, 256, 0, stream>>>(o2, qinb[i], nullptr, xoutb[i],
                                           (i == 2) ? 1 : 0,
                                           up_ln + (i * 2 + 0) * 256,
                                           up_ln + (i * 2 + 1) * 256);
  }

  // ---------------- output head: MFMA + transpose + de-norm ----------------
  out_mfma<<<dim3(1, (Bn * Cn) / 128, 1), 256, 0, stream>>>(q_bf, outT, out_b,
                                                            stdevv, mean, out);
}

// Round 16
// 1620.567 us; speedup vs baseline: 1.6308x; 1.0545x over previous
//
#include <hip/hip_runtime.h>
#include <hip/hip_bf16.h>
#include <math.h>

#define CDIV(a, b) (((a) + (b) - 1) / (b))
typedef long long ll;
typedef unsigned short ushort_t;

constexpr int Bn = 32;    // batch
constexpr int Sn = 720;   // seq len
constexpr int SnP = 768;  // seq len padded to K-step multiple
constexpr int Cn = 2048;  // channels (tokens after transpose)
constexpr int Dn = 256;   // d_model
constexpr int Pn = 96;    // pred len

typedef __attribute__((ext_vector_type(8))) short bf16x8;
typedef __attribute__((ext_vector_type(4))) float f32x4;

__device__ inline ushort_t rne1(float x) {
  unsigned u = __float_as_uint(x);
  u = (u + 0x7fffu + ((u >> 16) & 1u)) >> 16;
  return (ushort_t)u;
}
__device__ inline float b2f(ushort_t u) { return __uint_as_float(((unsigned)u) << 16); }

__device__ inline void gl_lds16(const void* g, void* l) {
  __builtin_amdgcn_global_load_lds(
      (const __attribute__((address_space(1))) void*)g,
      (__attribute__((address_space(3))) void*)l, 16, 0, 0);
}

// ---------------- instance norm stats over time axis ----------------
__global__ void instnorm_stats(const float* __restrict__ x,
                               float* __restrict__ mean, float* __restrict__ stdev) {
  int c = blockIdx.x * 256 + threadIdx.x;
  int b = blockIdx.y;
  const float* p = x + (ll)b * Sn * Cn + c;
  float s = 0.f, q = 0.f;
  for (int t = 0; t < Sn; ++t) {
    float v = p[(ll)t * Cn];
    s += v; q += v * v;
  }
  float m = s / (float)Sn;
  float var = q / (float)Sn - m * m;
  var = fmaxf(var, 0.f);
  mean[b * Cn + c] = m;
  stdev[b * Cn + c] = sqrtf(var + 1e-5f);
}

// ---------------- normalize + transpose: x[b][s][c] -> xnT[b][c][s] bf16 (K-pad)
__global__ void normT_kernel(const float* __restrict__ X, ushort_t* __restrict__ D,
                             const float* __restrict__ mean,
                             const float* __restrict__ stdev) {
  int b = blockIdx.z;
  __shared__ float tl[32][33];
  int t = threadIdx.x;
  int tx = t & 31, ty = t >> 5;
  int s0 = blockIdx.y * 32, c0 = blockIdx.x * 32;
#pragma unroll
  for (int e = 0; e < 4; ++e) {
    int s = s0 + ty + 8 * e;
    tl[ty + 8 * e][tx] = (s < Sn) ? X[((ll)b * Sn + s) * Cn + c0 + tx] : 0.f;
  }
  __syncthreads();
#pragma unroll
  for (int e = 0; e < 4; ++e) {
    int c = c0 + ty + 8 * e, s = s0 + tx;
    if (s < SnP) {
      float mu = mean[b * Cn + c], sd = stdev[b * Cn + c];
      float v = (s < Sn) ? (tl[tx][ty + 8 * e] - mu) / sd : 0.f;
      D[((ll)b * Cn + c) * SnP + s] = rne1(v);
    }
  }
}

// ---------------- transpose-convert: W[K][N] f32 -> WT[N][KP] bf16 ------------
__global__ void cvtT_kernel(const float* __restrict__ S, ushort_t* __restrict__ D,
                            int K, int N, int KP) {
  int z = blockIdx.z;
  S += (ll)z * K * N;
  D += (ll)z * N * KP;
  __shared__ float tl[32][33];
  int t = threadIdx.x;
  int tx = t & 31, ty = t >> 5;
  int k0 = blockIdx.y * 32, n0 = blockIdx.x * 32;
#pragma unroll
  for (int e = 0; e < 4; ++e) {
    int k = k0 + ty + 8 * e;
    tl[ty + 8 * e][tx] = (k < K && n0 + tx < N) ? S[(ll)k * N + n0 + tx] : 0.f;
  }
  __syncthreads();
#pragma unroll
  for (int e = 0; e < 4; ++e) {
    int n = n0 + ty + 8 * e, kk = k0 + tx;
    if (n < N && kk < KP) D[(ll)n * KP + kk] = rne1(tl[tx][ty + 8 * e]);
  }
}

__global__ void cvt_bf(const float* __restrict__ S, ushort_t* __restrict__ D, int n) {
  int i = blockIdx.x * 256 + threadIdx.x;
  if (i < n) D[i] = rne1(S[i]);
}

// ---------------- canonical bf16 MFMA GEMM: C = A[M][K] * B[N][K]^T ----------
// Double-buffered 2-phase: STAGE(t+1) issued BEFORE compute(t); one barrier
// per iteration (vmcnt drain lands after the MFMA phase). K % 32 == 0.
// MODE bits: 1 = f32 C ; 2 = bf16 C ; 4 = bf16 C^T ;
//            8 = fused KV: c<256 -> bf16 C (Cb), c>=256 -> bf16 C^T (via Cf).
template <int MODE>
__global__ __launch_bounds__(256) void gemm_bf(
    const ushort_t* __restrict__ A, const ushort_t* __restrict__ B,
    int M, int N, int K, int lda, int ldb, ll sA, ll sB,
    const float* __restrict__ bias, float alpha,
    float* __restrict__ Cf, int ldcf, ll sCf,
    ushort_t* __restrict__ Cb, int ldcb, ll sCb) {
  int g = blockIdx.z;
  A += (ll)g * sA;
  B += (ll)g * sB;
  if (MODE & 1) Cf += (ll)g * sCf;
  if (MODE & 14) Cb += (ll)g * sCb;
  ushort_t* Vt = nullptr;
  if (MODE & 8) Vt = (ushort_t*)Cf + (ll)g * sCf;
  __shared__ ushort_t lds_ab[2][2][128][32];  // [buf][tile][row][k]
  int t = threadIdx.x;
  int m0 = blockIdx.y * 128, n0 = blockIdx.x * 128;
  int w = t >> 6, lane = t & 63;
  int wm = (w >> 1) * 64, wn = (w & 1) * 64;
  int lrow = lane & 15, kq = lane >> 4;
  int srow = lane >> 2, skcol = (lane & 3) * 8;

  auto stage = [&](int buf, int k0) {
#pragma unroll
    for (int cc = 0; cc < 4; ++cc) {
      int c = w * 4 + cc;
      int tile = c >> 3, rb = (c & 7) * 16;
      int row = rb + srow;
      const ushort_t* src;
      if (tile == 0) {
        int gm = min(m0 + row, M - 1);
        src = &A[(ll)gm * lda + k0 + skcol];
      } else {
        int gn = min(n0 + row, N - 1);
        src = &B[(ll)gn * ldb + k0 + skcol];
      }
      gl_lds16(src, &lds_ab[buf][tile][rb][0]);
    }
  };

  f32x4 acc[4][4] = {};
  int nt = K >> 5;
  stage(0, 0);
  __syncthreads();
  int cur = 0;
  for (int it = 0; it < nt; ++it) {
    if (it + 1 < nt) stage(cur ^ 1, (it + 1) * 32);
    bf16x8 af[4], bfr[4];
#pragma unroll
    for (int i = 0; i < 4; ++i)
      af[i] = *reinterpret_cast<const bf16x8*>(&lds_ab[cur][0][wm + i * 16 + lrow][kq * 8]);
#pragma unroll
    for (int j = 0; j < 4; ++j)
      bfr[j] = *reinterpret_cast<const bf16x8*>(&lds_ab[cur][1][wn + j * 16 + lrow][kq * 8]);
#pragma unroll
    for (int i = 0; i < 4; ++i)
#pragma unroll
      for (int j = 0; j < 4; ++j)
        acc[i][j] = __builtin_amdgcn_mfma_f32_16x16x32_bf16(af[i], bfr[j],
                                                            acc[i][j], 0, 0, 0);
    __syncthreads();
    cur ^= 1;
  }
#pragma unroll
  for (int i = 0; i < 4; ++i) {
    int mb = m0 + wm + i * 16 + kq * 4;
    if (mb >= M) continue;
#pragma unroll
    for (int j = 0; j < 4; ++j) {
      int c = n0 + wn + j * 16 + lrow;
      if (c >= N) continue;
      float bv = bias ? bias[c] : 0.f;
#pragma unroll
      for (int reg = 0; reg < 4; ++reg) {
        int m = mb + reg;
        float v = acc[i][j][reg] * alpha + bv;
        if (MODE & 8) {
          if (c < 256) Cb[(ll)m * ldcb + c] = rne1(v);
          else Vt[(ll)(c - 256) * ldcf + m] = rne1(v);
        } else {
          if (MODE & 1) Cf[(ll)m * ldcf + c] = v;
          if (MODE & 2) Cb[(ll)m * ldcb + c] = rne1(v);
          if (MODE & 4) Cb[(ll)c * ldcb + m] = rne1(v);
        }
      }
    }
  }
}

// ---------------- block reduction helper (blockDim = 256) ----------------
__device__ inline float blk_reduce(float v, volatile float* sh, int op) {
  int lane = threadIdx.x & 63, w = threadIdx.x >> 6;
#pragma unroll
  for (int off = 32; off > 0; off >>= 1) {
    float o = __shfl_down(v, off, 64);
    v = op ? fmaxf(v, o) : (v + o);
  }
  __syncthreads();
  if (lane == 0) sh[w] = v;
  __syncthreads();
  float r = op ? fmaxf(fmaxf(sh[0], sh[1]), fmaxf(sh[2], sh[3]))
               : (sh[0] + sh[1] + sh[2] + sh[3]);
  return r;
}

// ---------------- row softmax: f32 scores in, bf16 probs out ----------------
template <int LL>
__global__ void softmax_bf(const float* __restrict__ S, ushort_t* __restrict__ P) {
  constexpr int NE = (LL + 255) / 256;
  __shared__ float sh[4];
  ll row = blockIdx.x;
  const float* p = S + row * (ll)LL;
  ushort_t* q = P + row * (ll)LL;
  int t = threadIdx.x;
  float e[NE];
  float mx = -INFINITY;
#pragma unroll
  for (int k = 0; k < NE; ++k) {
    int i = t + k * 256;
    if (i < LL) { e[k] = p[i]; mx = fmaxf(mx, e[k]); }
  }
  mx = blk_reduce(mx, sh, 1);
  float sum = 0.f;
#pragma unroll
  for (int k = 0; k < NE; ++k) {
    int i = t + k * 256;
    if (i < LL) { e[k] = __expf(e[k] - mx); sum += e[k]; }
  }
  sum = blk_reduce(sum, sh, 0);
  float inv = 1.f / sum;
#pragma unroll
  for (int k = 0; k < NE; ++k) {
    int i = t + k * 256;
    if (i < LL) q[i] = rne1(e[k] * inv);
  }
}

// ---------------- LayerNorm over D=256; optional bf16 residual ----------------
__global__ void ln_kernel(const float* __restrict__ X, const ushort_t* __restrict__ RESb,
                          float* __restrict__ Yf, ushort_t* __restrict__ Yb, int postadd,
                          const float* __restrict__ gamma, const float* __restrict__ beta) {
  __shared__ float sh[4];
  ll row = blockIdx.x;
  int t = threadIdx.x;
  float r = RESb ? b2f(RESb[row * Dn + t]) : 0.f;
  float v = X[row * Dn + t] + r;
  float m = blk_reduce(v, sh, 0) * (1.f / (float)Dn);
  float d = v - m;
  float var = blk_reduce(d * d, sh, 0) * (1.f / (float)Dn);
  float y = d * rsqrtf(var + 1e-5f) * gamma[t] + beta[t];
  if (Yf) Yf[row * Dn + t] = y;
  if (Yb) Yb[row * Dn + t] = rne1(y + (postadd ? r : 0.f));
}

// --------- batched covariance column stats over the 3 skips (f64) -----------
// skips live contiguously from s1: offsets {0, 4194304, 5242880} floats.
__global__ void colstat_partial3(const float* __restrict__ X0,
                                 double* __restrict__ part) {
  int j = blockIdx.y;
  ll joff = (j == 0) ? 0LL : ((j == 1) ? 4194304LL : 5242880LL);
  int nrows = (j == 0) ? 16384 : ((j == 1) ? 4096 : 1024);
  const float* X = X0 + joff;
  int blk = blockIdx.x, t = threadIdx.x;
  int chunk = CDIV(nrows, 256);
  int r0 = blk * chunk, r1 = min(nrows, r0 + chunk);
  double s = 0.0, q = 0.0;
  for (int r = r0; r < r1; ++r) {
    double v = (double)X[(ll)r * Dn + t];
    s += v; q += v * v;
  }
  part[(ll)j * 131072 + blk * 512 + t] = s;
  part[(ll)j * 131072 + blk * 512 + 256 + t] = q;
}

__global__ void colstat_final3(const double* __restrict__ part,
                               float* __restrict__ cmean, float* __restrict__ cistd) {
  int j = blockIdx.x;
  int nrows = (j == 0) ? 16384 : ((j == 1) ? 4096 : 1024);
  int t = threadIdx.x;
  double s = 0.0, q = 0.0;
  for (int b = 0; b < 256; ++b) {
    s += part[(ll)j * 131072 + b * 512 + t];
    q += part[(ll)j * 131072 + b * 512 + 256 + t];
  }
  double m = s / (double)nrows;
  double var = (q - (double)nrows * m * m) / (double)(nrows - 1);
  var = fmax(var, 0.0);
  cmean[j * 256 + t] = (float)m;
  cistd[j * 256 + t] = (float)(1.0 / (sqrt(var) + 1e-5));
}

// -------- batched lower-triangle cov Gram: 64x64 f64 tiles, fused normalize --
__global__ __launch_bounds__(256) void cov_gram3(const float* __restrict__ X0,
                                                 const float* __restrict__ cmean0,
                                                 const float* __restrict__ cistd0,
                                                 double* __restrict__ part) {
  int j = blockIdx.z;
  int nz = (j == 0) ? 64 : ((j == 1) ? 32 : 16);
  int z = blockIdx.y;
  if (z >= nz) return;
  int nr = (j == 0) ? 16384 : ((j == 1) ? 4096 : 1024);
  ll joff = (j == 0) ? 0LL : ((j == 1) ? 4194304LL : 5242880LL);
  const float* X = X0 + joff;
  const float* cmean = cmean0 + j * 256;
  const float* cistd = cistd0 + j * 256;
  __shared__ double Am[32][66];
  __shared__ double Bq[32][66];
  __shared__ float cmA[64], ciA[64], cmB[64], ciB[64];
  int tile = blockIdx.x;
  int mi = 0;
  while (tile >= mi + 1) { tile -= mi + 1; ++mi; }
  int nj = tile;  // mi >= nj (4x4 blocks of 64)
  int m0 = mi * 64, n0 = nj * 64;
  bool diag = (mi == nj);
  int t = threadIdx.x;
  int tx4 = (t & 15) * 4, ty4 = (t >> 4) * 4;
  if (t < 64) { cmA[t] = cmean[m0 + t]; ciA[t] = cistd[m0 + t]; }
  else if (t < 128) { cmB[t - 64] = cmean[n0 + t - 64]; ciB[t - 64] = cistd[n0 + t - 64]; }
  __syncthreads();
  int chunk = nr / nz;
  int kbeg = z * chunk, kend = kbeg + chunk;
  double acc[4][4] = {};
  const double* Bbase = diag ? &Am[0][0] : &Bq[0][0];
  for (int k0 = kbeg; k0 < kend; k0 += 32) {
#pragma unroll
    for (int e = 0; e < 8; ++e) {
      int idx = t + e * 256;
      int kk = idx >> 6, mm = idx & 63;
      float xa = X[(ll)(k0 + kk) * Dn + m0 + mm];
      Am[kk][mm] = (double)((xa - cmA[mm]) * ciA[mm]);
      if (!diag) {
        float xb = X[(ll)(k0 + kk) * Dn + n0 + mm];
        Bq[kk][mm] = (double)((xb - cmB[mm]) * ciB[mm]);
      }
    }
    __syncthreads();
#pragma unroll 4
    for (int kk = 0; kk < 32; ++kk) {
      double a[4], b[4];
#pragma unroll
      for (int q = 0; q < 4; ++q) a[q] = Am[kk][ty4 + q];
#pragma unroll
      for (int q = 0; q < 4; ++q) b[q] = Bbase[kk * 66 + tx4 + q];
#pragma unroll
      for (int i = 0; i < 4; ++i)
#pragma unroll
        for (int jj = 0; jj < 4; ++jj) acc[i][jj] += a[i] * b[jj];
    }
    __syncthreads();
  }
  ll base = ((ll)((j * 64 + z) * 10 + blockIdx.x)) * 4096;
#pragma unroll
  for (int i = 0; i < 4; ++i)
#pragma unroll
    for (int jj = 0; jj < 4; ++jj)
      part[base + (ty4 + i) * 64 + tx4 + jj] = acc[i][jj];
}

// reduce split-K partials; grid (10 tiles, 16 segments, 3 skips)
__global__ void cov_reduce3(const double* __restrict__ part, double* __restrict__ Cd0) {
  int j = blockIdx.z;
  int nz = (j == 0) ? 64 : ((j == 1) ? 32 : 16);
  int nr = (j == 0) ? 16384 : ((j == 1) ? 4096 : 1024);
  double inv = 1.0 / (double)(nr - 1);
  double* Cd = Cd0 + (ll)j * 65536;
  int tile = blockIdx.x;
  int mi = 0;
  while (tile >= mi + 1) { tile -= mi + 1; ++mi; }
  int nj = tile;
  int e = blockIdx.y * 256 + threadIdx.x;
  int rr = e >> 6, cc = e & 63;
  int m = mi * 64 + rr, n = nj * 64 + cc;
  double s0 = 0.0, s1 = 0.0, s2 = 0.0, s3 = 0.0;
  int z = 0;
  for (; z + 4 <= nz; z += 4) {
    s0 += part[((ll)((j * 64 + z + 0) * 10 + blockIdx.x)) * 4096 + e];
    s1 += part[((ll)((j * 64 + z + 1) * 10 + blockIdx.x)) * 4096 + e];
    s2 += part[((ll)((j * 64 + z + 2) * 10 + blockIdx.x)) * 4096 + e];
    s3 += part[((ll)((j * 64 + z + 3) * 10 + blockIdx.x)) * 4096 + e];
  }
  double s = ((s0 + s1) + (s2 + s3)) * inv + ((m == n) ? 1e-5 : 0.0);
  Cd[m * 256 + n] = s;
}

// ---------------- multi-launch right-looking f64 Cholesky (NB=32) ------------
__global__ __launch_bounds__(256) void chol_step_a(double* __restrict__ mats, int d0) {
  double* A = mats + (ll)blockIdx.x * 65536;
  __shared__ double D[32][33];
  __shared__ double dinv[32];
  int t = threadIdx.x;
  for (int e = t; e < 1024; e += 256) {
    int i = e >> 5, j = e & 31;
    D[i][j] = (j <= i) ? A[(ll)(d0 + i) * 256 + d0 + j] : 0.0;  // upper never computed
  }
  __syncthreads();
  if (t < 32) {
    double x[32];
#pragma unroll
    for (int j = 0; j < 32; ++j) x[j] = D[t][j];
#pragma unroll
    for (int k = 0; k < 32; ++k) {
      double piv = fmax(__shfl(x[k], k, 64), 1e-300);
      double inv = 1.0 / sqrt(piv);
      double lrk = x[k] * inv;  // lane t: l_{t,k}; lane k: d_k
      x[k] = lrk;
#pragma unroll
      for (int j = k + 1; j < 32; ++j) x[j] -= lrk * __shfl(lrk, j, 64);
    }
#pragma unroll
    for (int j = 0; j < 32; ++j) D[t][j] = x[j];
    dinv[t] = 1.0 / x[t];
  }
  __syncthreads();
  // L21 solve: thread t -> row d0+32+t ; y = L11^{-1} a_row
  int r = d0 + 32 + t;
  if (r < 256) {
    double y[32];
#pragma unroll
    for (int j = 0; j < 32; ++j) y[j] = A[(ll)r * 256 + d0 + j];
#pragma unroll
    for (int j = 0; j < 32; ++j) {
      double s = y[j];
#pragma unroll
      for (int i = 0; i < j; ++i) s -= y[i] * D[j][i];
      y[j] = s * dinv[j];
    }
#pragma unroll
    for (int j = 0; j < 32; ++j) A[(ll)r * 256 + d0 + j] = y[j];
  }
  // write factored diag block back (logdet_diag reads diagonal)
  for (int e = t; e < 1024; e += 256)
    A[(ll)(d0 + (e >> 5)) * 256 + d0 + (e & 31)] = D[e >> 5][e & 31];
}

// step B (grid-parallel SYRK): trailing A22 -= L21 L21^T, 32x32 tiles, lower half
__global__ __launch_bounds__(256) void chol_step_b(double* __restrict__ mats, int d0) {
  double* A = mats + (ll)blockIdx.y * 65536;
  int tile = blockIdx.x;
  int i = 0;
  while (tile >= i + 1) { tile -= i + 1; ++i; }
  int j = tile;  // i >= j
  int ri = d0 + 32 + i * 32, rj = d0 + 32 + j * 32;
  __shared__ double Li[32][33];
  __shared__ double Lj[32][33];
  int t = threadIdx.x;
  for (int e = t; e < 1024; e += 256) {
    int rr = e >> 5, kk = e & 31;
    Li[rr][kk] = A[(ll)(ri + rr) * 256 + d0 + kk];
    Lj[rr][kk] = A[(ll)(rj + rr) * 256 + d0 + kk];
  }
  __syncthreads();
  for (int e = t; e < 1024; e += 256) {
    int rr = e >> 5, cc = e & 31;
    double s = 0.0;
#pragma unroll
    for (int k = 0; k < 32; ++k) s += Li[rr][k] * Lj[cc][k];
    A[(ll)(ri + rr) * 256 + rj + cc] -= s;
  }
}

// logdet = 2 * sum log(diag(L)), parallel reduce
__global__ void logdet_diag(const double* __restrict__ mats, double* __restrict__ ld) {
  __shared__ double sh[4];
  const double* A = mats + (ll)blockIdx.x * 65536;
  int t = threadIdx.x;
  double lg = log(A[(ll)t * 257]);
  int lane = t & 63, w = t >> 6;
#pragma unroll
  for (int off = 32; off > 0; off >>= 1) lg += __shfl_down(lg, off, 64);
  if (lane == 0) sh[w] = lg;
  __syncthreads();
  if (t == 0) ld[blockIdx.x] = 2.0 * (sh[0] + sh[1] + sh[2] + sh[3]);
}

__global__ void cov_final(const double* __restrict__ ld, float* __restrict__ outp) {
  outp[0] = (float)(-0.1 / (3.0 * 256.0) * (ld[0] + ld[1] + ld[2]));
}

// ---------------- output head: xph[M][256] @ outT[96][256]^T, scatter+denorm --
__global__ __launch_bounds__(256) void out_mfma(
    const ushort_t* __restrict__ A, const ushort_t* __restrict__ B,
    const float* __restrict__ bias, const float* __restrict__ stdev,
    const float* __restrict__ mean, float* __restrict__ out) {
  constexpr int M = Bn * Cn, N = Pn, K = Dn;
  __shared__ ushort_t lds_ab[2][128][32];
  int t = threadIdx.x;
  int m0 = blockIdx.y * 128;
  int w = t >> 6, lane = t & 63;
  int wm = (w >> 1) * 64, wn = (w & 1) * 64;
  int lrow = lane & 15, kq = lane >> 4;
  int srow = lane >> 2, skcol = (lane & 3) * 8;
  f32x4 acc[4][4] = {};
  for (int k0 = 0; k0 < K; k0 += 32) {
#pragma unroll
    for (int cc = 0; cc < 4; ++cc) {
      int c = w * 4 + cc;
      int tile = c >> 3, rb = (c & 7) * 16;
      int row = rb + srow;
      const ushort_t* src;
      if (tile == 0) {
        src = &A[(ll)(m0 + row) * K + k0 + skcol];
      } else {
        int gn = min(row, N - 1);
        src = &B[(ll)gn * K + k0 + skcol];
      }
      gl_lds16(src, &lds_ab[tile][rb][0]);
    }
    __syncthreads();
    bf16x8 af[4], bfr[4];
#pragma unroll
    for (int i = 0; i < 4; ++i)
      af[i] = *reinterpret_cast<const bf16x8*>(&lds_ab[0][wm + i * 16 + lrow][kq * 8]);
#pragma unroll
    for (int j = 0; j < 4; ++j)
      bfr[j] = *reinterpret_cast<const bf16x8*>(&lds_ab[1][wn + j * 16 + lrow][kq * 8]);
#pragma unroll
    for (int i = 0; i < 4; ++i)
#pragma unroll
      for (int j = 0; j < 4; ++j)
        acc[i][j] = __builtin_amdgcn_mfma_f32_16x16x32_bf16(af[i], bfr[j],
                                                            acc[i][j], 0, 0, 0);
    __syncthreads();
  }
#pragma unroll
  for (int i = 0; i < 4; ++i) {
    int mb = m0 + wm + i * 16 + kq * 4;
#pragma unroll
    for (int j = 0; j < 4; ++j) {
      int p = wn + j * 16 + lrow;
      if (p >= N) continue;
      float bv = bias[p];
#pragma unroll
      for (int reg = 0; reg < 4; ++reg) {
        int m = mb + reg;
        int b = m >> 11, c = m & 2047;
        float v = acc[i][j][reg] + bv;
        out[((ll)(b * Pn + p)) * Cn + c] = v * stdev[m] + mean[m];
      }
    }
  }
}

// =====================================================================
extern "C" void kernel_launch(void* const* d_in, const int* in_sizes, int n_in,
                              void* d_out, int out_size, void* d_ws, size_t ws_size,
                              hipStream_t stream) {
  (void)in_sizes; (void)n_in; (void)out_size; (void)ws_size;
  const float* x_enc = (const float*)d_in[0];
  const float* in_w = (const float*)d_in[4];
  const float* in_b = (const float*)d_in[5];
  const float* lq[3] = {(const float*)d_in[6], (const float*)d_in[7],
                        (const float*)d_in[8]};
  const float* down_w = (const float*)d_in[9];
  const float* down_b = (const float*)d_in[10];
  const float* down_ln = (const float*)d_in[11];
  const float* pred_w = (const float*)d_in[12];
  const float* pred_b = (const float*)d_in[13];
  const float* up_w = (const float*)d_in[14];
  const float* up_b = (const float*)d_in[15];
  const float* up_ln = (const float*)d_in[16];
  const float* out_w = (const float*)d_in[17];
  const float* out_b = (const float*)d_in[18];
  float* out = (float*)d_out;

  float* ws = (float*)d_ws;
  size_t off = 0;
  auto alloc = [&](size_t n) {
    n = (n + 3) & ~(size_t)3;  // 16B alignment
    float* p = ws + off;
    off += n;
    return p;
  };
  float* mean = alloc((size_t)Bn * Cn);
  float* stdevv = alloc((size_t)Bn * Cn);
  float* cmean = alloc(3 * 256);
  float* cistd = alloc(3 * 256);
  double* part = (double*)alloc(3 * 256 * 512 * 2);
  double* ld = (double*)alloc(32);
  double* covd = (double*)alloc(3 * 65536 * 2);
  float* s1 = alloc((size_t)Bn * 512 * Dn);   // s1,s2,s3 contiguous (cov batched)
  float* s2 = alloc((size_t)Bn * 128 * Dn);
  float* s3 = alloc((size_t)Bn * 32 * Dn);
  float* attn = alloc((size_t)Bn * 512 * 2048);     // f32 scores; also xnT(bf16)
  float* sbuf = alloc((size_t)16777216);            // attn_bf / o2 f32 / covpart
  ushort_t* h_bf = (ushort_t*)alloc((size_t)Bn * Cn * Dn / 2);
  ushort_t* s1b = (ushort_t*)alloc((size_t)Bn * 512 * Dn / 2);
  ushort_t* s2b = (ushort_t*)alloc((size_t)Bn * 128 * Dn / 2);
  ushort_t* s3b = (ushort_t*)alloc((size_t)Bn * 32 * Dn / 2);
  ushort_t* xpb = (ushort_t*)alloc((size_t)Bn * 32 * Dn / 2);
  ushort_t* xu0b = (ushort_t*)alloc((size_t)Bn * 128 * Dn / 2);
  ushort_t* xu1b = (ushort_t*)alloc((size_t)Bn * 512 * Dn / 2);
  ushort_t* qd_b = (ushort_t*)alloc(512 * 256 / 2);
  ushort_t* lqb0 = (ushort_t*)alloc(512 * 256 / 2);
  ushort_t* lqb1 = (ushort_t*)alloc(128 * 256 / 2);
  ushort_t* lqb2 = (ushort_t*)alloc(32 * 256 / 2);
  ushort_t* in_wT = (ushort_t*)alloc(256 * SnP / 2);
  ushort_t* downT = (ushort_t*)alloc(12 * 65536 / 2);
  ushort_t* upT = (ushort_t*)alloc(12 * 65536 / 2);
  ushort_t* predT = (ushort_t*)alloc(65536 / 2);
  ushort_t* outT = (ushort_t*)alloc(96 * 256 / 2);
  ushort_t* q_bf = (ushort_t*)alloc((size_t)Bn * 2048 * Dn / 2);  // also o1, xph
  ushort_t* k_bf = (ushort_t*)alloc((size_t)Bn * 2048 * Dn / 2);
  ushort_t* vT = (ushort_t*)alloc((size_t)Bn * 2048 * Dn / 2);

  ushort_t* xnT = (ushort_t*)attn;
  ushort_t* attn_b = (ushort_t*)sbuf;
  float* o2 = sbuf;
  double* covpart = (double*)sbuf;
  const float scale = 0.0625f;
  const float* npf = nullptr;

  // ---- prep: stats, normalize+transpose input, weight converts ----
  instnorm_stats<<<dim3(Cn / 256, Bn), 256, 0, stream>>>(x_enc, mean, stdevv);
  normT_kernel<<<dim3(Cn / 32, SnP / 32, Bn), 256, 0, stream>>>(x_enc, xnT, mean,
                                                                stdevv);
  cvtT_kernel<<<dim3(8, 8, 12), 256, 0, stream>>>(down_w, downT, 256, 256, 256);
  cvtT_kernel<<<dim3(8, 8, 12), 256, 0, stream>>>(up_w, upT, 256, 256, 256);
  cvtT_kernel<<<dim3(8, 8, 1), 256, 0, stream>>>(pred_w, predT, 256, 256, 256);
  cvtT_kernel<<<dim3(8, SnP / 32, 1), 256, 0, stream>>>(in_w, in_wT, Sn, 256, SnP);
  cvtT_kernel<<<dim3(3, 8, 1), 256, 0, stream>>>(out_w, outT, 256, Pn, 256);
  cvt_bf<<<512, 256, 0, stream>>>(lq[0], lqb0, 512 * 256);
  cvt_bf<<<128, 256, 0, stream>>>(lq[1], lqb1, 128 * 256);
  cvt_bf<<<32, 256, 0, stream>>>(lq[2], lqb2, 32 * 256);

  // ---- h = xn^T @ in_w + b : bf16 out (K padded to 768) ----
  gemm_bf<2><<<dim3(2, 16, Bn), 256, 0, stream>>>(
      xnT, in_wT, Cn, Dn, SnP, SnP, SnP, (ll)Cn * SnP, 0, in_b, 1.f,
      nullptr, 0, 0, h_bf, Dn, (ll)Cn * Dn);

  ushort_t* lqb[3] = {lqb0, lqb1, lqb2};
  float* skf[3] = {s1, s2, s3};
  ushort_t* skb[3] = {s1b, s2b, s3b};
  int Ls[4] = {2048, 512, 128, 32};
  const ushort_t* xinb = h_bf;

  // ---------------- down layers ----------------
  for (int i = 0; i < 3; ++i) {
    int L = Ls[i], Lq = Ls[i + 1];
    const ushort_t* WqT = downT + (size_t)(i * 4 + 0) * 65536;
    const ushort_t* WkvT = downT + (size_t)(i * 4 + 1) * 65536;  // Wk||Wv
    const ushort_t* WoT = downT + (size_t)(i * 4 + 3) * 65536;
    const float* bq = down_b + (i * 4 + 0) * 256;
    const float* bkv = down_b + (i * 4 + 1) * 256;  // bk||bv (512)
    const float* bo = down_b + (i * 4 + 3) * 256;

    gemm_bf<2><<<dim3(2, CDIV(Lq, 128), 1), 256, 0, stream>>>(
        lqb[i], WqT, Lq, Dn, Dn, Dn, Dn, 0, 0, bq, 1.f, nullptr, 0, 0, qd_b, Dn, 0);
    // fused K+V projection: c<256 -> k_bf (row), c>=256 -> vT (transposed)
    gemm_bf<8><<<dim3(4, L / 128, Bn), 256, 0, stream>>>(
        xinb, WkvT, L, 512, Dn, Dn, Dn, (ll)L * Dn, 0, bkv, 1.f,
        (float*)vT, L, (ll)Dn * L, k_bf, Dn, (ll)L * Dn);
    gemm_bf<1><<<dim3(L / 128, CDIV(Lq, 128), Bn), 256, 0, stream>>>(
        qd_b, k_bf, Lq, L, Dn, Dn, Dn, 0, (ll)L * Dn, npf, scale,
        attn, L, (ll)Lq * L, nullptr, 0, 0);
    if (L == 2048) softmax_bf<2048><<<Bn * Lq, 256, 0, stream>>>(attn, attn_b);
    else if (L == 512) softmax_bf<512><<<Bn * Lq, 256, 0, stream>>>(attn, attn_b);
    else softmax_bf<128><<<Bn * Lq, 256, 0, stream>>>(attn, attn_b);
    gemm_bf<2><<<dim3(2, CDIV(Lq, 128), Bn), 256, 0, stream>>>(
        attn_b, vT, Lq, Dn, L, L, L, (ll)Lq * L, (ll)Dn * L, npf, 1.f,
        nullptr, 0, 0, q_bf, Dn, (ll)Lq * Dn);
    gemm_bf<1><<<dim3(2, CDIV(Bn * Lq, 128), 1), 256, 0, stream>>>(
        q_bf, WoT, Bn * Lq, Dn, Dn, Dn, Dn, 0, 0, bo, 1.f, o2, Dn, 0, nullptr, 0, 0);
    ln_kernel<<<Bn * Lq, 256, 0, stream>>>(o2, nullptr, skf[i], skb[i], 0,
                                           down_ln + (i * 2 + 0) * 256,
                                           down_ln + (i * 2 + 1) * 256);
    xinb = skb[i];
  }

  // ------- covariance loss (batched front-end + NB=32 Cholesky) --------------
  colstat_partial3<<<dim3(256, 3), 256, 0, stream>>>(s1, part);
  colstat_final3<<<3, 256, 0, stream>>>(part, cmean, cistd);
  cov_gram3<<<dim3(10, 64, 3), 256, 0, stream>>>(s1, cmean, cistd, covpart);
  cov_reduce3<<<dim3(10, 16, 3), 256, 0, stream>>>(covpart, covd);
  for (int kb = 0; kb < 8; ++kb) {
    chol_step_a<<<3, 256, 0, stream>>>(covd, kb * 32);
    int T = 7 - kb;
    if (T > 0)
      chol_step_b<<<dim3(T * (T + 1) / 2, 3), 256, 0, stream>>>(covd, kb * 32);
  }
  logdet_diag<<<3, 256, 0, stream>>>(covd, ld);
  cov_final<<<1, 1, 0, stream>>>(ld, out + 6291456);

  // ---------------- pred head ----------------
  gemm_bf<2><<<dim3(2, 8, 1), 256, 0, stream>>>(
      s3b, predT, Bn * 32, Dn, Dn, Dn, Dn, 0, 0, pred_b, 1.f,
      nullptr, 0, 0, xpb, Dn, 0);

  // ---------------- up layers ----------------
  int Lks[3] = {32, 128, 512}, Lqs[3] = {128, 512, 2048};
  const ushort_t* qinb[3] = {s2b, s1b, h_bf};
  const ushort_t* xinbs[3] = {xpb, xu0b, xu1b};
  ushort_t* xoutb[3] = {xu0b, xu1b, q_bf};  // final writes xph into q_bf
  for (int i = 0; i < 3; ++i) {
    int Lk = Lks[i], Lq = Lqs[i];
    const ushort_t* WqT = upT + (size_t)(i * 4 + 0) * 65536;
    const ushort_t* WkvT = upT + (size_t)(i * 4 + 1) * 65536;  // Wk||Wv
    const ushort_t* WoT = upT + (size_t)(i * 4 + 3) * 65536;
    const float* bq = up_b + (i * 4 + 0) * 256;
    const float* bkv = up_b + (i * 4 + 1) * 256;  // bk||bv (512)
    const float* bo = up_b + (i * 4 + 3) * 256;

    gemm_bf<2><<<dim3(2, (Bn * Lq) / 128, 1), 256, 0, stream>>>(
        qinb[i], WqT, Bn * Lq, Dn, Dn, Dn, Dn, 0, 0, bq, 1.f,
        nullptr, 0, 0, q_bf, Dn, 0);
    gemm_bf<8><<<dim3(4, CDIV(Lk, 128), Bn), 256, 0, stream>>>(
        xinbs[i], WkvT, Lk, 512, Dn, Dn, Dn, (ll)Lk * Dn, 0, bkv, 1.f,
        (float*)vT, Lk, (ll)Dn * Lk, k_bf, Dn, (ll)Lk * Dn);
    gemm_bf<1><<<dim3(CDIV(Lk, 128), CDIV(Lq, 128), Bn), 256, 0, stream>>>(
        q_bf, k_bf, Lq, Lk, Dn, Dn, Dn, (ll)Lq * Dn, (ll)Lk * Dn, npf, scale,
        attn, Lk, (ll)Lq * Lk, nullptr, 0, 0);
    if (Lk == 32) softmax_bf<32><<<Bn * Lq, 256, 0, stream>>>(attn, attn_b);
    else if (Lk == 128) softmax_bf<128><<<Bn * Lq, 256, 0, stream>>>(attn, attn_b);
    else softmax_bf<512><<<Bn * Lq, 256, 0, stream>>>(attn, attn_b);
    gemm_bf<2><<<dim3(2, CDIV(Lq, 128), Bn), 256, 0, stream>>>(
        attn_b, vT, Lq, Dn, Lk, Lk, Lk, (ll)Lq * Lk, (ll)Dn * Lk, npf, 1.f,
        nullptr, 0, 0, q_bf, Dn, (ll)Lq * Dn);
    gemm_bf<1><<<dim3(2, (Bn * Lq) / 128, 1), 256, 0, stream>>>(
        q_bf, WoT, Bn * Lq, Dn, Dn, Dn, Dn, 0, 0, bo, 1.f, o2, Dn, 0, nullptr, 0, 0);
    ln_kernel<<<Bn * Lq, 256, 0, stream>>>(o2, qinb[i], nullptr, xoutb[i],
                                           (i == 2) ? 1 : 0,
                                           up_ln + (i * 2 + 0) * 256,
                                           up_ln + (i * 2 + 1) * 256);
  }

  // ---------------- output head: MFMA + transpose + de-norm ----------------
  out_mfma<<<dim3(1, (Bn * Cn) / 128, 1), 256, 0, stream>>>(q_bf, outT, out_b,
                                                            stdevv, mean, out);
}

// Round 17
// 1613.604 us; speedup vs baseline: 1.6378x; 1.0043x over previous
//
#include <hip/hip_runtime.h>
#include <hip/hip_bf16.h>
#include <math.h>

#define CDIV(a, b) (((a) + (b) - 1) / (b))
typedef long long ll;
typedef unsigned short ushort_t;

constexpr int Bn = 32;    // batch
constexpr int Sn = 720;   // seq len
constexpr int SnP = 768;  // seq len padded to K-step multiple
constexpr int Cn = 2048;  // channels (tokens after transpose)
constexpr int Dn = 256;   // d_model
constexpr int Pn = 96;    // pred len

typedef __attribute__((ext_vector_type(8))) short bf16x8;
typedef __attribute__((ext_vector_type(4))) float f32x4;

__device__ inline ushort_t rne1(float x) {
  unsigned u = __float_as_uint(x);
  u = (u + 0x7fffu + ((u >> 16) & 1u)) >> 16;
  return (ushort_t)u;
}
__device__ inline float b2f(ushort_t u) { return __uint_as_float(((unsigned)u) << 16); }

__device__ inline void gl_lds16(const void* g, void* l) {
  __builtin_amdgcn_global_load_lds(
      (const __attribute__((address_space(1))) void*)g,
      (__attribute__((address_space(3))) void*)l, 16, 0, 0);
}

// ---------------- instance norm stats over time axis ----------------
__global__ void instnorm_stats(const float* __restrict__ x,
                               float* __restrict__ mean, float* __restrict__ stdev) {
  int c = blockIdx.x * 256 + threadIdx.x;
  int b = blockIdx.y;
  const float* p = x + (ll)b * Sn * Cn + c;
  float s = 0.f, q = 0.f;
  for (int t = 0; t < Sn; ++t) {
    float v = p[(ll)t * Cn];
    s += v; q += v * v;
  }
  float m = s / (float)Sn;
  float var = q / (float)Sn - m * m;
  var = fmaxf(var, 0.f);
  mean[b * Cn + c] = m;
  stdev[b * Cn + c] = sqrtf(var + 1e-5f);
}

// ---------------- normalize + transpose: x[b][s][c] -> xnT[b][c][s] bf16 (K-pad)
__global__ void normT_kernel(const float* __restrict__ X, ushort_t* __restrict__ D,
                             const float* __restrict__ mean,
                             const float* __restrict__ stdev) {
  int b = blockIdx.z;
  __shared__ float tl[32][33];
  int t = threadIdx.x;
  int tx = t & 31, ty = t >> 5;
  int s0 = blockIdx.y * 32, c0 = blockIdx.x * 32;
#pragma unroll
  for (int e = 0; e < 4; ++e) {
    int s = s0 + ty + 8 * e;
    tl[ty + 8 * e][tx] = (s < Sn) ? X[((ll)b * Sn + s) * Cn + c0 + tx] : 0.f;
  }
  __syncthreads();
#pragma unroll
  for (int e = 0; e < 4; ++e) {
    int c = c0 + ty + 8 * e, s = s0 + tx;
    if (s < SnP) {
      float mu = mean[b * Cn + c], sd = stdev[b * Cn + c];
      float v = (s < Sn) ? (tl[tx][ty + 8 * e] - mu) / sd : 0.f;
      D[((ll)b * Cn + c) * SnP + s] = rne1(v);
    }
  }
}

// ---------------- transpose-convert: W[K][N] f32 -> WT[N][KP] bf16 ------------
__global__ void cvtT_kernel(const float* __restrict__ S, ushort_t* __restrict__ D,
                            int K, int N, int KP) {
  int z = blockIdx.z;
  S += (ll)z * K * N;
  D += (ll)z * N * KP;
  __shared__ float tl[32][33];
  int t = threadIdx.x;
  int tx = t & 31, ty = t >> 5;
  int k0 = blockIdx.y * 32, n0 = blockIdx.x * 32;
#pragma unroll
  for (int e = 0; e < 4; ++e) {
    int k = k0 + ty + 8 * e;
    tl[ty + 8 * e][tx] = (k < K && n0 + tx < N) ? S[(ll)k * N + n0 + tx] : 0.f;
  }
  __syncthreads();
#pragma unroll
  for (int e = 0; e < 4; ++e) {
    int n = n0 + ty + 8 * e, kk = k0 + tx;
    if (n < N && kk < KP) D[(ll)n * KP + kk] = rne1(tl[tx][ty + 8 * e]);
  }
}

__global__ void cvt_bf(const float* __restrict__ S, ushort_t* __restrict__ D, int n) {
  int i = blockIdx.x * 256 + threadIdx.x;
  if (i < n) D[i] = rne1(S[i]);
}

// ---------------- canonical bf16 MFMA GEMM: C = A[M][K] * B[N][K]^T ----------
// Double-buffered 2-phase prefetch + XCD-aware bijective block swizzle (T1,
// identity when nwg%8 != 0). K % 32 == 0. MODE bits: 1 = f32 C ; 2 = bf16 C ;
// 4 = bf16 C^T ; 8 = fused KV (c<256 -> Cb row-major, c>=256 -> C^T via Cf).
template <int MODE>
__global__ __launch_bounds__(256) void gemm_bf(
    const ushort_t* __restrict__ A, const ushort_t* __restrict__ B,
    int M, int N, int K, int lda, int ldb, ll sA, ll sB,
    const float* __restrict__ bias, float alpha,
    float* __restrict__ Cf, int ldcf, ll sCf,
    ushort_t* __restrict__ Cb, int ldcb, ll sCb) {
  // ---- XCD swizzle: consecutive tile-neighbors land on the same XCD L2 ----
  int gx = gridDim.x, gy = gridDim.y;
  int nwg = gx * gy * gridDim.z;
  int wg = blockIdx.x + gx * (blockIdx.y + gy * blockIdx.z);
  if ((nwg & 7) == 0) {
    int cpx = nwg >> 3;
    wg = (wg & 7) * cpx + (wg >> 3);
  }
  int g = wg / (gx * gy);
  int rem = wg - g * (gx * gy);
  int by = rem / gx;
  int bx = rem - by * gx;

  A += (ll)g * sA;
  B += (ll)g * sB;
  if (MODE & 1) Cf += (ll)g * sCf;
  if (MODE & 14) Cb += (ll)g * sCb;
  ushort_t* Vt = nullptr;
  if (MODE & 8) Vt = (ushort_t*)Cf + (ll)g * sCf;
  __shared__ ushort_t lds_ab[2][2][128][32];  // [buf][tile][row][k]
  int t = threadIdx.x;
  int m0 = by * 128, n0 = bx * 128;
  int w = t >> 6, lane = t & 63;
  int wm = (w >> 1) * 64, wn = (w & 1) * 64;
  int lrow = lane & 15, kq = lane >> 4;
  int srow = lane >> 2, skcol = (lane & 3) * 8;

  auto stage = [&](int buf, int k0) {
#pragma unroll
    for (int cc = 0; cc < 4; ++cc) {
      int c = w * 4 + cc;
      int tile = c >> 3, rb = (c & 7) * 16;
      int row = rb + srow;
      const ushort_t* src;
      if (tile == 0) {
        int gm = min(m0 + row, M - 1);
        src = &A[(ll)gm * lda + k0 + skcol];
      } else {
        int gn = min(n0 + row, N - 1);
        src = &B[(ll)gn * ldb + k0 + skcol];
      }
      gl_lds16(src, &lds_ab[buf][tile][rb][0]);
    }
  };

  f32x4 acc[4][4] = {};
  int nt = K >> 5;
  stage(0, 0);
  __syncthreads();
  int cur = 0;
  for (int it = 0; it < nt; ++it) {
    if (it + 1 < nt) stage(cur ^ 1, (it + 1) * 32);
    bf16x8 af[4], bfr[4];
#pragma unroll
    for (int i = 0; i < 4; ++i)
      af[i] = *reinterpret_cast<const bf16x8*>(&lds_ab[cur][0][wm + i * 16 + lrow][kq * 8]);
#pragma unroll
    for (int j = 0; j < 4; ++j)
      bfr[j] = *reinterpret_cast<const bf16x8*>(&lds_ab[cur][1][wn + j * 16 + lrow][kq * 8]);
#pragma unroll
    for (int i = 0; i < 4; ++i)
#pragma unroll
      for (int j = 0; j < 4; ++j)
        acc[i][j] = __builtin_amdgcn_mfma_f32_16x16x32_bf16(af[i], bfr[j],
                                                            acc[i][j], 0, 0, 0);
    __syncthreads();
    cur ^= 1;
  }
#pragma unroll
  for (int i = 0; i < 4; ++i) {
    int mb = m0 + wm + i * 16 + kq * 4;
    if (mb >= M) continue;
#pragma unroll
    for (int j = 0; j < 4; ++j) {
      int c = n0 + wn + j * 16 + lrow;
      if (c >= N) continue;
      float bv = bias ? bias[c] : 0.f;
#pragma unroll
      for (int reg = 0; reg < 4; ++reg) {
        int m = mb + reg;
        float v = acc[i][j][reg] * alpha + bv;
        if (MODE & 8) {
          if (c < 256) Cb[(ll)m * ldcb + c] = rne1(v);
          else Vt[(ll)(c - 256) * ldcf + m] = rne1(v);
        } else {
          if (MODE & 1) Cf[(ll)m * ldcf + c] = v;
          if (MODE & 2) Cb[(ll)m * ldcb + c] = rne1(v);
          if (MODE & 4) Cb[(ll)c * ldcb + m] = rne1(v);
        }
      }
    }
  }
}

// ---------------- block reduction helper (blockDim = 256) ----------------
__device__ inline float blk_reduce(float v, volatile float* sh, int op) {
  int lane = threadIdx.x & 63, w = threadIdx.x >> 6;
#pragma unroll
  for (int off = 32; off > 0; off >>= 1) {
    float o = __shfl_down(v, off, 64);
    v = op ? fmaxf(v, o) : (v + o);
  }
  __syncthreads();
  if (lane == 0) sh[w] = v;
  __syncthreads();
  float r = op ? fmaxf(fmaxf(sh[0], sh[1]), fmaxf(sh[2], sh[3]))
               : (sh[0] + sh[1] + sh[2] + sh[3]);
  return r;
}

// ---------------- row softmax: f32 scores in, bf16 probs out ----------------
template <int LL>
__global__ void softmax_bf(const float* __restrict__ S, ushort_t* __restrict__ P) {
  constexpr int NE = (LL + 255) / 256;
  __shared__ float sh[4];
  ll row = blockIdx.x;
  const float* p = S + row * (ll)LL;
  ushort_t* q = P + row * (ll)LL;
  int t = threadIdx.x;
  float e[NE];
  float mx = -INFINITY;
#pragma unroll
  for (int k = 0; k < NE; ++k) {
    int i = t + k * 256;
    if (i < LL) { e[k] = p[i]; mx = fmaxf(mx, e[k]); }
  }
  mx = blk_reduce(mx, sh, 1);
  float sum = 0.f;
#pragma unroll
  for (int k = 0; k < NE; ++k) {
    int i = t + k * 256;
    if (i < LL) { e[k] = __expf(e[k] - mx); sum += e[k]; }
  }
  sum = blk_reduce(sum, sh, 0);
  float inv = 1.f / sum;
#pragma unroll
  for (int k = 0; k < NE; ++k) {
    int i = t + k * 256;
    if (i < LL) q[i] = rne1(e[k] * inv);
  }
}

// ---------------- LayerNorm over D=256; optional bf16 residual ----------------
__global__ void ln_kernel(const float* __restrict__ X, const ushort_t* __restrict__ RESb,
                          float* __restrict__ Yf, ushort_t* __restrict__ Yb, int postadd,
                          const float* __restrict__ gamma, const float* __restrict__ beta) {
  __shared__ float sh[4];
  ll row = blockIdx.x;
  int t = threadIdx.x;
  float r = RESb ? b2f(RESb[row * Dn + t]) : 0.f;
  float v = X[row * Dn + t] + r;
  float m = blk_reduce(v, sh, 0) * (1.f / (float)Dn);
  float d = v - m;
  float var = blk_reduce(d * d, sh, 0) * (1.f / (float)Dn);
  float y = d * rsqrtf(var + 1e-5f) * gamma[t] + beta[t];
  if (Yf) Yf[row * Dn + t] = y;
  if (Yb) Yb[row * Dn + t] = rne1(y + (postadd ? r : 0.f));
}

// --------- batched covariance column stats over the 3 skips (f64) -----------
// skips live contiguously from s1: offsets {0, 4194304, 5242880} floats.
__global__ void colstat_partial3(const float* __restrict__ X0,
                                 double* __restrict__ part) {
  int j = blockIdx.y;
  ll joff = (j == 0) ? 0LL : ((j == 1) ? 4194304LL : 5242880LL);
  int nrows = (j == 0) ? 16384 : ((j == 1) ? 4096 : 1024);
  const float* X = X0 + joff;
  int blk = blockIdx.x, t = threadIdx.x;
  int chunk = CDIV(nrows, 256);
  int r0 = blk * chunk, r1 = min(nrows, r0 + chunk);
  double s = 0.0, q = 0.0;
  for (int r = r0; r < r1; ++r) {
    double v = (double)X[(ll)r * Dn + t];
    s += v; q += v * v;
  }
  part[(ll)j * 131072 + blk * 512 + t] = s;
  part[(ll)j * 131072 + blk * 512 + 256 + t] = q;
}

__global__ void colstat_final3(const double* __restrict__ part,
                               float* __restrict__ cmean, float* __restrict__ cistd) {
  int j = blockIdx.x;
  int nrows = (j == 0) ? 16384 : ((j == 1) ? 4096 : 1024);
  int t = threadIdx.x;
  double s = 0.0, q = 0.0;
  for (int b = 0; b < 256; ++b) {
    s += part[(ll)j * 131072 + b * 512 + t];
    q += part[(ll)j * 131072 + b * 512 + 256 + t];
  }
  double m = s / (double)nrows;
  double var = (q - (double)nrows * m * m) / (double)(nrows - 1);
  var = fmax(var, 0.0);
  cmean[j * 256 + t] = (float)m;
  cistd[j * 256 + t] = (float)(1.0 / (sqrt(var) + 1e-5));
}

// -------- batched lower-triangle cov Gram: 64x64 f64 tiles, fused normalize --
__global__ __launch_bounds__(256) void cov_gram3(const float* __restrict__ X0,
                                                 const float* __restrict__ cmean0,
                                                 const float* __restrict__ cistd0,
                                                 double* __restrict__ part) {
  int j = blockIdx.z;
  int nz = (j == 0) ? 64 : ((j == 1) ? 32 : 16);
  int z = blockIdx.y;
  if (z >= nz) return;
  int nr = (j == 0) ? 16384 : ((j == 1) ? 4096 : 1024);
  ll joff = (j == 0) ? 0LL : ((j == 1) ? 4194304LL : 5242880LL);
  const float* X = X0 + joff;
  const float* cmean = cmean0 + j * 256;
  const float* cistd = cistd0 + j * 256;
  __shared__ double Am[32][66];
  __shared__ double Bq[32][66];
  __shared__ float cmA[64], ciA[64], cmB[64], ciB[64];
  int tile = blockIdx.x;
  int mi = 0;
  while (tile >= mi + 1) { tile -= mi + 1; ++mi; }
  int nj = tile;  // mi >= nj (4x4 blocks of 64)
  int m0 = mi * 64, n0 = nj * 64;
  bool diag = (mi == nj);
  int t = threadIdx.x;
  int tx4 = (t & 15) * 4, ty4 = (t >> 4) * 4;
  if (t < 64) { cmA[t] = cmean[m0 + t]; ciA[t] = cistd[m0 + t]; }
  else if (t < 128) { cmB[t - 64] = cmean[n0 + t - 64]; ciB[t - 64] = cistd[n0 + t - 64]; }
  __syncthreads();
  int chunk = nr / nz;
  int kbeg = z * chunk, kend = kbeg + chunk;
  double acc[4][4] = {};
  const double* Bbase = diag ? &Am[0][0] : &Bq[0][0];
  for (int k0 = kbeg; k0 < kend; k0 += 32) {
#pragma unroll
    for (int e = 0; e < 8; ++e) {
      int idx = t + e * 256;
      int kk = idx >> 6, mm = idx & 63;
      float xa = X[(ll)(k0 + kk) * Dn + m0 + mm];
      Am[kk][mm] = (double)((xa - cmA[mm]) * ciA[mm]);
      if (!diag) {
        float xb = X[(ll)(k0 + kk) * Dn + n0 + mm];
        Bq[kk][mm] = (double)((xb - cmB[mm]) * ciB[mm]);
      }
    }
    __syncthreads();
#pragma unroll 4
    for (int kk = 0; kk < 32; ++kk) {
      double a[4], b[4];
#pragma unroll
      for (int q = 0; q < 4; ++q) a[q] = Am[kk][ty4 + q];
#pragma unroll
      for (int q = 0; q < 4; ++q) b[q] = Bbase[kk * 66 + tx4 + q];
#pragma unroll
      for (int i = 0; i < 4; ++i)
#pragma unroll
        for (int jj = 0; jj < 4; ++jj) acc[i][jj] += a[i] * b[jj];
    }
    __syncthreads();
  }
  ll base = ((ll)((j * 64 + z) * 10 + blockIdx.x)) * 4096;
#pragma unroll
  for (int i = 0; i < 4; ++i)
#pragma unroll
    for (int jj = 0; jj < 4; ++jj)
      part[base + (ty4 + i) * 64 + tx4 + jj] = acc[i][jj];
}

// reduce split-K partials; grid (10 tiles, 16 segments, 3 skips)
__global__ void cov_reduce3(const double* __restrict__ part, double* __restrict__ Cd0) {
  int j = blockIdx.z;
  int nz = (j == 0) ? 64 : ((j == 1) ? 32 : 16);
  int nr = (j == 0) ? 16384 : ((j == 1) ? 4096 : 1024);
  double inv = 1.0 / (double)(nr - 1);
  double* Cd = Cd0 + (ll)j * 65536;
  int tile = blockIdx.x;
  int mi = 0;
  while (tile >= mi + 1) { tile -= mi + 1; ++mi; }
  int nj = tile;
  int e = blockIdx.y * 256 + threadIdx.x;
  int rr = e >> 6, cc = e & 63;
  int m = mi * 64 + rr, n = nj * 64 + cc;
  double s0 = 0.0, s1 = 0.0, s2 = 0.0, s3 = 0.0;
  int z = 0;
  for (; z + 4 <= nz; z += 4) {
    s0 += part[((ll)((j * 64 + z + 0) * 10 + blockIdx.x)) * 4096 + e];
    s1 += part[((ll)((j * 64 + z + 1) * 10 + blockIdx.x)) * 4096 + e];
    s2 += part[((ll)((j * 64 + z + 2) * 10 + blockIdx.x)) * 4096 + e];
    s3 += part[((ll)((j * 64 + z + 3) * 10 + blockIdx.x)) * 4096 + e];
  }
  double s = ((s0 + s1) + (s2 + s3)) * inv + ((m == n) ? 1e-5 : 0.0);
  Cd[m * 256 + n] = s;
}

// ---------------- multi-launch right-looking f64 Cholesky (NB=32) ------------
__global__ __launch_bounds__(256) void chol_step_a(double* __restrict__ mats, int d0) {
  double* A = mats + (ll)blockIdx.x * 65536;
  __shared__ double D[32][33];
  __shared__ double dinv[32];
  int t = threadIdx.x;
  for (int e = t; e < 1024; e += 256) {
    int i = e >> 5, j = e & 31;
    D[i][j] = (j <= i) ? A[(ll)(d0 + i) * 256 + d0 + j] : 0.0;  // upper never computed
  }
  __syncthreads();
  if (t < 32) {
    double x[32];
#pragma unroll
    for (int j = 0; j < 32; ++j) x[j] = D[t][j];
#pragma unroll
    for (int k = 0; k < 32; ++k) {
      double piv = fmax(__shfl(x[k], k, 64), 1e-300);
      double inv = 1.0 / sqrt(piv);
      double lrk = x[k] * inv;  // lane t: l_{t,k}; lane k: d_k
      x[k] = lrk;
#pragma unroll
      for (int j = k + 1; j < 32; ++j) x[j] -= lrk * __shfl(lrk, j, 64);
    }
#pragma unroll
    for (int j = 0; j < 32; ++j) D[t][j] = x[j];
    dinv[t] = 1.0 / x[t];
  }
  __syncthreads();
  // L21 solve: thread t -> row d0+32+t ; y = L11^{-1} a_row
  int r = d0 + 32 + t;
  if (r < 256) {
    double y[32];
#pragma unroll
    for (int j = 0; j < 32; ++j) y[j] = A[(ll)r * 256 + d0 + j];
#pragma unroll
    for (int j = 0; j < 32; ++j) {
      double s = y[j];
#pragma unroll
      for (int i = 0; i < j; ++i) s -= y[i] * D[j][i];
      y[j] = s * dinv[j];
    }
#pragma unroll
    for (int j = 0; j < 32; ++j) A[(ll)r * 256 + d0 + j] = y[j];
  }
  // write factored diag block back (logdet_diag reads diagonal)
  for (int e = t; e < 1024; e += 256)
    A[(ll)(d0 + (e >> 5)) * 256 + d0 + (e & 31)] = D[e >> 5][e & 31];
}

// step B (grid-parallel SYRK): trailing A22 -= L21 L21^T, 32x32 tiles, lower half
__global__ __launch_bounds__(256) void chol_step_b(double* __restrict__ mats, int d0) {
  double* A = mats + (ll)blockIdx.y * 65536;
  int tile = blockIdx.x;
  int i = 0;
  while (tile >= i + 1) { tile -= i + 1; ++i; }
  int j = tile;  // i >= j
  int ri = d0 + 32 + i * 32, rj = d0 + 32 + j * 32;
  __shared__ double Li[32][33];
  __shared__ double Lj[32][33];
  int t = threadIdx.x;
  for (int e = t; e < 1024; e += 256) {
    int rr = e >> 5, kk = e & 31;
    Li[rr][kk] = A[(ll)(ri + rr) * 256 + d0 + kk];
    Lj[rr][kk] = A[(ll)(rj + rr) * 256 + d0 + kk];
  }
  __syncthreads();
  for (int e = t; e < 1024; e += 256) {
    int rr = e >> 5, cc = e & 31;
    double s = 0.0;
#pragma unroll
    for (int k = 0; k < 32; ++k) s += Li[rr][k] * Lj[cc][k];
    A[(ll)(ri + rr) * 256 + rj + cc] -= s;
  }
}

// logdet = 2 * sum log(diag(L)), parallel reduce
__global__ void logdet_diag(const double* __restrict__ mats, double* __restrict__ ld) {
  __shared__ double sh[4];
  const double* A = mats + (ll)blockIdx.x * 65536;
  int t = threadIdx.x;
  double lg = log(A[(ll)t * 257]);
  int lane = t & 63, w = t >> 6;
#pragma unroll
  for (int off = 32; off > 0; off >>= 1) lg += __shfl_down(lg, off, 64);
  if (lane == 0) sh[w] = lg;
  __syncthreads();
  if (t == 0) ld[blockIdx.x] = 2.0 * (sh[0] + sh[1] + sh[2] + sh[3]);
}

__global__ void cov_final(const double* __restrict__ ld, float* __restrict__ outp) {
  outp[0] = (float)(-0.1 / (3.0 * 256.0) * (ld[0] + ld[1] + ld[2]));
}

// ---------------- output head: xph[M][256] @ outT[96][256]^T, scatter+denorm --
__global__ __launch_bounds__(256) void out_mfma(
    const ushort_t* __restrict__ A, const ushort_t* __restrict__ B,
    const float* __restrict__ bias, const float* __restrict__ stdev,
    const float* __restrict__ mean, float* __restrict__ out) {
  constexpr int M = Bn * Cn, N = Pn, K = Dn;
  __shared__ ushort_t lds_ab[2][128][32];
  int t = threadIdx.x;
  // XCD swizzle over the y-grid (512 blocks, %8==0)
  int nwg = gridDim.y;
  int wg = blockIdx.y;
  if ((nwg & 7) == 0) {
    int cpx = nwg >> 3;
    wg = (wg & 7) * cpx + (wg >> 3);
  }
  int m0 = wg * 128;
  int w = t >> 6, lane = t & 63;
  int wm = (w >> 1) * 64, wn = (w & 1) * 64;
  int lrow = lane & 15, kq = lane >> 4;
  int srow = lane >> 2, skcol = (lane & 3) * 8;
  f32x4 acc[4][4] = {};
  for (int k0 = 0; k0 < K; k0 += 32) {
#pragma unroll
    for (int cc = 0; cc < 4; ++cc) {
      int c = w * 4 + cc;
      int tile = c >> 3, rb = (c & 7) * 16;
      int row = rb + srow;
      const ushort_t* src;
      if (tile == 0) {
        src = &A[(ll)(m0 + row) * K + k0 + skcol];
      } else {
        int gn = min(row, N - 1);
        src = &B[(ll)gn * K + k0 + skcol];
      }
      gl_lds16(src, &lds_ab[tile][rb][0]);
    }
    __syncthreads();
    bf16x8 af[4], bfr[4];
#pragma unroll
    for (int i = 0; i < 4; ++i)
      af[i] = *reinterpret_cast<const bf16x8*>(&lds_ab[0][wm + i * 16 + lrow][kq * 8]);
#pragma unroll
    for (int j = 0; j < 4; ++j)
      bfr[j] = *reinterpret_cast<const bf16x8*>(&lds_ab[1][wn + j * 16 + lrow][kq * 8]);
#pragma unroll
    for (int i = 0; i < 4; ++i)
#pragma unroll
      for (int j = 0; j < 4; ++j)
        acc[i][j] = __builtin_amdgcn_mfma_f32_16x16x32_bf16(af[i], bfr[j],
                                                            acc[i][j], 0, 0, 0);
    __syncthreads();
  }
#pragma unroll
  for (int i = 0; i < 4; ++i) {
    int mb = m0 + wm + i * 16 + kq * 4;
#pragma unroll
    for (int j = 0; j < 4; ++j) {
      int p = wn + j * 16 + lrow;
      if (p >= N) continue;
      float bv = bias[p];
#pragma unroll
      for (int reg = 0; reg < 4; ++reg) {
        int m = mb + reg;
        int b = m >> 11, c = m & 2047;
        float v = acc[i][j][reg] + bv;
        out[((ll)(b * Pn + p)) * Cn + c] = v * stdev[m] + mean[m];
      }
    }
  }
}

// =====================================================================
extern "C" void kernel_launch(void* const* d_in, const int* in_sizes, int n_in,
                              void* d_out, int out_size, void* d_ws, size_t ws_size,
                              hipStream_t stream) {
  (void)in_sizes; (void)n_in; (void)out_size; (void)ws_size;
  const float* x_enc = (const float*)d_in[0];
  const float* in_w = (const float*)d_in[4];
  const float* in_b = (const float*)d_in[5];
  const float* lq[3] = {(const float*)d_in[6], (const float*)d_in[7],
                        (const float*)d_in[8]};
  const float* down_w = (const float*)d_in[9];
  const float* down_b = (const float*)d_in[10];
  const float* down_ln = (const float*)d_in[11];
  const float* pred_w = (const float*)d_in[12];
  const float* pred_b = (const float*)d_in[13];
  const float* up_w = (const float*)d_in[14];
  const float* up_b = (const float*)d_in[15];
  const float* up_ln = (const float*)d_in[16];
  const float* out_w = (const float*)d_in[17];
  const float* out_b = (const float*)d_in[18];
  float* out = (float*)d_out;

  float* ws = (float*)d_ws;
  size_t off = 0;
  auto alloc = [&](size_t n) {
    n = (n + 3) & ~(size_t)3;  // 16B alignment
    float* p = ws + off;
    off += n;
    return p;
  };
  float* mean = alloc((size_t)Bn * Cn);
  float* stdevv = alloc((size_t)Bn * Cn);
  float* cmean = alloc(3 * 256);
  float* cistd = alloc(3 * 256);
  double* part = (double*)alloc(3 * 256 * 512 * 2);
  double* ld = (double*)alloc(32);
  double* covd = (double*)alloc(3 * 65536 * 2);
  float* s1 = alloc((size_t)Bn * 512 * Dn);   // s1,s2,s3 contiguous (cov batched)
  float* s2 = alloc((size_t)Bn * 128 * Dn);
  float* s3 = alloc((size_t)Bn * 32 * Dn);
  float* attn = alloc((size_t)Bn * 512 * 2048);     // f32 scores; also xnT(bf16)
  float* sbuf = alloc((size_t)16777216);            // attn_bf / o2 f32 / covpart
  ushort_t* h_bf = (ushort_t*)alloc((size_t)Bn * Cn * Dn / 2);
  ushort_t* s1b = (ushort_t*)alloc((size_t)Bn * 512 * Dn / 2);
  ushort_t* s2b = (ushort_t*)alloc((size_t)Bn * 128 * Dn / 2);
  ushort_t* s3b = (ushort_t*)alloc((size_t)Bn * 32 * Dn / 2);
  ushort_t* xpb = (ushort_t*)alloc((size_t)Bn * 32 * Dn / 2);
  ushort_t* xu0b = (ushort_t*)alloc((size_t)Bn * 128 * Dn / 2);
  ushort_t* xu1b = (ushort_t*)alloc((size_t)Bn * 512 * Dn / 2);
  ushort_t* qd_b = (ushort_t*)alloc(512 * 256 / 2);
  ushort_t* lqb0 = (ushort_t*)alloc(512 * 256 / 2);
  ushort_t* lqb1 = (ushort_t*)alloc(128 * 256 / 2);
  ushort_t* lqb2 = (ushort_t*)alloc(32 * 256 / 2);
  ushort_t* in_wT = (ushort_t*)alloc(256 * SnP / 2);
  ushort_t* downT = (ushort_t*)alloc(12 * 65536 / 2);
  ushort_t* upT = (ushort_t*)alloc(12 * 65536 / 2);
  ushort_t* predT = (ushort_t*)alloc(65536 / 2);
  ushort_t* outT = (ushort_t*)alloc(96 * 256 / 2);
  ushort_t* q_bf = (ushort_t*)alloc((size_t)Bn * 2048 * Dn / 2);  // also o1, xph
  ushort_t* k_bf = (ushort_t*)alloc((size_t)Bn * 2048 * Dn / 2);
  ushort_t* vT = (ushort_t*)alloc((size_t)Bn * 2048 * Dn / 2);

  ushort_t* xnT = (ushort_t*)attn;
  ushort_t* attn_b = (ushort_t*)sbuf;
  float* o2 = sbuf;
  double* covpart = (double*)sbuf;
  const float scale = 0.0625f;
  const float* npf = nullptr;

  // ---- prep: stats, normalize+transpose input, weight converts ----
  instnorm_stats<<<dim3(Cn / 256, Bn), 256, 0, stream>>>(x_enc, mean, stdevv);
  normT_kernel<<<dim3(Cn / 32, SnP / 32, Bn), 256, 0, stream>>>(x_enc, xnT, mean,
                                                                stdevv);
  cvtT_kernel<<<dim3(8, 8, 12), 256, 0, stream>>>(down_w, downT, 256, 256, 256);
  cvtT_kernel<<<dim3(8, 8, 12), 256, 0, stream>>>(up_w, upT, 256, 256, 256);
  cvtT_kernel<<<dim3(8, 8, 1), 256, 0, stream>>>(pred_w, predT, 256, 256, 256);
  cvtT_kernel<<<dim3(8, SnP / 32, 1), 256, 0, stream>>>(in_w, in_wT, Sn, 256, SnP);
  cvtT_kernel<<<dim3(3, 8, 1), 256, 0, stream>>>(out_w, outT, 256, Pn, 256);
  cvt_bf<<<512, 256, 0, stream>>>(lq[0], lqb0, 512 * 256);
  cvt_bf<<<128, 256, 0, stream>>>(lq[1], lqb1, 128 * 256);
  cvt_bf<<<32, 256, 0, stream>>>(lq[2], lqb2, 32 * 256);

  // ---- h = xn^T @ in_w + b : bf16 out (K padded to 768) ----
  gemm_bf<2><<<dim3(2, 16, Bn), 256, 0, stream>>>(
      xnT, in_wT, Cn, Dn, SnP, SnP, SnP, (ll)Cn * SnP, 0, in_b, 1.f,
      nullptr, 0, 0, h_bf, Dn, (ll)Cn * Dn);

  ushort_t* lqb[3] = {lqb0, lqb1, lqb2};
  float* skf[3] = {s1, s2, s3};
  ushort_t* skb[3] = {s1b, s2b, s3b};
  int Ls[4] = {2048, 512, 128, 32};
  const ushort_t* xinb = h_bf;

  // ---------------- down layers ----------------
  for (int i = 0; i < 3; ++i) {
    int L = Ls[i], Lq = Ls[i + 1];
    const ushort_t* WqT = downT + (size_t)(i * 4 + 0) * 65536;
    const ushort_t* WkvT = downT + (size_t)(i * 4 + 1) * 65536;  // Wk||Wv
    const ushort_t* WoT = downT + (size_t)(i * 4 + 3) * 65536;
    const float* bq = down_b + (i * 4 + 0) * 256;
    const float* bkv = down_b + (i * 4 + 1) * 256;  // bk||bv (512)
    const float* bo = down_b + (i * 4 + 3) * 256;

    gemm_bf<2><<<dim3(2, CDIV(Lq, 128), 1), 256, 0, stream>>>(
        lqb[i], WqT, Lq, Dn, Dn, Dn, Dn, 0, 0, bq, 1.f, nullptr, 0, 0, qd_b, Dn, 0);
    // fused K+V projection: c<256 -> k_bf (row), c>=256 -> vT (transposed)
    gemm_bf<8><<<dim3(4, L / 128, Bn), 256, 0, stream>>>(
        xinb, WkvT, L, 512, Dn, Dn, Dn, (ll)L * Dn, 0, bkv, 1.f,
        (float*)vT, L, (ll)Dn * L, k_bf, Dn, (ll)L * Dn);
    gemm_bf<1><<<dim3(L / 128, CDIV(Lq, 128), Bn), 256, 0, stream>>>(
        qd_b, k_bf, Lq, L, Dn, Dn, Dn, 0, (ll)L * Dn, npf, scale,
        attn, L, (ll)Lq * L, nullptr, 0, 0);
    if (L == 2048) softmax_bf<2048><<<Bn * Lq, 256, 0, stream>>>(attn, attn_b);
    else if (L == 512) softmax_bf<512><<<Bn * Lq, 256, 0, stream>>>(attn, attn_b);
    else softmax_bf<128><<<Bn * Lq, 256, 0, stream>>>(attn, attn_b);
    gemm_bf<2><<<dim3(2, CDIV(Lq, 128), Bn), 256, 0, stream>>>(
        attn_b, vT, Lq, Dn, L, L, L, (ll)Lq * L, (ll)Dn * L, npf, 1.f,
        nullptr, 0, 0, q_bf, Dn, (ll)Lq * Dn);
    gemm_bf<1><<<dim3(2, CDIV(Bn * Lq, 128), 1), 256, 0, stream>>>(
        q_bf, WoT, Bn * Lq, Dn, Dn, Dn, Dn, 0, 0, bo, 1.f, o2, Dn, 0, nullptr, 0, 0);
    ln_kernel<<<Bn * Lq, 256, 0, stream>>>(o2, nullptr, skf[i], skb[i], 0,
                                           down_ln + (i * 2 + 0) * 256,
                                           down_ln + (i * 2 + 1) * 256);
    xinb = skb[i];
  }

  // ------- covariance loss (batched front-end + NB=32 Cholesky) --------------
  colstat_partial3<<<dim3(256, 3), 256, 0, stream>>>(s1, part);
  colstat_final3<<<3, 256, 0, stream>>>(part, cmean, cistd);
  cov_gram3<<<dim3(10, 64, 3), 256, 0, stream>>>(s1, cmean, cistd, covpart);
  cov_reduce3<<<dim3(10, 16, 3), 256, 0, stream>>>(covpart, covd);
  for (int kb = 0; kb < 8; ++kb) {
    chol_step_a<<<3, 256, 0, stream>>>(covd, kb * 32);
    int T = 7 - kb;
    if (T > 0)
      chol_step_b<<<dim3(T * (T + 1) / 2, 3), 256, 0, stream>>>(covd, kb * 32);
  }
  logdet_diag<<<3, 256, 0, stream>>>(covd, ld);
  cov_final<<<1, 1, 0, stream>>>(ld, out + 6291456);

  // ---------------- pred head ----------------
  gemm_bf<2><<<dim3(2, 8, 1), 256, 0, stream>>>(
      s3b, predT, Bn * 32, Dn, Dn, Dn, Dn, 0, 0, pred_b, 1.f,
      nullptr, 0, 0, xpb, Dn, 0);

  // ---------------- up layers ----------------
  int Lks[3] = {32, 128, 512}, Lqs[3] = {128, 512, 2048};
  const ushort_t* qinb[3] = {s2b, s1b, h_bf};
  const ushort_t* xinbs[3] = {xpb, xu0b, xu1b};
  ushort_t* xoutb[3] = {xu0b, xu1b, q_bf};  // final writes xph into q_bf
  for (int i = 0; i < 3; ++i) {
    int Lk = Lks[i], Lq = Lqs[i];
    const ushort_t* WqT = upT + (size_t)(i * 4 + 0) * 65536;
    const ushort_t* WkvT = upT + (size_t)(i * 4 + 1) * 65536;  // Wk||Wv
    const ushort_t* WoT = upT + (size_t)(i * 4 + 3) * 65536;
    const float* bq = up_b + (i * 4 + 0) * 256;
    const float* bkv = up_b + (i * 4 + 1) * 256;  // bk||bv (512)
    const float* bo = up_b + (i * 4 + 3) * 256;

    gemm_bf<2><<<dim3(2, (Bn * Lq) / 128, 1), 256, 0, stream>>>(
        qinb[i], WqT, Bn * Lq, Dn, Dn, Dn, Dn, 0, 0, bq, 1.f,
        nullptr, 0, 0, q_bf, Dn, 0);
    gemm_bf<8><<<dim3(4, CDIV(Lk, 128), Bn), 256, 0, stream>>>(
        xinbs[i], WkvT, Lk, 512, Dn, Dn, Dn, (ll)Lk * Dn, 0, bkv, 1.f,
        (float*)vT, Lk, (ll)Dn * Lk, k_bf, Dn, (ll)Lk * Dn);
    gemm_bf<1><<<dim3(CDIV(Lk, 128), CDIV(Lq, 128), Bn), 256, 0, stream>>>(
        q_bf, k_bf, Lq, Lk, Dn, Dn, Dn, (ll)Lq * Dn, (ll)Lk * Dn, npf, scale,
        attn, Lk, (ll)Lq * Lk, nullptr, 0, 0);
    if (Lk == 32) softmax_bf<32><<<Bn * Lq, 256, 0, stream>>>(attn, attn_b);
    else if (Lk == 128) softmax_bf<128><<<Bn * Lq, 256, 0, stream>>>(attn, attn_b);
    else softmax_bf<512><<<Bn * Lq, 256, 0, stream>>>(attn, attn_b);
    gemm_bf<2><<<dim3(2, CDIV(Lq, 128), Bn), 256, 0, stream>>>(
        attn_b, vT, Lq, Dn, Lk, Lk, Lk, (ll)Lq * Lk, (ll)Dn * Lk, npf, 1.f,
        nullptr, 0, 0, q_bf, Dn, (ll)Lq * Dn);
    gemm_bf<1><<<dim3(2, (Bn * Lq) / 128, 1), 256, 0, stream>>>(
        q_bf, WoT, Bn * Lq, Dn, Dn, Dn, Dn, 0, 0, bo, 1.f, o2, Dn, 0, nullptr, 0, 0);
    ln_kernel<<<Bn * Lq, 256, 0, stream>>>(o2, qinb[i], nullptr, xoutb[i],
                                           (i == 2) ? 1 : 0,
                                           up_ln + (i * 2 + 0) * 256,
                                           up_ln + (i * 2 + 1) * 256);
  }

  // ---------------- output head: MFMA + transpose + de-norm ----------------
  out_mfma<<<dim3(1, (Bn * Cn) / 128, 1), 256, 0, stream>>>(q_bf, outT, out_b,
                                                            stdevv, mean, out);
}

// Round 18
// 1556.077 us; speedup vs baseline: 1.6984x; 1.0370x over previous
//
#include <hip/hip_runtime.h>
#include <hip/hip_bf16.h>
#include <math.h>

#define CDIV(a, b) (((a) + (b) - 1) / (b))
typedef long long ll;
typedef unsigned short ushort_t;

constexpr int Bn = 32;    // batch
constexpr int Sn = 720;   // seq len
constexpr int SnP = 768;  // seq len padded to K-step multiple
constexpr int Cn = 2048;  // channels (tokens after transpose)
constexpr int Dn = 256;   // d_model
constexpr int Pn = 96;    // pred len

typedef __attribute__((ext_vector_type(8))) short bf16x8;
typedef __attribute__((ext_vector_type(4))) float f32x4;

__device__ inline ushort_t rne1(float x) {
  unsigned u = __float_as_uint(x);
  u = (u + 0x7fffu + ((u >> 16) & 1u)) >> 16;
  return (ushort_t)u;
}
__device__ inline float b2f(ushort_t u) { return __uint_as_float(((unsigned)u) << 16); }

__device__ inline void gl_lds16(const void* g, void* l) {
  __builtin_amdgcn_global_load_lds(
      (const __attribute__((address_space(1))) void*)g,
      (__attribute__((address_space(3))) void*)l, 16, 0, 0);
}

// ---------------- instance norm stats over time axis ----------------
__global__ void instnorm_stats(const float* __restrict__ x,
                               float* __restrict__ mean, float* __restrict__ stdev) {
  int c = blockIdx.x * 256 + threadIdx.x;
  int b = blockIdx.y;
  const float* p = x + (ll)b * Sn * Cn + c;
  float s = 0.f, q = 0.f;
  for (int t = 0; t < Sn; ++t) {
    float v = p[(ll)t * Cn];
    s += v; q += v * v;
  }
  float m = s / (float)Sn;
  float var = q / (float)Sn - m * m;
  var = fmaxf(var, 0.f);
  mean[b * Cn + c] = m;
  stdev[b * Cn + c] = sqrtf(var + 1e-5f);
}

// ---------------- normalize + transpose: x[b][s][c] -> xnT[b][c][s] bf16 (K-pad)
__global__ void normT_kernel(const float* __restrict__ X, ushort_t* __restrict__ D,
                             const float* __restrict__ mean,
                             const float* __restrict__ stdev) {
  int b = blockIdx.z;
  __shared__ float tl[32][33];
  int t = threadIdx.x;
  int tx = t & 31, ty = t >> 5;
  int s0 = blockIdx.y * 32, c0 = blockIdx.x * 32;
#pragma unroll
  for (int e = 0; e < 4; ++e) {
    int s = s0 + ty + 8 * e;
    tl[ty + 8 * e][tx] = (s < Sn) ? X[((ll)b * Sn + s) * Cn + c0 + tx] : 0.f;
  }
  __syncthreads();
#pragma unroll
  for (int e = 0; e < 4; ++e) {
    int c = c0 + ty + 8 * e, s = s0 + tx;
    if (s < SnP) {
      float mu = mean[b * Cn + c], sd = stdev[b * Cn + c];
      float v = (s < Sn) ? (tl[tx][ty + 8 * e] - mu) / sd : 0.f;
      D[((ll)b * Cn + c) * SnP + s] = rne1(v);
    }
  }
}

// ---------------- transpose-convert: W[K][N] f32 -> WT[N][KP] bf16 ------------
__global__ void cvtT_kernel(const float* __restrict__ S, ushort_t* __restrict__ D,
                            int K, int N, int KP) {
  int z = blockIdx.z;
  S += (ll)z * K * N;
  D += (ll)z * N * KP;
  __shared__ float tl[32][33];
  int t = threadIdx.x;
  int tx = t & 31, ty = t >> 5;
  int k0 = blockIdx.y * 32, n0 = blockIdx.x * 32;
#pragma unroll
  for (int e = 0; e < 4; ++e) {
    int k = k0 + ty + 8 * e;
    tl[ty + 8 * e][tx] = (k < K && n0 + tx < N) ? S[(ll)k * N + n0 + tx] : 0.f;
  }
  __syncthreads();
#pragma unroll
  for (int e = 0; e < 4; ++e) {
    int n = n0 + ty + 8 * e, kk = k0 + tx;
    if (n < N && kk < KP) D[(ll)n * KP + kk] = rne1(tl[tx][ty + 8 * e]);
  }
}

__global__ void cvt_bf(const float* __restrict__ S, ushort_t* __restrict__ D, int n) {
  int i = blockIdx.x * 256 + threadIdx.x;
  if (i < n) D[i] = rne1(S[i]);
}

// ---------------- canonical bf16 MFMA GEMM: C = A[M][K] * B[N][K]^T ----------
// Double-buffered 2-phase prefetch + XCD-aware bijective block swizzle (T1,
// identity when nwg%8 != 0). K % 32 == 0. MODE bits: 1 = f32 C ; 2 = bf16 C ;
// 4 = bf16 C^T ; 8 = fused KV (c<256 -> Cb row-major, c>=256 -> C^T via Cf).
template <int MODE>
__global__ __launch_bounds__(256) void gemm_bf(
    const ushort_t* __restrict__ A, const ushort_t* __restrict__ B,
    int M, int N, int K, int lda, int ldb, ll sA, ll sB,
    const float* __restrict__ bias, float alpha,
    float* __restrict__ Cf, int ldcf, ll sCf,
    ushort_t* __restrict__ Cb, int ldcb, ll sCb) {
  // ---- XCD swizzle: consecutive tile-neighbors land on the same XCD L2 ----
  int gx = gridDim.x, gy = gridDim.y;
  int nwg = gx * gy * gridDim.z;
  int wg = blockIdx.x + gx * (blockIdx.y + gy * blockIdx.z);
  if ((nwg & 7) == 0) {
    int cpx = nwg >> 3;
    wg = (wg & 7) * cpx + (wg >> 3);
  }
  int g = wg / (gx * gy);
  int rem = wg - g * (gx * gy);
  int by = rem / gx;
  int bx = rem - by * gx;

  A += (ll)g * sA;
  B += (ll)g * sB;
  if (MODE & 1) Cf += (ll)g * sCf;
  if (MODE & 14) Cb += (ll)g * sCb;
  ushort_t* Vt = nullptr;
  if (MODE & 8) Vt = (ushort_t*)Cf + (ll)g * sCf;
  __shared__ ushort_t lds_ab[2][2][128][32];  // [buf][tile][row][k]
  int t = threadIdx.x;
  int m0 = by * 128, n0 = bx * 128;
  int w = t >> 6, lane = t & 63;
  int wm = (w >> 1) * 64, wn = (w & 1) * 64;
  int lrow = lane & 15, kq = lane >> 4;
  int srow = lane >> 2, skcol = (lane & 3) * 8;

  auto stage = [&](int buf, int k0) {
#pragma unroll
    for (int cc = 0; cc < 4; ++cc) {
      int c = w * 4 + cc;
      int tile = c >> 3, rb = (c & 7) * 16;
      int row = rb + srow;
      const ushort_t* src;
      if (tile == 0) {
        int gm = min(m0 + row, M - 1);
        src = &A[(ll)gm * lda + k0 + skcol];
      } else {
        int gn = min(n0 + row, N - 1);
        src = &B[(ll)gn * ldb + k0 + skcol];
      }
      gl_lds16(src, &lds_ab[buf][tile][rb][0]);
    }
  };

  f32x4 acc[4][4] = {};
  int nt = K >> 5;
  stage(0, 0);
  __syncthreads();
  int cur = 0;
  for (int it = 0; it < nt; ++it) {
    if (it + 1 < nt) stage(cur ^ 1, (it + 1) * 32);
    bf16x8 af[4], bfr[4];
#pragma unroll
    for (int i = 0; i < 4; ++i)
      af[i] = *reinterpret_cast<const bf16x8*>(&lds_ab[cur][0][wm + i * 16 + lrow][kq * 8]);
#pragma unroll
    for (int j = 0; j < 4; ++j)
      bfr[j] = *reinterpret_cast<const bf16x8*>(&lds_ab[cur][1][wn + j * 16 + lrow][kq * 8]);
#pragma unroll
    for (int i = 0; i < 4; ++i)
#pragma unroll
      for (int j = 0; j < 4; ++j)
        acc[i][j] = __builtin_amdgcn_mfma_f32_16x16x32_bf16(af[i], bfr[j],
                                                            acc[i][j], 0, 0, 0);
    __syncthreads();
    cur ^= 1;
  }
#pragma unroll
  for (int i = 0; i < 4; ++i) {
    int mb = m0 + wm + i * 16 + kq * 4;
    if (mb >= M) continue;
#pragma unroll
    for (int j = 0; j < 4; ++j) {
      int c = n0 + wn + j * 16 + lrow;
      if (c >= N) continue;
      float bv = bias ? bias[c] : 0.f;
#pragma unroll
      for (int reg = 0; reg < 4; ++reg) {
        int m = mb + reg;
        float v = acc[i][j][reg] * alpha + bv;
        if (MODE & 8) {
          if (c < 256) Cb[(ll)m * ldcb + c] = rne1(v);
          else Vt[(ll)(c - 256) * ldcf + m] = rne1(v);
        } else {
          if (MODE & 1) Cf[(ll)m * ldcf + c] = v;
          if (MODE & 2) Cb[(ll)m * ldcb + c] = rne1(v);
          if (MODE & 4) Cb[(ll)c * ldcb + m] = rne1(v);
        }
      }
    }
  }
}

// ---------------- block reduction helper (blockDim = 256) ----------------
__device__ inline float blk_reduce(float v, volatile float* sh, int op) {
  int lane = threadIdx.x & 63, w = threadIdx.x >> 6;
#pragma unroll
  for (int off = 32; off > 0; off >>= 1) {
    float o = __shfl_down(v, off, 64);
    v = op ? fmaxf(v, o) : (v + o);
  }
  __syncthreads();
  if (lane == 0) sh[w] = v;
  __syncthreads();
  float r = op ? fmaxf(fmaxf(sh[0], sh[1]), fmaxf(sh[2], sh[3]))
               : (sh[0] + sh[1] + sh[2] + sh[3]);
  return r;
}

// ---------------- row softmax: bf16 scores in, bf16 probs out ----------------
template <int LL>
__global__ void softmax_bf(const ushort_t* __restrict__ S, ushort_t* __restrict__ P) {
  constexpr int NE = (LL + 255) / 256;
  __shared__ float sh[4];
  ll row = blockIdx.x;
  const ushort_t* p = S + row * (ll)LL;
  ushort_t* q = P + row * (ll)LL;
  int t = threadIdx.x;
  float e[NE];
  float mx = -INFINITY;
#pragma unroll
  for (int k = 0; k < NE; ++k) {
    int i = t + k * 256;
    if (i < LL) { e[k] = b2f(p[i]); mx = fmaxf(mx, e[k]); }
  }
  mx = blk_reduce(mx, sh, 1);
  float sum = 0.f;
#pragma unroll
  for (int k = 0; k < NE; ++k) {
    int i = t + k * 256;
    if (i < LL) { e[k] = __expf(e[k] - mx); sum += e[k]; }
  }
  sum = blk_reduce(sum, sh, 0);
  float inv = 1.f / sum;
#pragma unroll
  for (int k = 0; k < NE; ++k) {
    int i = t + k * 256;
    if (i < LL) q[i] = rne1(e[k] * inv);
  }
}

// ---------------- LayerNorm over D=256; optional bf16 residual ----------------
__global__ void ln_kernel(const float* __restrict__ X, const ushort_t* __restrict__ RESb,
                          float* __restrict__ Yf, ushort_t* __restrict__ Yb, int postadd,
                          const float* __restrict__ gamma, const float* __restrict__ beta) {
  __shared__ float sh[4];
  ll row = blockIdx.x;
  int t = threadIdx.x;
  float r = RESb ? b2f(RESb[row * Dn + t]) : 0.f;
  float v = X[row * Dn + t] + r;
  float m = blk_reduce(v, sh, 0) * (1.f / (float)Dn);
  float d = v - m;
  float var = blk_reduce(d * d, sh, 0) * (1.f / (float)Dn);
  float y = d * rsqrtf(var + 1e-5f) * gamma[t] + beta[t];
  if (Yf) Yf[row * Dn + t] = y;
  if (Yb) Yb[row * Dn + t] = rne1(y + (postadd ? r : 0.f));
}

// --------- batched covariance column stats over the 3 skips (f64) -----------
// skips live contiguously from s1: offsets {0, 4194304, 5242880} floats.
__global__ void colstat_partial3(const float* __restrict__ X0,
                                 double* __restrict__ part) {
  int j = blockIdx.y;
  ll joff = (j == 0) ? 0LL : ((j == 1) ? 4194304LL : 5242880LL);
  int nrows = (j == 0) ? 16384 : ((j == 1) ? 4096 : 1024);
  const float* X = X0 + joff;
  int blk = blockIdx.x, t = threadIdx.x;
  int chunk = CDIV(nrows, 256);
  int r0 = blk * chunk, r1 = min(nrows, r0 + chunk);
  double s = 0.0, q = 0.0;
  for (int r = r0; r < r1; ++r) {
    double v = (double)X[(ll)r * Dn + t];
    s += v; q += v * v;
  }
  part[(ll)j * 131072 + blk * 512 + t] = s;
  part[(ll)j * 131072 + blk * 512 + 256 + t] = q;
}

__global__ void colstat_final3(const double* __restrict__ part,
                               float* __restrict__ cmean, float* __restrict__ cistd) {
  int j = blockIdx.x;
  int nrows = (j == 0) ? 16384 : ((j == 1) ? 4096 : 1024);
  int t = threadIdx.x;
  double s = 0.0, q = 0.0;
  for (int b = 0; b < 256; ++b) {
    s += part[(ll)j * 131072 + b * 512 + t];
    q += part[(ll)j * 131072 + b * 512 + 256 + t];
  }
  double m = s / (double)nrows;
  double var = (q - (double)nrows * m * m) / (double)(nrows - 1);
  var = fmax(var, 0.0);
  cmean[j * 256 + t] = (float)m;
  cistd[j * 256 + t] = (float)(1.0 / (sqrt(var) + 1e-5));
}

// -------- batched lower-triangle cov Gram: 64x64 f64 tiles, fused normalize --
__global__ __launch_bounds__(256) void cov_gram3(const float* __restrict__ X0,
                                                 const float* __restrict__ cmean0,
                                                 const float* __restrict__ cistd0,
                                                 double* __restrict__ part) {
  int j = blockIdx.z;
  int nz = (j == 0) ? 64 : ((j == 1) ? 32 : 16);
  int z = blockIdx.y;
  if (z >= nz) return;
  int nr = (j == 0) ? 16384 : ((j == 1) ? 4096 : 1024);
  ll joff = (j == 0) ? 0LL : ((j == 1) ? 4194304LL : 5242880LL);
  const float* X = X0 + joff;
  const float* cmean = cmean0 + j * 256;
  const float* cistd = cistd0 + j * 256;
  __shared__ double Am[32][66];
  __shared__ double Bq[32][66];
  __shared__ float cmA[64], ciA[64], cmB[64], ciB[64];
  int tile = blockIdx.x;
  int mi = 0;
  while (tile >= mi + 1) { tile -= mi + 1; ++mi; }
  int nj = tile;  // mi >= nj (4x4 blocks of 64)
  int m0 = mi * 64, n0 = nj * 64;
  bool diag = (mi == nj);
  int t = threadIdx.x;
  int tx4 = (t & 15) * 4, ty4 = (t >> 4) * 4;
  if (t < 64) { cmA[t] = cmean[m0 + t]; ciA[t] = cistd[m0 + t]; }
  else if (t < 128) { cmB[t - 64] = cmean[n0 + t - 64]; ciB[t - 64] = cistd[n0 + t - 64]; }
  __syncthreads();
  int chunk = nr / nz;
  int kbeg = z * chunk, kend = kbeg + chunk;
  double acc[4][4] = {};
  const double* Bbase = diag ? &Am[0][0] : &Bq[0][0];
  for (int k0 = kbeg; k0 < kend; k0 += 32) {
#pragma unroll
    for (int e = 0; e < 8; ++e) {
      int idx = t + e * 256;
      int kk = idx >> 6, mm = idx & 63;
      float xa = X[(ll)(k0 + kk) * Dn + m0 + mm];
      Am[kk][mm] = (double)((xa - cmA[mm]) * ciA[mm]);
      if (!diag) {
        float xb = X[(ll)(k0 + kk) * Dn + n0 + mm];
        Bq[kk][mm] = (double)((xb - cmB[mm]) * ciB[mm]);
      }
    }
    __syncthreads();
#pragma unroll 4
    for (int kk = 0; kk < 32; ++kk) {
      double a[4], b[4];
#pragma unroll
      for (int q = 0; q < 4; ++q) a[q] = Am[kk][ty4 + q];
#pragma unroll
      for (int q = 0; q < 4; ++q) b[q] = Bbase[kk * 66 + tx4 + q];
#pragma unroll
      for (int i = 0; i < 4; ++i)
#pragma unroll
        for (int jj = 0; jj < 4; ++jj) acc[i][jj] += a[i] * b[jj];
    }
    __syncthreads();
  }
  ll base = ((ll)((j * 64 + z) * 10 + blockIdx.x)) * 4096;
#pragma unroll
  for (int i = 0; i < 4; ++i)
#pragma unroll
    for (int jj = 0; jj < 4; ++jj)
      part[base + (ty4 + i) * 64 + tx4 + jj] = acc[i][jj];
}

// reduce split-K partials; grid (10 tiles, 16 segments, 3 skips)
__global__ void cov_reduce3(const double* __restrict__ part, double* __restrict__ Cd0) {
  int j = blockIdx.z;
  int nz = (j == 0) ? 64 : ((j == 1) ? 32 : 16);
  int nr = (j == 0) ? 16384 : ((j == 1) ? 4096 : 1024);
  double inv = 1.0 / (double)(nr - 1);
  double* Cd = Cd0 + (ll)j * 65536;
  int tile = blockIdx.x;
  int mi = 0;
  while (tile >= mi + 1) { tile -= mi + 1; ++mi; }
  int nj = tile;
  int e = blockIdx.y * 256 + threadIdx.x;
  int rr = e >> 6, cc = e & 63;
  int m = mi * 64 + rr, n = nj * 64 + cc;
  double s0 = 0.0, s1 = 0.0, s2 = 0.0, s3 = 0.0;
  int z = 0;
  for (; z + 4 <= nz; z += 4) {
    s0 += part[((ll)((j * 64 + z + 0) * 10 + blockIdx.x)) * 4096 + e];
    s1 += part[((ll)((j * 64 + z + 1) * 10 + blockIdx.x)) * 4096 + e];
    s2 += part[((ll)((j * 64 + z + 2) * 10 + blockIdx.x)) * 4096 + e];
    s3 += part[((ll)((j * 64 + z + 3) * 10 + blockIdx.x)) * 4096 + e];
  }
  double s = ((s0 + s1) + (s2 + s3)) * inv + ((m == n) ? 1e-5 : 0.0);
  Cd[m * 256 + n] = s;
}

// ---------------- multi-launch right-looking f64 Cholesky (NB=32) ------------
__global__ __launch_bounds__(256) void chol_step_a(double* __restrict__ mats, int d0) {
  double* A = mats + (ll)blockIdx.x * 65536;
  __shared__ double D[32][33];
  __shared__ double dinv[32];
  int t = threadIdx.x;
  for (int e = t; e < 1024; e += 256) {
    int i = e >> 5, j = e & 31;
    D[i][j] = (j <= i) ? A[(ll)(d0 + i) * 256 + d0 + j] : 0.0;  // upper never computed
  }
  __syncthreads();
  if (t < 32) {
    double x[32];
#pragma unroll
    for (int j = 0; j < 32; ++j) x[j] = D[t][j];
#pragma unroll
    for (int k = 0; k < 32; ++k) {
      double piv = fmax(__shfl(x[k], k, 64), 1e-300);
      double inv = 1.0 / sqrt(piv);
      double lrk = x[k] * inv;  // lane t: l_{t,k}; lane k: d_k
      x[k] = lrk;
#pragma unroll
      for (int j = k + 1; j < 32; ++j) x[j] -= lrk * __shfl(lrk, j, 64);
    }
#pragma unroll
    for (int j = 0; j < 32; ++j) D[t][j] = x[j];
    dinv[t] = 1.0 / x[t];
  }
  __syncthreads();
  // L21 solve: thread t -> row d0+32+t ; y = L11^{-1} a_row
  int r = d0 + 32 + t;
  if (r < 256) {
    double y[32];
#pragma unroll
    for (int j = 0; j < 32; ++j) y[j] = A[(ll)r * 256 + d0 + j];
#pragma unroll
    for (int j = 0; j < 32; ++j) {
      double s = y[j];
#pragma unroll
      for (int i = 0; i < j; ++i) s -= y[i] * D[j][i];
      y[j] = s * dinv[j];
    }
#pragma unroll
    for (int j = 0; j < 32; ++j) A[(ll)r * 256 + d0 + j] = y[j];
  }
  // write factored diag block back (logdet_diag reads diagonal)
  for (int e = t; e < 1024; e += 256)
    A[(ll)(d0 + (e >> 5)) * 256 + d0 + (e & 31)] = D[e >> 5][e & 31];
}

// step B (grid-parallel SYRK): trailing A22 -= L21 L21^T, 32x32 tiles, lower half
__global__ __launch_bounds__(256) void chol_step_b(double* __restrict__ mats, int d0) {
  double* A = mats + (ll)blockIdx.y * 65536;
  int tile = blockIdx.x;
  int i = 0;
  while (tile >= i + 1) { tile -= i + 1; ++i; }
  int j = tile;  // i >= j
  int ri = d0 + 32 + i * 32, rj = d0 + 32 + j * 32;
  __shared__ double Li[32][33];
  __shared__ double Lj[32][33];
  int t = threadIdx.x;
  for (int e = t; e < 1024; e += 256) {
    int rr = e >> 5, kk = e & 31;
    Li[rr][kk] = A[(ll)(ri + rr) * 256 + d0 + kk];
    Lj[rr][kk] = A[(ll)(rj + rr) * 256 + d0 + kk];
  }
  __syncthreads();
  for (int e = t; e < 1024; e += 256) {
    int rr = e >> 5, cc = e & 31;
    double s = 0.0;
#pragma unroll
    for (int k = 0; k < 32; ++k) s += Li[rr][k] * Lj[cc][k];
    A[(ll)(ri + rr) * 256 + rj + cc] -= s;
  }
}

// logdet = 2 * sum log(diag(L)), parallel reduce
__global__ void logdet_diag(const double* __restrict__ mats, double* __restrict__ ld) {
  __shared__ double sh[4];
  const double* A = mats + (ll)blockIdx.x * 65536;
  int t = threadIdx.x;
  double lg = log(A[(ll)t * 257]);
  int lane = t & 63, w = t >> 6;
#pragma unroll
  for (int off = 32; off > 0; off >>= 1) lg += __shfl_down(lg, off, 64);
  if (lane == 0) sh[w] = lg;
  __syncthreads();
  if (t == 0) ld[blockIdx.x] = 2.0 * (sh[0] + sh[1] + sh[2] + sh[3]);
}

__global__ void cov_final(const double* __restrict__ ld, float* __restrict__ outp) {
  outp[0] = (float)(-0.1 / (3.0 * 256.0) * (ld[0] + ld[1] + ld[2]));
}

// ---------------- output head: xph[M][256] @ outT[96][256]^T, scatter+denorm --
__global__ __launch_bounds__(256) void out_mfma(
    const ushort_t* __restrict__ A, const ushort_t* __restrict__ B,
    const float* __restrict__ bias, const float* __restrict__ stdev,
    const float* __restrict__ mean, float* __restrict__ out) {
  constexpr int M = Bn * Cn, N = Pn, K = Dn;
  __shared__ ushort_t lds_ab[2][128][32];
  int t = threadIdx.x;
  // XCD swizzle over the y-grid (512 blocks, %8==0)
  int nwg = gridDim.y;
  int wg = blockIdx.y;
  if ((nwg & 7) == 0) {
    int cpx = nwg >> 3;
    wg = (wg & 7) * cpx + (wg >> 3);
  }
  int m0 = wg * 128;
  int w = t >> 6, lane = t & 63;
  int wm = (w >> 1) * 64, wn = (w & 1) * 64;
  int lrow = lane & 15, kq = lane >> 4;
  int srow = lane >> 2, skcol = (lane & 3) * 8;
  f32x4 acc[4][4] = {};
  for (int k0 = 0; k0 < K; k0 += 32) {
#pragma unroll
    for (int cc = 0; cc < 4; ++cc) {
      int c = w * 4 + cc;
      int tile = c >> 3, rb = (c & 7) * 16;
      int row = rb + srow;
      const ushort_t* src;
      if (tile == 0) {
        src = &A[(ll)(m0 + row) * K + k0 + skcol];
      } else {
        int gn = min(row, N - 1);
        src = &B[(ll)gn * K + k0 + skcol];
      }
      gl_lds16(src, &lds_ab[tile][rb][0]);
    }
    __syncthreads();
    bf16x8 af[4], bfr[4];
#pragma unroll
    for (int i = 0; i < 4; ++i)
      af[i] = *reinterpret_cast<const bf16x8*>(&lds_ab[0][wm + i * 16 + lrow][kq * 8]);
#pragma unroll
    for (int j = 0; j < 4; ++j)
      bfr[j] = *reinterpret_cast<const bf16x8*>(&lds_ab[1][wn + j * 16 + lrow][kq * 8]);
#pragma unroll
    for (int i = 0; i < 4; ++i)
#pragma unroll
      for (int j = 0; j < 4; ++j)
        acc[i][j] = __builtin_amdgcn_mfma_f32_16x16x32_bf16(af[i], bfr[j],
                                                            acc[i][j], 0, 0, 0);
    __syncthreads();
  }
#pragma unroll
  for (int i = 0; i < 4; ++i) {
    int mb = m0 + wm + i * 16 + kq * 4;
#pragma unroll
    for (int j = 0; j < 4; ++j) {
      int p = wn + j * 16 + lrow;
      if (p >= N) continue;
      float bv = bias[p];
#pragma unroll
      for (int reg = 0; reg < 4; ++reg) {
        int m = mb + reg;
        int b = m >> 11, c = m & 2047;
        float v = acc[i][j][reg] + bv;
        out[((ll)(b * Pn + p)) * Cn + c] = v * stdev[m] + mean[m];
      }
    }
  }
}

// =====================================================================
extern "C" void kernel_launch(void* const* d_in, const int* in_sizes, int n_in,
                              void* d_out, int out_size, void* d_ws, size_t ws_size,
                              hipStream_t stream) {
  (void)in_sizes; (void)n_in; (void)out_size; (void)ws_size;
  const float* x_enc = (const float*)d_in[0];
  const float* in_w = (const float*)d_in[4];
  const float* in_b = (const float*)d_in[5];
  const float* lq[3] = {(const float*)d_in[6], (const float*)d_in[7],
                        (const float*)d_in[8]};
  const float* down_w = (const float*)d_in[9];
  const float* down_b = (const float*)d_in[10];
  const float* down_ln = (const float*)d_in[11];
  const float* pred_w = (const float*)d_in[12];
  const float* pred_b = (const float*)d_in[13];
  const float* up_w = (const float*)d_in[14];
  const float* up_b = (const float*)d_in[15];
  const float* up_ln = (const float*)d_in[16];
  const float* out_w = (const float*)d_in[17];
  const float* out_b = (const float*)d_in[18];
  float* out = (float*)d_out;

  float* ws = (float*)d_ws;
  size_t off = 0;
  auto alloc = [&](size_t n) {
    n = (n + 3) & ~(size_t)3;  // 16B alignment
    float* p = ws + off;
    off += n;
    return p;
  };
  float* mean = alloc((size_t)Bn * Cn);
  float* stdevv = alloc((size_t)Bn * Cn);
  float* cmean = alloc(3 * 256);
  float* cistd = alloc(3 * 256);
  double* part = (double*)alloc(3 * 256 * 512 * 2);
  double* ld = (double*)alloc(32);
  double* covd = (double*)alloc(3 * 65536 * 2);
  float* s1 = alloc((size_t)Bn * 512 * Dn);   // s1,s2,s3 contiguous (cov batched)
  float* s2 = alloc((size_t)Bn * 128 * Dn);
  float* s3 = alloc((size_t)Bn * 32 * Dn);
  float* attn = alloc((size_t)Bn * 512 * 2048);     // bf16 scores; also xnT(bf16)
  float* sbuf = alloc((size_t)16777216);            // attn_bf / o2 f32 / covpart
  ushort_t* h_bf = (ushort_t*)alloc((size_t)Bn * Cn * Dn / 2);
  ushort_t* s1b = (ushort_t*)alloc((size_t)Bn * 512 * Dn / 2);
  ushort_t* s2b = (ushort_t*)alloc((size_t)Bn * 128 * Dn / 2);
  ushort_t* s3b = (ushort_t*)alloc((size_t)Bn * 32 * Dn / 2);
  ushort_t* xpb = (ushort_t*)alloc((size_t)Bn * 32 * Dn / 2);
  ushort_t* xu0b = (ushort_t*)alloc((size_t)Bn * 128 * Dn / 2);
  ushort_t* xu1b = (ushort_t*)alloc((size_t)Bn * 512 * Dn / 2);
  ushort_t* qd_b = (ushort_t*)alloc(512 * 256 / 2);
  ushort_t* lqb0 = (ushort_t*)alloc(512 * 256 / 2);
  ushort_t* lqb1 = (ushort_t*)alloc(128 * 256 / 2);
  ushort_t* lqb2 = (ushort_t*)alloc(32 * 256 / 2);
  ushort_t* in_wT = (ushort_t*)alloc(256 * SnP / 2);
  ushort_t* downT = (ushort_t*)alloc(12 * 65536 / 2);
  ushort_t* upT = (ushort_t*)alloc(12 * 65536 / 2);
  ushort_t* predT = (ushort_t*)alloc(65536 / 2);
  ushort_t* outT = (ushort_t*)alloc(96 * 256 / 2);
  ushort_t* q_bf = (ushort_t*)alloc((size_t)Bn * 2048 * Dn / 2);  // also o1, xph
  ushort_t* k_bf = (ushort_t*)alloc((size_t)Bn * 2048 * Dn / 2);
  ushort_t* vT = (ushort_t*)alloc((size_t)Bn * 2048 * Dn / 2);

  ushort_t* xnT = (ushort_t*)attn;
  ushort_t* attn_s = (ushort_t*)attn;          // bf16 scores (post-prep reuse)
  ushort_t* attn_b = (ushort_t*)sbuf;
  float* o2 = sbuf;
  double* covpart = (double*)sbuf;
  const float scale = 0.0625f;
  const float* npf = nullptr;

  // ---- prep: stats, normalize+transpose input, weight converts ----
  instnorm_stats<<<dim3(Cn / 256, Bn), 256, 0, stream>>>(x_enc, mean, stdevv);
  normT_kernel<<<dim3(Cn / 32, SnP / 32, Bn), 256, 0, stream>>>(x_enc, xnT, mean,
                                                                stdevv);
  cvtT_kernel<<<dim3(8, 8, 12), 256, 0, stream>>>(down_w, downT, 256, 256, 256);
  cvtT_kernel<<<dim3(8, 8, 12), 256, 0, stream>>>(up_w, upT, 256, 256, 256);
  cvtT_kernel<<<dim3(8, 8, 1), 256, 0, stream>>>(pred_w, predT, 256, 256, 256);
  cvtT_kernel<<<dim3(8, SnP / 32, 1), 256, 0, stream>>>(in_w, in_wT, Sn, 256, SnP);
  cvtT_kernel<<<dim3(3, 8, 1), 256, 0, stream>>>(out_w, outT, 256, Pn, 256);
  cvt_bf<<<512, 256, 0, stream>>>(lq[0], lqb0, 512 * 256);
  cvt_bf<<<128, 256, 0, stream>>>(lq[1], lqb1, 128 * 256);
  cvt_bf<<<32, 256, 0, stream>>>(lq[2], lqb2, 32 * 256);

  // ---- h = xn^T @ in_w + b : bf16 out (K padded to 768) ----
  gemm_bf<2><<<dim3(2, 16, Bn), 256, 0, stream>>>(
      xnT, in_wT, Cn, Dn, SnP, SnP, SnP, (ll)Cn * SnP, 0, in_b, 1.f,
      nullptr, 0, 0, h_bf, Dn, (ll)Cn * Dn);

  ushort_t* lqb[3] = {lqb0, lqb1, lqb2};
  float* skf[3] = {s1, s2, s3};
  ushort_t* skb[3] = {s1b, s2b, s3b};
  int Ls[4] = {2048, 512, 128, 32};
  const ushort_t* xinb = h_bf;

  // ---------------- down layers ----------------
  for (int i = 0; i < 3; ++i) {
    int L = Ls[i], Lq = Ls[i + 1];
    const ushort_t* WqT = downT + (size_t)(i * 4 + 0) * 65536;
    const ushort_t* WkvT = downT + (size_t)(i * 4 + 1) * 65536;  // Wk||Wv
    const ushort_t* WoT = downT + (size_t)(i * 4 + 3) * 65536;
    const float* bq = down_b + (i * 4 + 0) * 256;
    const float* bkv = down_b + (i * 4 + 1) * 256;  // bk||bv (512)
    const float* bo = down_b + (i * 4 + 3) * 256;

    gemm_bf<2><<<dim3(2, CDIV(Lq, 128), 1), 256, 0, stream>>>(
        lqb[i], WqT, Lq, Dn, Dn, Dn, Dn, 0, 0, bq, 1.f, nullptr, 0, 0, qd_b, Dn, 0);
    // fused K+V projection: c<256 -> k_bf (row), c>=256 -> vT (transposed)
    gemm_bf<8><<<dim3(4, L / 128, Bn), 256, 0, stream>>>(
        xinb, WkvT, L, 512, Dn, Dn, Dn, (ll)L * Dn, 0, bkv, 1.f,
        (float*)vT, L, (ll)Dn * L, k_bf, Dn, (ll)L * Dn);
    // scores -> bf16 (alpha = scale folded in)
    gemm_bf<2><<<dim3(L / 128, CDIV(Lq, 128), Bn), 256, 0, stream>>>(
        qd_b, k_bf, Lq, L, Dn, Dn, Dn, 0, (ll)L * Dn, npf, scale,
        nullptr, 0, 0, attn_s, L, (ll)Lq * L);
    if (L == 2048) softmax_bf<2048><<<Bn * Lq, 256, 0, stream>>>(attn_s, attn_b);
    else if (L == 512) softmax_bf<512><<<Bn * Lq, 256, 0, stream>>>(attn_s, attn_b);
    else softmax_bf<128><<<Bn * Lq, 256, 0, stream>>>(attn_s, attn_b);
    gemm_bf<2><<<dim3(2, CDIV(Lq, 128), Bn), 256, 0, stream>>>(
        attn_b, vT, Lq, Dn, L, L, L, (ll)Lq * L, (ll)Dn * L, npf, 1.f,
        nullptr, 0, 0, q_bf, Dn, (ll)Lq * Dn);
    gemm_bf<1><<<dim3(2, CDIV(Bn * Lq, 128), 1), 256, 0, stream>>>(
        q_bf, WoT, Bn * Lq, Dn, Dn, Dn, Dn, 0, 0, bo, 1.f, o2, Dn, 0, nullptr, 0, 0);
    ln_kernel<<<Bn * Lq, 256, 0, stream>>>(o2, nullptr, skf[i], skb[i], 0,
                                           down_ln + (i * 2 + 0) * 256,
                                           down_ln + (i * 2 + 1) * 256);
    xinb = skb[i];
  }

  // ------- covariance loss (batched front-end + NB=32 Cholesky) --------------
  colstat_partial3<<<dim3(256, 3), 256, 0, stream>>>(s1, part);
  colstat_final3<<<3, 256, 0, stream>>>(part, cmean, cistd);
  cov_gram3<<<dim3(10, 64, 3), 256, 0, stream>>>(s1, cmean, cistd, covpart);
  cov_reduce3<<<dim3(10, 16, 3), 256, 0, stream>>>(covpart, covd);
  for (int kb = 0; kb < 8; ++kb) {
    chol_step_a<<<3, 256, 0, stream>>>(covd, kb * 32);
    int T = 7 - kb;
    if (T > 0)
      chol_step_b<<<dim3(T * (T + 1) / 2, 3), 256, 0, stream>>>(covd, kb * 32);
  }
  logdet_diag<<<3, 256, 0, stream>>>(covd, ld);
  cov_final<<<1, 1, 0, stream>>>(ld, out + 6291456);

  // ---------------- pred head ----------------
  gemm_bf<2><<<dim3(2, 8, 1), 256, 0, stream>>>(
      s3b, predT, Bn * 32, Dn, Dn, Dn, Dn, 0, 0, pred_b, 1.f,
      nullptr, 0, 0, xpb, Dn, 0);

  // ---------------- up layers ----------------
  int Lks[3] = {32, 128, 512}, Lqs[3] = {128, 512, 2048};
  const ushort_t* qinb[3] = {s2b, s1b, h_bf};
  const ushort_t* xinbs[3] = {xpb, xu0b, xu1b};
  ushort_t* xoutb[3] = {xu0b, xu1b, q_bf};  // final writes xph into q_bf
  for (int i = 0; i < 3; ++i) {
    int Lk = Lks[i], Lq = Lqs[i];
    const ushort_t* WqT = upT + (size_t)(i * 4 + 0) * 65536;
    const ushort_t* WkvT = upT + (size_t)(i * 4 + 1) * 65536;  // Wk||Wv
    const ushort_t* WoT = upT + (size_t)(i * 4 + 3) * 65536;
    const float* bq = up_b + (i * 4 + 0) * 256;
    const float* bkv = up_b + (i * 4 + 1) * 256;  // bk||bv (512)
    const float* bo = up_b + (i * 4 + 3) * 256;

    gemm_bf<2><<<dim3(2, (Bn * Lq) / 128, 1), 256, 0, stream>>>(
        qinb[i], WqT, Bn * Lq, Dn, Dn, Dn, Dn, 0, 0, bq, 1.f,
        nullptr, 0, 0, q_bf, Dn, 0);
    gemm_bf<8><<<dim3(4, CDIV(Lk, 128), Bn), 256, 0, stream>>>(
        xinbs[i], WkvT, Lk, 512, Dn, Dn, Dn, (ll)Lk * Dn, 0, bkv, 1.f,
        (float*)vT, Lk, (ll)Dn * Lk, k_bf, Dn, (ll)Lk * Dn);
    // scores -> bf16 (alpha = scale folded in)
    gemm_bf<2><<<dim3(CDIV(Lk, 128), CDIV(Lq, 128), Bn), 256, 0, stream>>>(
        q_bf, k_bf, Lq, Lk, Dn, Dn, Dn, (ll)Lq * Dn, (ll)Lk * Dn, npf, scale,
        nullptr, 0, 0, attn_s, Lk, (ll)Lq * Lk);
    if (Lk == 32) softmax_bf<32><<<Bn * Lq, 256, 0, stream>>>(attn_s, attn_b);
    else if (Lk == 128) softmax_bf<128><<<Bn * Lq, 256, 0, stream>>>(attn_s, attn_b);
    else softmax_bf<512><<<Bn * Lq, 256, 0, stream>>>(attn_s, attn_b);
    gemm_bf<2><<<dim3(2, CDIV(Lq, 128), Bn), 256, 0, stream>>>(
        attn_b, vT, Lq, Dn, Lk, Lk, Lk, (ll)Lq * Lk, (ll)Dn * Lk, npf, 1.f,
        nullptr, 0, 0, q_bf, Dn, (ll)Lq * Dn);
    gemm_bf<1><<<dim3(2, (Bn * Lq) / 128, 1), 256, 0, stream>>>(
        q_bf, WoT, Bn * Lq, Dn, Dn, Dn, Dn, 0, 0, bo, 1.f, o2, Dn, 0, nullptr, 0, 0);
    ln_kernel<<<Bn * Lq, 256, 0, stream>>>(o2, qinb[i], nullptr, xoutb[i],
                                           (i == 2) ? 1 : 0,
                                           up_ln + (i * 2 + 0) * 256,
                                           up_ln + (i * 2 + 1) * 256);
  }

  // ---------------- output head: MFMA + transpose + de-norm ----------------
  out_mfma<<<dim3(1, (Bn * Cn) / 128, 1), 256, 0, stream>>>(q_bf, outT, out_b,
                                                            stdevv, mean, out);
}